// Round 12
// baseline (362.239 us; speedup 1.0000x reference)
//
#include <hip/hip_runtime.h>
#include <math.h>

#define WD 64
#define TD 8192
#define NT 131072           // 16 * 8192 rows
#define KB 2048
// Output layout (float32, concatenated): x_l [NT], x_d [NT*WD], commit, fit, prenorm
#define OFF_XL 0
#define OFF_XD NT
#define OFF_SC (NT + NT * WD)

// ws layout (bytes)
#define RED_OFF   0                      // double[4]: xsum, xsumsq, fit, commit
#define CNT_OFF   32                     // uint: rescan count
#define KN2_OFF   4096                   // float[2048] np-exact ||k||^2
#define CB_OFF    16384                  // bf16 B-frags: 128jt * 4frag * 64lane * 16B = 512KB
#define M1_OFF    (16384 + 524288)       // float[NT]
#define M2_OFF    (M1_OFF + 4 * NT)      // float[NT]
#define J1_OFF    (M2_OFF + 4 * NT)      // int[NT]
#define LIST_OFF  (J1_OFF + 4 * NT)      // int[NT] rescan rows
#define KT_OFF    (LIST_OFF + 4 * NT)    // float[64][2048] transposed codebook (512KB)
#define XR_OFF    (KT_OFF + 8 * NT)      // float[XRCAP][64] compacted rescan rows
#define XRCAP     32768                  // 8MB cap (count ~2.9k observed r5-r11)

#define EPS_GAP 4e-3f    // approx top-2 gap below this -> exact rescan (~2% rows)
#define VEPS    2e-3f    // |approx score(j1) - exact score(j1)| above this -> rescan (~0)

typedef __attribute__((ext_vector_type(8))) short bf16x8_t;  // 8 bf16 (4 VGPRs)
typedef __attribute__((ext_vector_type(4))) float f32x4_t;

__device__ __forceinline__ unsigned short bf16_rne(float f) {
  unsigned int u = __float_as_uint(f);
  unsigned int r = u + 0x7fffu + ((u >> 16) & 1u);
  return (unsigned short)(r >> 16);
}

#define REP64(F) F(0) F(1) F(2) F(3) F(4) F(5) F(6) F(7) \
  F(8) F(9) F(10) F(11) F(12) F(13) F(14) F(15) \
  F(16) F(17) F(18) F(19) F(20) F(21) F(22) F(23) \
  F(24) F(25) F(26) F(27) F(28) F(29) F(30) F(31) \
  F(32) F(33) F(34) F(35) F(36) F(37) F(38) F(39) \
  F(40) F(41) F(42) F(43) F(44) F(45) F(46) F(47) \
  F(48) F(49) F(50) F(51) F(52) F(53) F(54) F(55) \
  F(56) F(57) F(58) F(59) F(60) F(61) F(62) F(63)

// numpy pairwise_sum (scalar 8-accumulator, n=64) of PRE-ROUNDED squares; *_rn
// intrinsics forbid contraction. Bit-exact vs np.sum(a*a, -1) (verified r2-r11).
#define NP_SUMSQ64_NAMED(SVAR) \
  float r0 = __fmul_rn(x0, x0); \
  float r1 = __fmul_rn(x1, x1); \
  float r2 = __fmul_rn(x2, x2); \
  float r3 = __fmul_rn(x3, x3); \
  float r4 = __fmul_rn(x4, x4); \
  float r5 = __fmul_rn(x5, x5); \
  float r6 = __fmul_rn(x6, x6); \
  float r7 = __fmul_rn(x7, x7); \
  SQ8(8, 9, 10, 11, 12, 13, 14, 15) \
  SQ8(16, 17, 18, 19, 20, 21, 22, 23) \
  SQ8(24, 25, 26, 27, 28, 29, 30, 31) \
  SQ8(32, 33, 34, 35, 36, 37, 38, 39) \
  SQ8(40, 41, 42, 43, 44, 45, 46, 47) \
  SQ8(48, 49, 50, 51, 52, 53, 54, 55) \
  SQ8(56, 57, 58, 59, 60, 61, 62, 63) \
  const float SVAR = __fadd_rn(__fadd_rn(__fadd_rn(r0, r1), __fadd_rn(r2, r3)), \
                               __fadd_rn(__fadd_rn(r4, r5), __fadd_rn(r6, r7)));
#define SQ8(a,b,c,d,e,f,g,h) \
  r0 = __fadd_rn(r0, __fmul_rn(x##a, x##a)); \
  r1 = __fadd_rn(r1, __fmul_rn(x##b, x##b)); \
  r2 = __fadd_rn(r2, __fmul_rn(x##c, x##c)); \
  r3 = __fadd_rn(r3, __fmul_rn(x##d, x##d)); \
  r4 = __fadd_rn(r4, __fmul_rn(x##e, x##e)); \
  r5 = __fadd_rn(r5, __fmul_rn(x##f, x##f)); \
  r6 = __fadd_rn(r6, __fmul_rn(x##g, x##g)); \
  r7 = __fadd_rn(r7, __fmul_rn(x##h, x##h));

__device__ __forceinline__ float np_sumsq64_ptr(const float* a) {
  float r0 = __fmul_rn(a[0], a[0]);
  float r1 = __fmul_rn(a[1], a[1]);
  float r2 = __fmul_rn(a[2], a[2]);
  float r3 = __fmul_rn(a[3], a[3]);
  float r4 = __fmul_rn(a[4], a[4]);
  float r5 = __fmul_rn(a[5], a[5]);
  float r6 = __fmul_rn(a[6], a[6]);
  float r7 = __fmul_rn(a[7], a[7]);
#pragma unroll
  for (int i = 8; i < 64; i += 8) {
    r0 = __fadd_rn(r0, __fmul_rn(a[i + 0], a[i + 0]));
    r1 = __fadd_rn(r1, __fmul_rn(a[i + 1], a[i + 1]));
    r2 = __fadd_rn(r2, __fmul_rn(a[i + 2], a[i + 2]));
    r3 = __fadd_rn(r3, __fmul_rn(a[i + 3], a[i + 3]));
    r4 = __fadd_rn(r4, __fmul_rn(a[i + 4], a[i + 4]));
    r5 = __fadd_rn(r5, __fmul_rn(a[i + 5], a[i + 5]));
    r6 = __fadd_rn(r6, __fmul_rn(a[i + 6], a[i + 6]));
    r7 = __fadd_rn(r7, __fmul_rn(a[i + 7], a[i + 7]));
  }
  float t01 = __fadd_rn(r0, r1);
  float t23 = __fadd_rn(r2, r3);
  float t45 = __fadd_rn(r4, r5);
  float t67 = __fadd_rn(r6, r7);
  return __fadd_rn(__fadd_rn(t01, t23), __fadd_rn(t45, t67));
}

// ---------- K0: kn2_np + bf16 B-frags + transposed codebook kT[w][c] ----------
__global__ __launch_bounds__(256)
void vq_prep(const float* __restrict__ k, char* __restrict__ wsb) {
  int c = blockIdx.x * 256 + threadIdx.x;
  if (c >= KB) return;
  const float* kr = k + (size_t)c * WD;
  ((float*)(wsb + KN2_OFF))[c] = np_sumsq64_ptr(kr);
  float* kt = (float*)(wsb + KT_OFF);
#pragma unroll
  for (int w = 0; w < WD; ++w) kt[(size_t)w * KB + c] = kr[w];
  int jt = c >> 4, col = c & 15;
  unsigned short* cb = (unsigned short*)(wsb + CB_OFF);
#pragma unroll
  for (int w = 0; w < WD; ++w) {
    float f = kr[w];
    unsigned short hb = bf16_rne(f);
    float hf = __uint_as_float((unsigned int)hb << 16);
    unsigned short lb = bf16_rne(f - hf);
    int fH = w >> 5;                       // K-half: frag 0/1 (hi), 2/3 (lo)
    int lane = col | (((w >> 3) & 3) << 4);
    int e = w & 7;
    cb[((size_t)((jt * 4 + fH) * 64 + lane)) * 8 + e] = hb;
    cb[((size_t)((jt * 4 + 2 + fH) * 64 + lane)) * 8 + e] = lb;
  }
}

// ---------- K1: MFMA bf16x3 score scan -> per-row (m1, m2, j1) ----------
__global__ __launch_bounds__(256, 3)
void vq_scan(const float* __restrict__ x, char* __restrict__ wsb) {
  __shared__ float lkn2[KB];
  for (int i = threadIdx.x; i < KB; i += 256)
    lkn2[i] = ((const float*)(wsb + KN2_OFF))[i];
  __syncthreads();

  const int tid = threadIdx.x, lane = tid & 63, wave = tid >> 6;
  const int col = lane & 15, grp = lane >> 4;
  const int n = blockIdx.x >> 6;           // 64 blocks per n (8192/128)
  const int t0 = (blockIdx.x & 63) * 128;
  const float* xb = x + (size_t)n * WD * TD;

  bf16x8_t aH[2][2], aL[2][2];             // [tile][k-step]
#pragma unroll
  for (int T = 0; T < 2; ++T) {
    int trow = t0 + wave * 32 + T * 16 + col;
#pragma unroll
    for (int s = 0; s < 2; ++s) {
#pragma unroll
      for (int e = 0; e < 8; ++e) {
        int w = s * 32 + grp * 8 + e;
        float f = xb[(size_t)w * TD + trow];
        unsigned short hb = bf16_rne(f);
        float hf = __uint_as_float((unsigned int)hb << 16);
        unsigned short lb = bf16_rne(f - hf);
        aH[T][s][e] = (short)hb;
        aL[T][s][e] = (short)lb;
      }
    }
  }

  float m1v[2][4], m2v[2][4];
  int j1v[2][4];
#pragma unroll
  for (int T = 0; T < 2; ++T)
#pragma unroll
    for (int e = 0; e < 4; ++e) {
      m1v[T][e] = INFINITY; m2v[T][e] = INFINITY; j1v[T][e] = 0;
    }

  const bf16x8_t* cb = (const bf16x8_t*)(wsb + CB_OFF);
  const f32x4_t zero4 = {0.f, 0.f, 0.f, 0.f};

  for (int jt = 0; jt < 128; ++jt) {
    const bf16x8_t* bp = cb + (size_t)jt * 256 + lane;
    bf16x8_t bH0 = bp[0], bH1 = bp[64], bL0 = bp[128], bL1 = bp[192];
    float kv = lkn2[jt * 16 + col];
    f32x4_t aA0 = __builtin_amdgcn_mfma_f32_16x16x32_bf16(aH[0][0], bH0, zero4, 0, 0, 0);
    f32x4_t aB0 = __builtin_amdgcn_mfma_f32_16x16x32_bf16(aH[0][1], bH1, zero4, 0, 0, 0);
    f32x4_t aA1 = __builtin_amdgcn_mfma_f32_16x16x32_bf16(aH[1][0], bH0, zero4, 0, 0, 0);
    f32x4_t aB1 = __builtin_amdgcn_mfma_f32_16x16x32_bf16(aH[1][1], bH1, zero4, 0, 0, 0);
    aA0 = __builtin_amdgcn_mfma_f32_16x16x32_bf16(aL[0][0], bH0, aA0, 0, 0, 0);
    aB0 = __builtin_amdgcn_mfma_f32_16x16x32_bf16(aL[0][1], bH1, aB0, 0, 0, 0);
    aA1 = __builtin_amdgcn_mfma_f32_16x16x32_bf16(aL[1][0], bH0, aA1, 0, 0, 0);
    aB1 = __builtin_amdgcn_mfma_f32_16x16x32_bf16(aL[1][1], bH1, aB1, 0, 0, 0);
    aA0 = __builtin_amdgcn_mfma_f32_16x16x32_bf16(aH[0][0], bL0, aA0, 0, 0, 0);
    aB0 = __builtin_amdgcn_mfma_f32_16x16x32_bf16(aH[0][1], bL1, aB0, 0, 0, 0);
    aA1 = __builtin_amdgcn_mfma_f32_16x16x32_bf16(aH[1][0], bL0, aA1, 0, 0, 0);
    aB1 = __builtin_amdgcn_mfma_f32_16x16x32_bf16(aH[1][1], bL1, aB1, 0, 0, 0);

    int cd = jt * 16 + col;
#define UPD(T, E, V) { bool b = (V) < m1v[T][E]; \
      m2v[T][E] = b ? m1v[T][E] : fminf(m2v[T][E], (V)); \
      m1v[T][E] = b ? (V) : m1v[T][E]; \
      j1v[T][E] = b ? cd : j1v[T][E]; }
    {
      float v0 = fmaf(-2.f, aA0[0] + aB0[0], kv);
      float v1 = fmaf(-2.f, aA0[1] + aB0[1], kv);
      float v2 = fmaf(-2.f, aA0[2] + aB0[2], kv);
      float v3 = fmaf(-2.f, aA0[3] + aB0[3], kv);
      UPD(0, 0, v0) UPD(0, 1, v1) UPD(0, 2, v2) UPD(0, 3, v3)
      float u0 = fmaf(-2.f, aA1[0] + aB1[0], kv);
      float u1 = fmaf(-2.f, aA1[1] + aB1[1], kv);
      float u2 = fmaf(-2.f, aA1[2] + aB1[2], kv);
      float u3 = fmaf(-2.f, aA1[3] + aB1[3], kv);
      UPD(1, 0, u0) UPD(1, 1, u1) UPD(1, 2, u2) UPD(1, 3, u3)
    }
#undef UPD
  }

#pragma unroll
  for (int T = 0; T < 2; ++T)
#pragma unroll
    for (int e = 0; e < 4; ++e) {
      float m1 = m1v[T][e], m2 = m2v[T][e];
      int j1 = j1v[T][e];
#pragma unroll
      for (int d = 1; d < 16; d <<= 1) {
        float om1 = __shfl_xor(m1, d, 64);
        float om2 = __shfl_xor(m2, d, 64);
        int oj = __shfl_xor(j1, d, 64);
        bool take = (om1 < m1) || (om1 == m1 && oj < j1);
        float loser = take ? m1 : om1;
        m2 = fminf(fminf(m2, om2), loser);
        m1 = take ? om1 : m1;
        j1 = take ? oj : j1;
      }
      if (col == 0) {
        int row = blockIdx.x * 128 + wave * 32 + T * 16 + grp * 4 + e;
        ((float*)(wsb + M1_OFF))[row] = m1;
        ((float*)(wsb + M2_OFF))[row] = m2;
        ((int*)(wsb + J1_OFF))[row] = j1;
      }
    }
}

// ---------- K2: per-row finalize: verify j1, epilogue, flag + compact rescans ----------
__global__ __launch_bounds__(256, 4)
void vq_fin(const float* __restrict__ x, const float* __restrict__ k,
            float* __restrict__ out, char* __restrict__ wsb) {
  __shared__ double sred[16];
  const int tid = threadIdx.x;
  const int row = blockIdx.x * 256 + tid;
  const int n = row >> 13;
  const int t = row & (TD - 1);

  float m1r = ((const float*)(wsb + M1_OFF))[row];
  float m2r = ((const float*)(wsb + M2_OFF))[row];
  int j1r = ((const int*)(wsb + J1_OFF))[row];

  const float* xr = x + ((size_t)n * WD) * TD + t;
#define LOADX(w) float x##w = xr[(size_t)(w) * TD];
  REP64(LOADX)
#undef LOADX

  NP_SUMSQ64_NAMED(s)

  double xsum = 0.0, xsumsq = 0.0;
#define PRE(w) { double xd = (double)x##w; xsum += xd; xsumsq = fma(xd, xd, xsumsq); }
  REP64(PRE)
#undef PRE

  const float* kbr = k + (size_t)j1r * WD;
  float* xo = out + OFF_XD + ((size_t)n * WD) * TD + t;
  double commit = 0.0;
  float g = 0.f;
#define EPI(w) { \
    float kw = kbr[w]; \
    float diff = __fsub_rn(kw, x##w); \
    commit = fma((double)diff, (double)diff, commit); \
    g = __fmaf_rn(x##w, kw, g); \
    xo[(size_t)(w) * TD] = __fadd_rn(x##w, diff); }
  REP64(EPI)
#undef EPI

  float kn2j = ((const float*)(wsb + KN2_OFF))[j1r];
  float score = kn2j - 2.f * g;
  bool resc = (m2r - m1r < EPS_GAP) || (fabsf(score - m1r) > VEPS);
  float dist1 = __fadd_rn(__fsub_rn(s, __fmul_rn(2.f, g)), kn2j);

  out[OFF_XL + row] = (float)j1r;
  if (resc) {
    unsigned idx = atomicAdd((unsigned*)(wsb + CNT_OFF), 1u);
    ((int*)(wsb + LIST_OFF))[idx] = row;
    if (idx < XRCAP) {                                    // compact row for rescan
      float* xrw = (float*)(wsb + XR_OFF) + (size_t)idx * WD;
#define XWR(w) xrw[w] = x##w;
      REP64(XWR)
#undef XWR
    }
  }

  double v0 = xsum, v1 = xsumsq;
  double v2 = resc ? 0.0 : (double)dist1;
  double v3 = resc ? 0.0 : commit;
#pragma unroll
  for (int off = 32; off > 0; off >>= 1) {
    v0 += __shfl_down(v0, off, 64);
    v1 += __shfl_down(v1, off, 64);
    v2 += __shfl_down(v2, off, 64);
    v3 += __shfl_down(v3, off, 64);
  }
  if ((tid & 63) == 0) {
    int wv = tid >> 6;
    sred[wv * 4 + 0] = v0;
    sred[wv * 4 + 1] = v1;
    sred[wv * 4 + 2] = v2;
    sred[wv * 4 + 3] = v3;
  }
  __syncthreads();
  if (tid == 0) {
    double a0 = 0, a1 = 0, a2 = 0, a3 = 0;
#pragma unroll
    for (int w2 = 0; w2 < 4; ++w2) {
      a0 += sred[w2 * 4 + 0];
      a1 += sred[w2 * 4 + 1];
      a2 += sred[w2 * 4 + 2];
      a3 += sred[w2 * 4 + 3];
    }
    double* red = (double*)(wsb + RED_OFF);
    atomicAdd(&red[0], a0);
    atomicAdd(&red[1], a1);
    atomicAdd(&red[2], a2);
    atomicAdd(&red[3], a3);
  }
}

// ---------- K3: exact rescan via transposed codebook, FOUR rows per block ----------
// r11 counters: rescan5 was L2-BW-bound (2.9k blocks x 512KB kT = 1.5GB).
// Amortize: one kT stream feeds 4 rows -> 370MB. Per w-step: 2 coalesced
// float4 loads (8 codes) FMA'd into 32 NAMED accumulators (8 codes x 4 rows);
// ~60 live VGPRs, structurally spill-proof (r9/r10 lesson). np-exact chains.
__global__ __launch_bounds__(256)
void vq_rescan6(const float* __restrict__ x, const float* __restrict__ k,
                float* __restrict__ out, char* __restrict__ wsb) {
  __shared__ float xs[4][WD];
  __shared__ float ss[4];
  __shared__ unsigned long long wred[4][4];   // [row][wave]
  __shared__ unsigned long long bbest[4];
  const unsigned count = *(const unsigned*)(wsb + CNT_OFF);
  const int* list = (const int*)(wsb + LIST_OFF);
  const float* kn2 = (const float*)(wsb + KN2_OFF);
  const float* XR = (const float*)(wsb + XR_OFF);
  const float* kT = (const float*)(wsb + KT_OFF);
  double* red = (double*)(wsb + RED_OFF);
  const int tid = threadIdx.x;
  const int lane = tid & 63, wv = tid >> 6;
  const int c0 = tid * 8;

  for (unsigned base = blockIdx.x * 4u; base < count; base += gridDim.x * 4u) {
    __syncthreads();                       // xs/ss/wred reuse guard
    {                                      // stage up to 4 rows (256 thr = 4x64)
      const int r = tid >> 6, w = tid & 63;
      const unsigned li = base + (unsigned)r;
      if (li < count) {
        if (li < XRCAP) {
          xs[r][w] = XR[(size_t)li * WD + w];
        } else {
          const int row = list[li];
          const int n = row >> 13, t = row & (TD - 1);
          xs[r][w] = x[(size_t)n * WD * TD + (size_t)w * TD + t];
        }
      }
    }
    __syncthreads();
    if (lane == 0) ss[wv] = np_sumsq64_ptr(xs[wv]);   // 1x per row (wave-uniform)
    __syncthreads();
    const float s0 = ss[0], s1 = ss[1], s2 = ss[2], s3 = ss[3];

    float a00 = 0.f, a01 = 0.f, a02 = 0.f, a03 = 0.f, a04 = 0.f, a05 = 0.f, a06 = 0.f, a07 = 0.f;
    float a10 = 0.f, a11 = 0.f, a12 = 0.f, a13 = 0.f, a14 = 0.f, a15 = 0.f, a16 = 0.f, a17 = 0.f;
    float a20 = 0.f, a21 = 0.f, a22 = 0.f, a23 = 0.f, a24 = 0.f, a25 = 0.f, a26 = 0.f, a27 = 0.f;
    float a30 = 0.f, a31 = 0.f, a32 = 0.f, a33 = 0.f, a34 = 0.f, a35 = 0.f, a36 = 0.f, a37 = 0.f;
    const float* kt = kT + c0;
#pragma unroll 4
    for (int w = 0; w < WD; ++w) {
      const float4 ka = *(const float4*)(kt + (size_t)w * KB);
      const float4 kb = *(const float4*)(kt + (size_t)w * KB + 4);
      const float xw0 = xs[0][w], xw1 = xs[1][w], xw2 = xs[2][w], xw3 = xs[3][w];
      a00 = __fmaf_rn(xw0, ka.x, a00); a01 = __fmaf_rn(xw0, ka.y, a01);
      a02 = __fmaf_rn(xw0, ka.z, a02); a03 = __fmaf_rn(xw0, ka.w, a03);
      a04 = __fmaf_rn(xw0, kb.x, a04); a05 = __fmaf_rn(xw0, kb.y, a05);
      a06 = __fmaf_rn(xw0, kb.z, a06); a07 = __fmaf_rn(xw0, kb.w, a07);
      a10 = __fmaf_rn(xw1, ka.x, a10); a11 = __fmaf_rn(xw1, ka.y, a11);
      a12 = __fmaf_rn(xw1, ka.z, a12); a13 = __fmaf_rn(xw1, ka.w, a13);
      a14 = __fmaf_rn(xw1, kb.x, a14); a15 = __fmaf_rn(xw1, kb.y, a15);
      a16 = __fmaf_rn(xw1, kb.z, a16); a17 = __fmaf_rn(xw1, kb.w, a17);
      a20 = __fmaf_rn(xw2, ka.x, a20); a21 = __fmaf_rn(xw2, ka.y, a21);
      a22 = __fmaf_rn(xw2, ka.z, a22); a23 = __fmaf_rn(xw2, ka.w, a23);
      a24 = __fmaf_rn(xw2, kb.x, a24); a25 = __fmaf_rn(xw2, kb.y, a25);
      a26 = __fmaf_rn(xw2, kb.z, a26); a27 = __fmaf_rn(xw2, kb.w, a27);
      a30 = __fmaf_rn(xw3, ka.x, a30); a31 = __fmaf_rn(xw3, ka.y, a31);
      a32 = __fmaf_rn(xw3, ka.z, a32); a33 = __fmaf_rn(xw3, ka.w, a33);
      a34 = __fmaf_rn(xw3, kb.x, a34); a35 = __fmaf_rn(xw3, kb.y, a35);
      a36 = __fmaf_rn(xw3, kb.z, a36); a37 = __fmaf_rn(xw3, kb.w, a37);
    }

    // per-row packed argmin over this thread's 8 codes, then wave reduce
#define ROWBEST(R, SV, A0, A1, A2, A3, A4, A5, A6, A7) { \
      unsigned long long best = ~0ull; \
      float d; unsigned long long p; \
      d = __fadd_rn(__fsub_rn(SV, __fmul_rn(2.f, A0)), kn2[c0 + 0]); \
      p = ((unsigned long long)__float_as_uint(d) << 32) | (unsigned)(c0 + 0); best = p < best ? p : best; \
      d = __fadd_rn(__fsub_rn(SV, __fmul_rn(2.f, A1)), kn2[c0 + 1]); \
      p = ((unsigned long long)__float_as_uint(d) << 32) | (unsigned)(c0 + 1); best = p < best ? p : best; \
      d = __fadd_rn(__fsub_rn(SV, __fmul_rn(2.f, A2)), kn2[c0 + 2]); \
      p = ((unsigned long long)__float_as_uint(d) << 32) | (unsigned)(c0 + 2); best = p < best ? p : best; \
      d = __fadd_rn(__fsub_rn(SV, __fmul_rn(2.f, A3)), kn2[c0 + 3]); \
      p = ((unsigned long long)__float_as_uint(d) << 32) | (unsigned)(c0 + 3); best = p < best ? p : best; \
      d = __fadd_rn(__fsub_rn(SV, __fmul_rn(2.f, A4)), kn2[c0 + 4]); \
      p = ((unsigned long long)__float_as_uint(d) << 32) | (unsigned)(c0 + 4); best = p < best ? p : best; \
      d = __fadd_rn(__fsub_rn(SV, __fmul_rn(2.f, A5)), kn2[c0 + 5]); \
      p = ((unsigned long long)__float_as_uint(d) << 32) | (unsigned)(c0 + 5); best = p < best ? p : best; \
      d = __fadd_rn(__fsub_rn(SV, __fmul_rn(2.f, A6)), kn2[c0 + 6]); \
      p = ((unsigned long long)__float_as_uint(d) << 32) | (unsigned)(c0 + 6); best = p < best ? p : best; \
      d = __fadd_rn(__fsub_rn(SV, __fmul_rn(2.f, A7)), kn2[c0 + 7]); \
      p = ((unsigned long long)__float_as_uint(d) << 32) | (unsigned)(c0 + 7); best = p < best ? p : best; \
      _Pragma("unroll") \
      for (int dd = 1; dd < 64; dd <<= 1) { \
        unsigned lo = (unsigned)best, hi = (unsigned)(best >> 32); \
        unsigned olo = __shfl_xor(lo, dd, 64); \
        unsigned ohi = __shfl_xor(hi, dd, 64); \
        unsigned long long o = ((unsigned long long)ohi << 32) | olo; \
        best = o < best ? o : best; \
      } \
      if (lane == 0) wred[R][wv] = best; }
    ROWBEST(0, s0, a00, a01, a02, a03, a04, a05, a06, a07)
    ROWBEST(1, s1, a10, a11, a12, a13, a14, a15, a16, a17)
    ROWBEST(2, s2, a20, a21, a22, a23, a24, a25, a26, a27)
    ROWBEST(3, s3, a30, a31, a32, a33, a34, a35, a36, a37)
#undef ROWBEST
    __syncthreads();
    if (tid < 4) {
      unsigned long long b = wred[tid][0];
      b = wred[tid][1] < b ? wred[tid][1] : b;
      b = wred[tid][2] < b ? wred[tid][2] : b;
      b = wred[tid][3] < b ? wred[tid][3] : b;
      bbest[tid] = b;
    }
    __syncthreads();

    // epilogue: wave wv handles row base+wv, lane = w (one wave per row)
    {
      const int r = wv, w = lane;
      const unsigned li = base + (unsigned)r;
      if (li < count) {
        const int row = list[li];
        const int n = row >> 13, t = row & (TD - 1);
        const unsigned long long fb = bbest[r];
        const int bi = (int)(fb & 0xffffffffu);
        const float bv = __uint_as_float((unsigned)(fb >> 32));
        float kw = k[(size_t)bi * WD + w];
        float xw = xs[r][w];
        float diff = __fsub_rn(kw, xw);
        out[OFF_XD + (size_t)n * WD * TD + (size_t)w * TD + t] = __fadd_rn(xw, diff);
        double d2 = (double)diff * (double)diff;
#pragma unroll
        for (int dd = 32; dd > 0; dd >>= 1) d2 += __shfl_down(d2, dd, 64);
        if (w == 0) {
          out[OFF_XL + row] = (float)bi;
          atomicAdd(&red[2], (double)bv);
          atomicAdd(&red[3], d2);
        }
      }
    }
  }
}

__global__ void vq_final(const char* __restrict__ wsb, float* __restrict__ out) {
  const double* red = (const double*)(wsb + RED_OFF);
  double sum = red[0], sumsq = red[1];
  double mean = sum / 8388608.0;
  double ss = sumsq - sum * mean;
  if (ss < 0.0) ss = 0.0;
  out[OFF_SC + 0] = (float)(red[3] / 8388608.0);       // commit_loss
  out[OFF_SC + 1] = (float)(red[2] / 131072.0);        // fit
  out[OFF_SC + 2] = (float)sqrt(ss / 8388608.0);       // prenorm
}

extern "C" void kernel_launch(void* const* d_in, const int* in_sizes, int n_in,
                              void* d_out, int out_size, void* d_ws, size_t ws_size,
                              hipStream_t stream) {
  const float* x = (const float*)d_in[0];
  const float* k = (const float*)d_in[1];
  float* out = (float*)d_out;
  char* wsb = (char*)d_ws;

  hipMemsetAsync(d_ws, 0, 64, stream);                 // red[4] + count
  vq_prep<<<KB / 256, 256, 0, stream>>>(k, wsb);
  vq_scan<<<NT / 128, 256, 0, stream>>>(x, wsb);
  vq_fin<<<NT / 256, 256, 0, stream>>>(x, k, out, wsb);
  vq_rescan6<<<1024, 256, 0, stream>>>(x, k, out, wsb);
  vq_final<<<1, 1, 0, stream>>>(wsb, out);
}

// Round 13
// 245.905 us; speedup vs baseline: 1.4731x; 1.4731x over previous
//
#include <hip/hip_runtime.h>
#include <math.h>

#define WD 64
#define TD 8192
#define NT 131072           // 16 * 8192 rows
#define KB 2048
// Output layout (float32, concatenated): x_l [NT], x_d [NT*WD], commit, fit, prenorm
#define OFF_XL 0
#define OFF_XD NT
#define OFF_SC (NT + NT * WD)

// ws layout (bytes)
#define RED_OFF   0                      // double[4]: xsum, xsumsq, fit, commit
#define CNT_OFF   32                     // uint: rescan count
#define KN2_OFF   4096                   // float[2048] np-exact ||k||^2
#define CB_OFF    16384                  // bf16 B-frags: 128jt * 4frag * 64lane * 16B = 512KB
#define M1_OFF    (16384 + 524288)       // float[NT]
#define M2_OFF    (M1_OFF + 4 * NT)      // float[NT]
#define J1_OFF    (M2_OFF + 4 * NT)      // int[NT]
#define LIST_OFF  (J1_OFF + 4 * NT)      // int[NT] rescan rows
#define KT_OFF    (LIST_OFF + 4 * NT)    // float[64][2048] transposed codebook (512KB)
#define XR_OFF    (KT_OFF + 8 * NT)      // float[XRCAP][64] compacted rescan rows (8MB)
#define FITV_OFF  (XR_OFF + XRCAP * WD * 4)  // double[NT] per-rescan-slot min dist
#define CMV_OFF   (FITV_OFF + 8 * NT)        // double[NT] per-rescan-slot commit part
#define XRCAP     32768                  // cap (count ~2.9k observed r5-r12)

#define EPS_GAP 4e-3f    // approx top-2 gap below this -> exact rescan (~2% rows)
#define VEPS    2e-3f    // |approx score(j1) - exact score(j1)| above this -> rescan (~0)

typedef __attribute__((ext_vector_type(8))) short bf16x8_t;  // 8 bf16 (4 VGPRs)
typedef __attribute__((ext_vector_type(4))) float f32x4_t;

__device__ __forceinline__ unsigned short bf16_rne(float f) {
  unsigned int u = __float_as_uint(f);
  unsigned int r = u + 0x7fffu + ((u >> 16) & 1u);
  return (unsigned short)(r >> 16);
}

#define REP64(F) F(0) F(1) F(2) F(3) F(4) F(5) F(6) F(7) \
  F(8) F(9) F(10) F(11) F(12) F(13) F(14) F(15) \
  F(16) F(17) F(18) F(19) F(20) F(21) F(22) F(23) \
  F(24) F(25) F(26) F(27) F(28) F(29) F(30) F(31) \
  F(32) F(33) F(34) F(35) F(36) F(37) F(38) F(39) \
  F(40) F(41) F(42) F(43) F(44) F(45) F(46) F(47) \
  F(48) F(49) F(50) F(51) F(52) F(53) F(54) F(55) \
  F(56) F(57) F(58) F(59) F(60) F(61) F(62) F(63)

// numpy pairwise_sum (scalar 8-accumulator, n=64) of PRE-ROUNDED squares; *_rn
// intrinsics forbid contraction. Bit-exact vs np.sum(a*a, -1) (verified r2-r12).
#define NP_SUMSQ64_NAMED(SVAR) \
  float r0 = __fmul_rn(x0, x0); \
  float r1 = __fmul_rn(x1, x1); \
  float r2 = __fmul_rn(x2, x2); \
  float r3 = __fmul_rn(x3, x3); \
  float r4 = __fmul_rn(x4, x4); \
  float r5 = __fmul_rn(x5, x5); \
  float r6 = __fmul_rn(x6, x6); \
  float r7 = __fmul_rn(x7, x7); \
  SQ8(8, 9, 10, 11, 12, 13, 14, 15) \
  SQ8(16, 17, 18, 19, 20, 21, 22, 23) \
  SQ8(24, 25, 26, 27, 28, 29, 30, 31) \
  SQ8(32, 33, 34, 35, 36, 37, 38, 39) \
  SQ8(40, 41, 42, 43, 44, 45, 46, 47) \
  SQ8(48, 49, 50, 51, 52, 53, 54, 55) \
  SQ8(56, 57, 58, 59, 60, 61, 62, 63) \
  const float SVAR = __fadd_rn(__fadd_rn(__fadd_rn(r0, r1), __fadd_rn(r2, r3)), \
                               __fadd_rn(__fadd_rn(r4, r5), __fadd_rn(r6, r7)));
#define SQ8(a,b,c,d,e,f,g,h) \
  r0 = __fadd_rn(r0, __fmul_rn(x##a, x##a)); \
  r1 = __fadd_rn(r1, __fmul_rn(x##b, x##b)); \
  r2 = __fadd_rn(r2, __fmul_rn(x##c, x##c)); \
  r3 = __fadd_rn(r3, __fmul_rn(x##d, x##d)); \
  r4 = __fadd_rn(r4, __fmul_rn(x##e, x##e)); \
  r5 = __fadd_rn(r5, __fmul_rn(x##f, x##f)); \
  r6 = __fadd_rn(r6, __fmul_rn(x##g, x##g)); \
  r7 = __fadd_rn(r7, __fmul_rn(x##h, x##h));

__device__ __forceinline__ float np_sumsq64_ptr(const float* a) {
  float r0 = __fmul_rn(a[0], a[0]);
  float r1 = __fmul_rn(a[1], a[1]);
  float r2 = __fmul_rn(a[2], a[2]);
  float r3 = __fmul_rn(a[3], a[3]);
  float r4 = __fmul_rn(a[4], a[4]);
  float r5 = __fmul_rn(a[5], a[5]);
  float r6 = __fmul_rn(a[6], a[6]);
  float r7 = __fmul_rn(a[7], a[7]);
#pragma unroll
  for (int i = 8; i < 64; i += 8) {
    r0 = __fadd_rn(r0, __fmul_rn(a[i + 0], a[i + 0]));
    r1 = __fadd_rn(r1, __fmul_rn(a[i + 1], a[i + 1]));
    r2 = __fadd_rn(r2, __fmul_rn(a[i + 2], a[i + 2]));
    r3 = __fadd_rn(r3, __fmul_rn(a[i + 3], a[i + 3]));
    r4 = __fadd_rn(r4, __fmul_rn(a[i + 4], a[i + 4]));
    r5 = __fadd_rn(r5, __fmul_rn(a[i + 5], a[i + 5]));
    r6 = __fadd_rn(r6, __fmul_rn(a[i + 6], a[i + 6]));
    r7 = __fadd_rn(r7, __fmul_rn(a[i + 7], a[i + 7]));
  }
  float t01 = __fadd_rn(r0, r1);
  float t23 = __fadd_rn(r2, r3);
  float t45 = __fadd_rn(r4, r5);
  float t67 = __fadd_rn(r6, r7);
  return __fadd_rn(__fadd_rn(t01, t23), __fadd_rn(t45, t67));
}

// ---------- K0: kn2_np + bf16 B-frags + transposed codebook kT[w][c] ----------
__global__ __launch_bounds__(256)
void vq_prep(const float* __restrict__ k, char* __restrict__ wsb) {
  int c = blockIdx.x * 256 + threadIdx.x;
  if (c >= KB) return;
  const float* kr = k + (size_t)c * WD;
  ((float*)(wsb + KN2_OFF))[c] = np_sumsq64_ptr(kr);
  float* kt = (float*)(wsb + KT_OFF);
#pragma unroll
  for (int w = 0; w < WD; ++w) kt[(size_t)w * KB + c] = kr[w];
  int jt = c >> 4, col = c & 15;
  unsigned short* cb = (unsigned short*)(wsb + CB_OFF);
#pragma unroll
  for (int w = 0; w < WD; ++w) {
    float f = kr[w];
    unsigned short hb = bf16_rne(f);
    float hf = __uint_as_float((unsigned int)hb << 16);
    unsigned short lb = bf16_rne(f - hf);
    int fH = w >> 5;                       // K-half: frag 0/1 (hi), 2/3 (lo)
    int lane = col | (((w >> 3) & 3) << 4);
    int e = w & 7;
    cb[((size_t)((jt * 4 + fH) * 64 + lane)) * 8 + e] = hb;
    cb[((size_t)((jt * 4 + 2 + fH) * 64 + lane)) * 8 + e] = lb;
  }
}

// ---------- K1: MFMA bf16x3 score scan -> per-row (m1, m2, j1) ----------
__global__ __launch_bounds__(256, 3)
void vq_scan(const float* __restrict__ x, char* __restrict__ wsb) {
  __shared__ float lkn2[KB];
  for (int i = threadIdx.x; i < KB; i += 256)
    lkn2[i] = ((const float*)(wsb + KN2_OFF))[i];
  __syncthreads();

  const int tid = threadIdx.x, lane = tid & 63, wave = tid >> 6;
  const int col = lane & 15, grp = lane >> 4;
  const int n = blockIdx.x >> 6;           // 64 blocks per n (8192/128)
  const int t0 = (blockIdx.x & 63) * 128;
  const float* xb = x + (size_t)n * WD * TD;

  bf16x8_t aH[2][2], aL[2][2];             // [tile][k-step]
#pragma unroll
  for (int T = 0; T < 2; ++T) {
    int trow = t0 + wave * 32 + T * 16 + col;
#pragma unroll
    for (int s = 0; s < 2; ++s) {
#pragma unroll
      for (int e = 0; e < 8; ++e) {
        int w = s * 32 + grp * 8 + e;
        float f = xb[(size_t)w * TD + trow];
        unsigned short hb = bf16_rne(f);
        float hf = __uint_as_float((unsigned int)hb << 16);
        unsigned short lb = bf16_rne(f - hf);
        aH[T][s][e] = (short)hb;
        aL[T][s][e] = (short)lb;
      }
    }
  }

  float m1v[2][4], m2v[2][4];
  int j1v[2][4];
#pragma unroll
  for (int T = 0; T < 2; ++T)
#pragma unroll
    for (int e = 0; e < 4; ++e) {
      m1v[T][e] = INFINITY; m2v[T][e] = INFINITY; j1v[T][e] = 0;
    }

  const bf16x8_t* cb = (const bf16x8_t*)(wsb + CB_OFF);
  const f32x4_t zero4 = {0.f, 0.f, 0.f, 0.f};

  for (int jt = 0; jt < 128; ++jt) {
    const bf16x8_t* bp = cb + (size_t)jt * 256 + lane;
    bf16x8_t bH0 = bp[0], bH1 = bp[64], bL0 = bp[128], bL1 = bp[192];
    float kv = lkn2[jt * 16 + col];
    f32x4_t aA0 = __builtin_amdgcn_mfma_f32_16x16x32_bf16(aH[0][0], bH0, zero4, 0, 0, 0);
    f32x4_t aB0 = __builtin_amdgcn_mfma_f32_16x16x32_bf16(aH[0][1], bH1, zero4, 0, 0, 0);
    f32x4_t aA1 = __builtin_amdgcn_mfma_f32_16x16x32_bf16(aH[1][0], bH0, zero4, 0, 0, 0);
    f32x4_t aB1 = __builtin_amdgcn_mfma_f32_16x16x32_bf16(aH[1][1], bH1, zero4, 0, 0, 0);
    aA0 = __builtin_amdgcn_mfma_f32_16x16x32_bf16(aL[0][0], bH0, aA0, 0, 0, 0);
    aB0 = __builtin_amdgcn_mfma_f32_16x16x32_bf16(aL[0][1], bH1, aB0, 0, 0, 0);
    aA1 = __builtin_amdgcn_mfma_f32_16x16x32_bf16(aL[1][0], bH0, aA1, 0, 0, 0);
    aB1 = __builtin_amdgcn_mfma_f32_16x16x32_bf16(aL[1][1], bH1, aB1, 0, 0, 0);
    aA0 = __builtin_amdgcn_mfma_f32_16x16x32_bf16(aH[0][0], bL0, aA0, 0, 0, 0);
    aB0 = __builtin_amdgcn_mfma_f32_16x16x32_bf16(aH[0][1], bL1, aB0, 0, 0, 0);
    aA1 = __builtin_amdgcn_mfma_f32_16x16x32_bf16(aH[1][0], bL0, aA1, 0, 0, 0);
    aB1 = __builtin_amdgcn_mfma_f32_16x16x32_bf16(aH[1][1], bL1, aB1, 0, 0, 0);

    int cd = jt * 16 + col;
#define UPD(T, E, V) { bool b = (V) < m1v[T][E]; \
      m2v[T][E] = b ? m1v[T][E] : fminf(m2v[T][E], (V)); \
      m1v[T][E] = b ? (V) : m1v[T][E]; \
      j1v[T][E] = b ? cd : j1v[T][E]; }
    {
      float v0 = fmaf(-2.f, aA0[0] + aB0[0], kv);
      float v1 = fmaf(-2.f, aA0[1] + aB0[1], kv);
      float v2 = fmaf(-2.f, aA0[2] + aB0[2], kv);
      float v3 = fmaf(-2.f, aA0[3] + aB0[3], kv);
      UPD(0, 0, v0) UPD(0, 1, v1) UPD(0, 2, v2) UPD(0, 3, v3)
      float u0 = fmaf(-2.f, aA1[0] + aB1[0], kv);
      float u1 = fmaf(-2.f, aA1[1] + aB1[1], kv);
      float u2 = fmaf(-2.f, aA1[2] + aB1[2], kv);
      float u3 = fmaf(-2.f, aA1[3] + aB1[3], kv);
      UPD(1, 0, u0) UPD(1, 1, u1) UPD(1, 2, u2) UPD(1, 3, u3)
    }
#undef UPD
  }

#pragma unroll
  for (int T = 0; T < 2; ++T)
#pragma unroll
    for (int e = 0; e < 4; ++e) {
      float m1 = m1v[T][e], m2 = m2v[T][e];
      int j1 = j1v[T][e];
#pragma unroll
      for (int d = 1; d < 16; d <<= 1) {
        float om1 = __shfl_xor(m1, d, 64);
        float om2 = __shfl_xor(m2, d, 64);
        int oj = __shfl_xor(j1, d, 64);
        bool take = (om1 < m1) || (om1 == m1 && oj < j1);
        float loser = take ? m1 : om1;
        m2 = fminf(fminf(m2, om2), loser);
        m1 = take ? om1 : m1;
        j1 = take ? oj : j1;
      }
      if (col == 0) {
        int row = blockIdx.x * 128 + wave * 32 + T * 16 + grp * 4 + e;
        ((float*)(wsb + M1_OFF))[row] = m1;
        ((float*)(wsb + M2_OFF))[row] = m2;
        ((int*)(wsb + J1_OFF))[row] = j1;
      }
    }
}

// ---------- K2: per-row finalize: verify j1, epilogue, flag + compact rescans ----------
__global__ __launch_bounds__(256, 4)
void vq_fin(const float* __restrict__ x, const float* __restrict__ k,
            float* __restrict__ out, char* __restrict__ wsb) {
  __shared__ double sred[16];
  const int tid = threadIdx.x;
  const int row = blockIdx.x * 256 + tid;
  const int n = row >> 13;
  const int t = row & (TD - 1);

  float m1r = ((const float*)(wsb + M1_OFF))[row];
  float m2r = ((const float*)(wsb + M2_OFF))[row];
  int j1r = ((const int*)(wsb + J1_OFF))[row];

  const float* xr = x + ((size_t)n * WD) * TD + t;
#define LOADX(w) float x##w = xr[(size_t)(w) * TD];
  REP64(LOADX)
#undef LOADX

  NP_SUMSQ64_NAMED(s)

  double xsum = 0.0, xsumsq = 0.0;
#define PRE(w) { double xd = (double)x##w; xsum += xd; xsumsq = fma(xd, xd, xsumsq); }
  REP64(PRE)
#undef PRE

  const float* kbr = k + (size_t)j1r * WD;
  float* xo = out + OFF_XD + ((size_t)n * WD) * TD + t;
  double commit = 0.0;
  float g = 0.f;
#define EPI(w) { \
    float kw = kbr[w]; \
    float diff = __fsub_rn(kw, x##w); \
    commit = fma((double)diff, (double)diff, commit); \
    g = __fmaf_rn(x##w, kw, g); \
    xo[(size_t)(w) * TD] = __fadd_rn(x##w, diff); }
  REP64(EPI)
#undef EPI

  float kn2j = ((const float*)(wsb + KN2_OFF))[j1r];
  float score = kn2j - 2.f * g;
  bool resc = (m2r - m1r < EPS_GAP) || (fabsf(score - m1r) > VEPS);
  float dist1 = __fadd_rn(__fsub_rn(s, __fmul_rn(2.f, g)), kn2j);

  out[OFF_XL + row] = (float)j1r;
  if (resc) {
    unsigned idx = atomicAdd((unsigned*)(wsb + CNT_OFF), 1u);
    ((int*)(wsb + LIST_OFF))[idx] = row;
    if (idx < XRCAP) {                                    // compact row for rescan
      float* xrw = (float*)(wsb + XR_OFF) + (size_t)idx * WD;
#define XWR(w) xrw[w] = x##w;
      REP64(XWR)
#undef XWR
    }
  }

  double v0 = xsum, v1 = xsumsq;
  double v2 = resc ? 0.0 : (double)dist1;
  double v3 = resc ? 0.0 : commit;
#pragma unroll
  for (int off = 32; off > 0; off >>= 1) {
    v0 += __shfl_down(v0, off, 64);
    v1 += __shfl_down(v1, off, 64);
    v2 += __shfl_down(v2, off, 64);
    v3 += __shfl_down(v3, off, 64);
  }
  if ((tid & 63) == 0) {
    int wv = tid >> 6;
    sred[wv * 4 + 0] = v0;
    sred[wv * 4 + 1] = v1;
    sred[wv * 4 + 2] = v2;
    sred[wv * 4 + 3] = v3;
  }
  __syncthreads();
  if (tid == 0) {
    double a0 = 0, a1 = 0, a2 = 0, a3 = 0;
#pragma unroll
    for (int w2 = 0; w2 < 4; ++w2) {
      a0 += sred[w2 * 4 + 0];
      a1 += sred[w2 * 4 + 1];
      a2 += sred[w2 * 4 + 2];
      a3 += sred[w2 * 4 + 3];
    }
    double* red = (double*)(wsb + RED_OFF);
    atomicAdd(&red[0], a0);
    atomicAdd(&red[1], a1);
    atomicAdd(&red[2], a2);
    atomicAdd(&red[3], a3);
  }
}

// ---------- K3: exact rescan, 4 rows/block, NO per-row atomics ----------
// r12 diagnosis: 5.8k same-address f64 atomicAdds serialize at the L2 bank
// (~70cyc each = ~170us queue drain = the entire kernel duration; r11 and r12
// identical despite 4x traffic change). Fix: write per-slot fitv/cmv arrays
// (each slot written once, no contention); vq_final reduces them.
__global__ __launch_bounds__(256)
void vq_rescan7(const float* __restrict__ x, const float* __restrict__ k,
                float* __restrict__ out, char* __restrict__ wsb) {
  __shared__ float xs[4][WD];
  __shared__ float ss[4];
  __shared__ unsigned long long wred[4][4];   // [row][wave]
  __shared__ unsigned long long bbest[4];
  const unsigned count = *(const unsigned*)(wsb + CNT_OFF);
  const int* list = (const int*)(wsb + LIST_OFF);
  const float* kn2 = (const float*)(wsb + KN2_OFF);
  const float* XR = (const float*)(wsb + XR_OFF);
  const float* kT = (const float*)(wsb + KT_OFF);
  double* fitv = (double*)(wsb + FITV_OFF);
  double* cmv = (double*)(wsb + CMV_OFF);
  const int tid = threadIdx.x;
  const int lane = tid & 63, wv = tid >> 6;
  const int c0 = tid * 8;

  for (unsigned base = blockIdx.x * 4u; base < count; base += gridDim.x * 4u) {
    __syncthreads();                       // xs/ss/wred reuse guard
    {                                      // stage up to 4 rows (256 thr = 4x64)
      const int r = tid >> 6, w = tid & 63;
      const unsigned li = base + (unsigned)r;
      if (li < count) {
        if (li < XRCAP) {
          xs[r][w] = XR[(size_t)li * WD + w];
        } else {
          const int row = list[li];
          const int n = row >> 13, t = row & (TD - 1);
          xs[r][w] = x[(size_t)n * WD * TD + (size_t)w * TD + t];
        }
      }
    }
    __syncthreads();
    if (lane == 0) ss[wv] = np_sumsq64_ptr(xs[wv]);   // 1x per row (wave-uniform)
    __syncthreads();
    const float s0 = ss[0], s1 = ss[1], s2 = ss[2], s3 = ss[3];

    float a00 = 0.f, a01 = 0.f, a02 = 0.f, a03 = 0.f, a04 = 0.f, a05 = 0.f, a06 = 0.f, a07 = 0.f;
    float a10 = 0.f, a11 = 0.f, a12 = 0.f, a13 = 0.f, a14 = 0.f, a15 = 0.f, a16 = 0.f, a17 = 0.f;
    float a20 = 0.f, a21 = 0.f, a22 = 0.f, a23 = 0.f, a24 = 0.f, a25 = 0.f, a26 = 0.f, a27 = 0.f;
    float a30 = 0.f, a31 = 0.f, a32 = 0.f, a33 = 0.f, a34 = 0.f, a35 = 0.f, a36 = 0.f, a37 = 0.f;
    const float* kt = kT + c0;
#pragma unroll 4
    for (int w = 0; w < WD; ++w) {
      const float4 ka = *(const float4*)(kt + (size_t)w * KB);
      const float4 kb = *(const float4*)(kt + (size_t)w * KB + 4);
      const float xw0 = xs[0][w], xw1 = xs[1][w], xw2 = xs[2][w], xw3 = xs[3][w];
      a00 = __fmaf_rn(xw0, ka.x, a00); a01 = __fmaf_rn(xw0, ka.y, a01);
      a02 = __fmaf_rn(xw0, ka.z, a02); a03 = __fmaf_rn(xw0, ka.w, a03);
      a04 = __fmaf_rn(xw0, kb.x, a04); a05 = __fmaf_rn(xw0, kb.y, a05);
      a06 = __fmaf_rn(xw0, kb.z, a06); a07 = __fmaf_rn(xw0, kb.w, a07);
      a10 = __fmaf_rn(xw1, ka.x, a10); a11 = __fmaf_rn(xw1, ka.y, a11);
      a12 = __fmaf_rn(xw1, ka.z, a12); a13 = __fmaf_rn(xw1, ka.w, a13);
      a14 = __fmaf_rn(xw1, kb.x, a14); a15 = __fmaf_rn(xw1, kb.y, a15);
      a16 = __fmaf_rn(xw1, kb.z, a16); a17 = __fmaf_rn(xw1, kb.w, a17);
      a20 = __fmaf_rn(xw2, ka.x, a20); a21 = __fmaf_rn(xw2, ka.y, a21);
      a22 = __fmaf_rn(xw2, ka.z, a22); a23 = __fmaf_rn(xw2, ka.w, a23);
      a24 = __fmaf_rn(xw2, kb.x, a24); a25 = __fmaf_rn(xw2, kb.y, a25);
      a26 = __fmaf_rn(xw2, kb.z, a26); a27 = __fmaf_rn(xw2, kb.w, a27);
      a30 = __fmaf_rn(xw3, ka.x, a30); a31 = __fmaf_rn(xw3, ka.y, a31);
      a32 = __fmaf_rn(xw3, ka.z, a32); a33 = __fmaf_rn(xw3, ka.w, a33);
      a34 = __fmaf_rn(xw3, kb.x, a34); a35 = __fmaf_rn(xw3, kb.y, a35);
      a36 = __fmaf_rn(xw3, kb.z, a36); a37 = __fmaf_rn(xw3, kb.w, a37);
    }

    // per-row packed argmin over this thread's 8 codes, then wave reduce
#define ROWBEST(R, SV, A0, A1, A2, A3, A4, A5, A6, A7) { \
      unsigned long long best = ~0ull; \
      float d; unsigned long long p; \
      d = __fadd_rn(__fsub_rn(SV, __fmul_rn(2.f, A0)), kn2[c0 + 0]); \
      p = ((unsigned long long)__float_as_uint(d) << 32) | (unsigned)(c0 + 0); best = p < best ? p : best; \
      d = __fadd_rn(__fsub_rn(SV, __fmul_rn(2.f, A1)), kn2[c0 + 1]); \
      p = ((unsigned long long)__float_as_uint(d) << 32) | (unsigned)(c0 + 1); best = p < best ? p : best; \
      d = __fadd_rn(__fsub_rn(SV, __fmul_rn(2.f, A2)), kn2[c0 + 2]); \
      p = ((unsigned long long)__float_as_uint(d) << 32) | (unsigned)(c0 + 2); best = p < best ? p : best; \
      d = __fadd_rn(__fsub_rn(SV, __fmul_rn(2.f, A3)), kn2[c0 + 3]); \
      p = ((unsigned long long)__float_as_uint(d) << 32) | (unsigned)(c0 + 3); best = p < best ? p : best; \
      d = __fadd_rn(__fsub_rn(SV, __fmul_rn(2.f, A4)), kn2[c0 + 4]); \
      p = ((unsigned long long)__float_as_uint(d) << 32) | (unsigned)(c0 + 4); best = p < best ? p : best; \
      d = __fadd_rn(__fsub_rn(SV, __fmul_rn(2.f, A5)), kn2[c0 + 5]); \
      p = ((unsigned long long)__float_as_uint(d) << 32) | (unsigned)(c0 + 5); best = p < best ? p : best; \
      d = __fadd_rn(__fsub_rn(SV, __fmul_rn(2.f, A6)), kn2[c0 + 6]); \
      p = ((unsigned long long)__float_as_uint(d) << 32) | (unsigned)(c0 + 6); best = p < best ? p : best; \
      d = __fadd_rn(__fsub_rn(SV, __fmul_rn(2.f, A7)), kn2[c0 + 7]); \
      p = ((unsigned long long)__float_as_uint(d) << 32) | (unsigned)(c0 + 7); best = p < best ? p : best; \
      _Pragma("unroll") \
      for (int dd = 1; dd < 64; dd <<= 1) { \
        unsigned lo = (unsigned)best, hi = (unsigned)(best >> 32); \
        unsigned olo = __shfl_xor(lo, dd, 64); \
        unsigned ohi = __shfl_xor(hi, dd, 64); \
        unsigned long long o = ((unsigned long long)ohi << 32) | olo; \
        best = o < best ? o : best; \
      } \
      if (lane == 0) wred[R][wv] = best; }
    ROWBEST(0, s0, a00, a01, a02, a03, a04, a05, a06, a07)
    ROWBEST(1, s1, a10, a11, a12, a13, a14, a15, a16, a17)
    ROWBEST(2, s2, a20, a21, a22, a23, a24, a25, a26, a27)
    ROWBEST(3, s3, a30, a31, a32, a33, a34, a35, a36, a37)
#undef ROWBEST
    __syncthreads();
    if (tid < 4) {
      unsigned long long b = wred[tid][0];
      b = wred[tid][1] < b ? wred[tid][1] : b;
      b = wred[tid][2] < b ? wred[tid][2] : b;
      b = wred[tid][3] < b ? wred[tid][3] : b;
      bbest[tid] = b;
    }
    __syncthreads();

    // epilogue: wave wv handles row base+wv, lane = w (one wave per row)
    {
      const int r = wv, w = lane;
      const unsigned li = base + (unsigned)r;
      if (li < count) {
        const int row = list[li];
        const int n = row >> 13, t = row & (TD - 1);
        const unsigned long long fb = bbest[r];
        const int bi = (int)(fb & 0xffffffffu);
        const float bv = __uint_as_float((unsigned)(fb >> 32));
        float kw = k[(size_t)bi * WD + w];
        float xw = xs[r][w];
        float diff = __fsub_rn(kw, xw);
        out[OFF_XD + (size_t)n * WD * TD + (size_t)w * TD + t] = __fadd_rn(xw, diff);
        double d2 = (double)diff * (double)diff;
#pragma unroll
        for (int dd = 32; dd > 0; dd >>= 1) d2 += __shfl_down(d2, dd, 64);
        if (w == 0) {
          out[OFF_XL + row] = (float)bi;
          fitv[li] = (double)bv;           // plain store, no contention
          cmv[li] = d2;
        }
      }
    }
  }
}

// ---------- K4: final scalars — reduce rescan arrays + red[] ----------
__global__ __launch_bounds__(256)
void vq_final(const char* __restrict__ wsb, float* __restrict__ out) {
  __shared__ double sred[8];
  const unsigned count = *(const unsigned*)(wsb + CNT_OFF);
  const double* fitv = (const double*)(wsb + FITV_OFF);
  const double* cmv = (const double*)(wsb + CMV_OFF);
  const double* red = (const double*)(wsb + RED_OFF);
  const int tid = threadIdx.x;

  double fa = 0.0, ca = 0.0;
  for (unsigned i = tid; i < count; i += 256) {
    fa += fitv[i];
    ca += cmv[i];
  }
#pragma unroll
  for (int off = 32; off > 0; off >>= 1) {
    fa += __shfl_down(fa, off, 64);
    ca += __shfl_down(ca, off, 64);
  }
  if ((tid & 63) == 0) {
    sred[(tid >> 6) * 2 + 0] = fa;
    sred[(tid >> 6) * 2 + 1] = ca;
  }
  __syncthreads();
  if (tid == 0) {
    double fit = red[2], cm = red[3];
#pragma unroll
    for (int i = 0; i < 4; ++i) {
      fit += sred[i * 2 + 0];
      cm += sred[i * 2 + 1];
    }
    double sum = red[0], sumsq = red[1];
    double mean = sum / 8388608.0;
    double ss = sumsq - sum * mean;
    if (ss < 0.0) ss = 0.0;
    out[OFF_SC + 0] = (float)(cm / 8388608.0);         // commit_loss
    out[OFF_SC + 1] = (float)(fit / 131072.0);         // fit
    out[OFF_SC + 2] = (float)sqrt(ss / 8388608.0);     // prenorm
  }
}

extern "C" void kernel_launch(void* const* d_in, const int* in_sizes, int n_in,
                              void* d_out, int out_size, void* d_ws, size_t ws_size,
                              hipStream_t stream) {
  const float* x = (const float*)d_in[0];
  const float* k = (const float*)d_in[1];
  float* out = (float*)d_out;
  char* wsb = (char*)d_ws;

  hipMemsetAsync(d_ws, 0, 64, stream);                 // red[4] + count
  vq_prep<<<KB / 256, 256, 0, stream>>>(k, wsb);
  vq_scan<<<NT / 128, 256, 0, stream>>>(x, wsb);
  vq_fin<<<NT / 256, 256, 0, stream>>>(x, k, out, wsb);
  vq_rescan7<<<1024, 256, 0, stream>>>(x, k, out, wsb);
  vq_final<<<1, 256, 0, stream>>>(wsb, out);
}

// Round 14
// 245.376 us; speedup vs baseline: 1.4763x; 1.0022x over previous
//
#include <hip/hip_runtime.h>
#include <math.h>

#define WD 64
#define TD 8192
#define NT 131072           // 16 * 8192 rows
#define KB 2048
// Output layout (float32, concatenated): x_l [NT], x_d [NT*WD], commit, fit, prenorm
#define OFF_XL 0
#define OFF_XD NT
#define OFF_SC (NT + NT * WD)

// ws layout (bytes)
#define RED_OFF   0                      // double[4]: xsum, xsumsq, fit, commit
#define CNT_OFF   32                     // uint: rescan count
#define KN2_OFF   4096                   // float[2048] np-exact ||k||^2
#define CB_OFF    16384                  // bf16 B-frags: 128jt * 4frag * 64lane * 16B = 512KB
#define M1_OFF    (16384 + 524288)       // float[NT]
#define M2_OFF    (M1_OFF + 4 * NT)      // float[NT]
#define J1_OFF    (M2_OFF + 4 * NT)      // int[NT]
#define LIST_OFF  (J1_OFF + 4 * NT)      // int[NT] rescan rows
#define KT_OFF    (LIST_OFF + 4 * NT)    // float[64][2048] transposed codebook (512KB)
#define XR_OFF    (KT_OFF + 8 * NT)      // float[XRCAP][64] compacted rescan rows (8MB)
#define FITV_OFF  (XR_OFF + XRCAP * WD * 4)  // double[NT] per-rescan-slot min dist
#define CMV_OFF   (FITV_OFF + 8 * NT)        // double[NT] per-rescan-slot commit part
#define XRCAP     32768                  // cap (count ~2.9k observed r5-r13)

#define EPS_GAP 4e-3f    // approx top-2 gap below this -> exact rescan (~2% rows)
#define VEPS    2e-3f    // |approx score(j1) - exact score(j1)| above this -> rescan (~0)

typedef __attribute__((ext_vector_type(8))) short bf16x8_t;  // 8 bf16 (4 VGPRs)
typedef __attribute__((ext_vector_type(4))) float f32x4_t;

__device__ __forceinline__ unsigned short bf16_rne(float f) {
  unsigned int u = __float_as_uint(f);
  unsigned int r = u + 0x7fffu + ((u >> 16) & 1u);
  return (unsigned short)(r >> 16);
}

#define REP64(F) F(0) F(1) F(2) F(3) F(4) F(5) F(6) F(7) \
  F(8) F(9) F(10) F(11) F(12) F(13) F(14) F(15) \
  F(16) F(17) F(18) F(19) F(20) F(21) F(22) F(23) \
  F(24) F(25) F(26) F(27) F(28) F(29) F(30) F(31) \
  F(32) F(33) F(34) F(35) F(36) F(37) F(38) F(39) \
  F(40) F(41) F(42) F(43) F(44) F(45) F(46) F(47) \
  F(48) F(49) F(50) F(51) F(52) F(53) F(54) F(55) \
  F(56) F(57) F(58) F(59) F(60) F(61) F(62) F(63)

// numpy pairwise_sum (scalar 8-accumulator, n=64) of PRE-ROUNDED squares; *_rn
// intrinsics forbid contraction. Bit-exact vs np.sum(a*a, -1) (verified r2-r13).
#define NP_SUMSQ64_NAMED(SVAR) \
  float r0 = __fmul_rn(x0, x0); \
  float r1 = __fmul_rn(x1, x1); \
  float r2 = __fmul_rn(x2, x2); \
  float r3 = __fmul_rn(x3, x3); \
  float r4 = __fmul_rn(x4, x4); \
  float r5 = __fmul_rn(x5, x5); \
  float r6 = __fmul_rn(x6, x6); \
  float r7 = __fmul_rn(x7, x7); \
  SQ8(8, 9, 10, 11, 12, 13, 14, 15) \
  SQ8(16, 17, 18, 19, 20, 21, 22, 23) \
  SQ8(24, 25, 26, 27, 28, 29, 30, 31) \
  SQ8(32, 33, 34, 35, 36, 37, 38, 39) \
  SQ8(40, 41, 42, 43, 44, 45, 46, 47) \
  SQ8(48, 49, 50, 51, 52, 53, 54, 55) \
  SQ8(56, 57, 58, 59, 60, 61, 62, 63) \
  const float SVAR = __fadd_rn(__fadd_rn(__fadd_rn(r0, r1), __fadd_rn(r2, r3)), \
                               __fadd_rn(__fadd_rn(r4, r5), __fadd_rn(r6, r7)));
#define SQ8(a,b,c,d,e,f,g,h) \
  r0 = __fadd_rn(r0, __fmul_rn(x##a, x##a)); \
  r1 = __fadd_rn(r1, __fmul_rn(x##b, x##b)); \
  r2 = __fadd_rn(r2, __fmul_rn(x##c, x##c)); \
  r3 = __fadd_rn(r3, __fmul_rn(x##d, x##d)); \
  r4 = __fadd_rn(r4, __fmul_rn(x##e, x##e)); \
  r5 = __fadd_rn(r5, __fmul_rn(x##f, x##f)); \
  r6 = __fadd_rn(r6, __fmul_rn(x##g, x##g)); \
  r7 = __fadd_rn(r7, __fmul_rn(x##h, x##h));

__device__ __forceinline__ float np_sumsq64_ptr(const float* a) {
  float r0 = __fmul_rn(a[0], a[0]);
  float r1 = __fmul_rn(a[1], a[1]);
  float r2 = __fmul_rn(a[2], a[2]);
  float r3 = __fmul_rn(a[3], a[3]);
  float r4 = __fmul_rn(a[4], a[4]);
  float r5 = __fmul_rn(a[5], a[5]);
  float r6 = __fmul_rn(a[6], a[6]);
  float r7 = __fmul_rn(a[7], a[7]);
#pragma unroll
  for (int i = 8; i < 64; i += 8) {
    r0 = __fadd_rn(r0, __fmul_rn(a[i + 0], a[i + 0]));
    r1 = __fadd_rn(r1, __fmul_rn(a[i + 1], a[i + 1]));
    r2 = __fadd_rn(r2, __fmul_rn(a[i + 2], a[i + 2]));
    r3 = __fadd_rn(r3, __fmul_rn(a[i + 3], a[i + 3]));
    r4 = __fadd_rn(r4, __fmul_rn(a[i + 4], a[i + 4]));
    r5 = __fadd_rn(r5, __fmul_rn(a[i + 5], a[i + 5]));
    r6 = __fadd_rn(r6, __fmul_rn(a[i + 6], a[i + 6]));
    r7 = __fadd_rn(r7, __fmul_rn(a[i + 7], a[i + 7]));
  }
  float t01 = __fadd_rn(r0, r1);
  float t23 = __fadd_rn(r2, r3);
  float t45 = __fadd_rn(r4, r5);
  float t67 = __fadd_rn(r6, r7);
  return __fadd_rn(__fadd_rn(t01, t23), __fadd_rn(t45, t67));
}

// ---------- K0: kn2_np + bf16 B-frags + transposed codebook kT[w][c] ----------
__global__ __launch_bounds__(256)
void vq_prep(const float* __restrict__ k, char* __restrict__ wsb) {
  int c = blockIdx.x * 256 + threadIdx.x;
  if (c >= KB) return;
  const float* kr = k + (size_t)c * WD;
  ((float*)(wsb + KN2_OFF))[c] = np_sumsq64_ptr(kr);
  float* kt = (float*)(wsb + KT_OFF);
#pragma unroll
  for (int w = 0; w < WD; ++w) kt[(size_t)w * KB + c] = kr[w];
  int jt = c >> 4, col = c & 15;
  unsigned short* cb = (unsigned short*)(wsb + CB_OFF);
#pragma unroll
  for (int w = 0; w < WD; ++w) {
    float f = kr[w];
    unsigned short hb = bf16_rne(f);
    float hf = __uint_as_float((unsigned int)hb << 16);
    unsigned short lb = bf16_rne(f - hf);
    int fH = w >> 5;                       // K-half: frag 0/1 (hi), 2/3 (lo)
    int lane = col | (((w >> 3) & 3) << 4);
    int e = w & 7;
    cb[((size_t)((jt * 4 + fH) * 64 + lane)) * 8 + e] = hb;
    cb[((size_t)((jt * 4 + 2 + fH) * 64 + lane)) * 8 + e] = lb;
  }
}

// ---------- K1: MFMA bf16x3 score scan, LDS-staged codebook ----------
// r13 diagnosis: each wave privately streamed the full 512KB B-frag table from
// L2 (4096 waves x 512KB = 2.1GB, ~60us of L2 BW + exposed latency). Fix:
// double-buffered LDS chunks (4 jt = 16KB), reg-prefetch pipeline, 1 barrier
// per chunk. Also chain K-halves into one MFMA accumulator per tile (saves the
// aA+aB adds; approx path only -> rescan set shifts slightly, still exact).
__global__ __launch_bounds__(256)
void vq_scan(const float* __restrict__ x, char* __restrict__ wsb) {
  __shared__ float lkn2[KB];          // 8KB
  __shared__ char cbuf[2][16384];     // 32KB: 2 x (4 jt x 4 frag x 64 lane x 16B)
  for (int i = threadIdx.x; i < KB; i += 256)
    lkn2[i] = ((const float*)(wsb + KN2_OFF))[i];

  const int tid = threadIdx.x, lane = tid & 63, wave = tid >> 6;
  const int col = lane & 15, grp = lane >> 4;
  const int n = blockIdx.x >> 6;           // 64 blocks per n (8192/128)
  const int t0 = (blockIdx.x & 63) * 128;
  const float* xb = x + (size_t)n * WD * TD;

  bf16x8_t aH[2][2], aL[2][2];             // [tile][k-step]
#pragma unroll
  for (int T = 0; T < 2; ++T) {
    int trow = t0 + wave * 32 + T * 16 + col;
#pragma unroll
    for (int s = 0; s < 2; ++s) {
#pragma unroll
      for (int e = 0; e < 8; ++e) {
        int w = s * 32 + grp * 8 + e;
        float f = xb[(size_t)w * TD + trow];
        unsigned short hb = bf16_rne(f);
        float hf = __uint_as_float((unsigned int)hb << 16);
        unsigned short lb = bf16_rne(f - hf);
        aH[T][s][e] = (short)hb;
        aL[T][s][e] = (short)lb;
      }
    }
  }

  float m1v[2][4], m2v[2][4];
  int j1v[2][4];
#pragma unroll
  for (int T = 0; T < 2; ++T)
#pragma unroll
    for (int e = 0; e < 4; ++e) {
      m1v[T][e] = INFINITY; m2v[T][e] = INFINITY; j1v[T][e] = 0;
    }

  const char* cbsrc = wsb + CB_OFF;
  float4 pf0, pf1, pf2, pf3;
#define PREF(c) { const float4* sp = (const float4*)(cbsrc + (size_t)(c) * 16384); \
    pf0 = sp[tid]; pf1 = sp[tid + 256]; pf2 = sp[tid + 512]; pf3 = sp[tid + 768]; }
#define WRBUF(b) { float4* dp = (float4*)cbuf[b]; \
    dp[tid] = pf0; dp[tid + 256] = pf1; dp[tid + 512] = pf2; dp[tid + 768] = pf3; }

  PREF(0)
  WRBUF(0)
  PREF(1)
  __syncthreads();                         // chunk0 visible + lkn2 + A-frags done

  const f32x4_t zero4 = {0.f, 0.f, 0.f, 0.f};
  for (int c = 0; c < 32; ++c) {
    const int cur = c & 1;
    // 1. write prefetched chunk c+1 -> other buffer (safe: its readers done at
    //    the barrier ending iter c-1); 2. prefetch chunk c+2
    if (c < 31) WRBUF(cur ^ 1)
    if (c < 30) PREF(c + 2)
    // 3. process 4 jt from buf[cur]
#pragma unroll
    for (int jl = 0; jl < 4; ++jl) {
      const bf16x8_t* bp = (const bf16x8_t*)(cbuf[cur] + jl * 4096) + lane;
      bf16x8_t bH0 = bp[0], bH1 = bp[64], bL0 = bp[128], bL1 = bp[192];
      const int jt = c * 4 + jl;
      float kv = lkn2[jt * 16 + col];
      // one 6-deep chain per tile (K-halves chained; no cross-acc adds)
      f32x4_t acc0 = __builtin_amdgcn_mfma_f32_16x16x32_bf16(aH[0][0], bH0, zero4, 0, 0, 0);
      f32x4_t acc1 = __builtin_amdgcn_mfma_f32_16x16x32_bf16(aH[1][0], bH0, zero4, 0, 0, 0);
      acc0 = __builtin_amdgcn_mfma_f32_16x16x32_bf16(aH[0][1], bH1, acc0, 0, 0, 0);
      acc1 = __builtin_amdgcn_mfma_f32_16x16x32_bf16(aH[1][1], bH1, acc1, 0, 0, 0);
      acc0 = __builtin_amdgcn_mfma_f32_16x16x32_bf16(aL[0][0], bH0, acc0, 0, 0, 0);
      acc1 = __builtin_amdgcn_mfma_f32_16x16x32_bf16(aL[1][0], bH0, acc1, 0, 0, 0);
      acc0 = __builtin_amdgcn_mfma_f32_16x16x32_bf16(aL[0][1], bH1, acc0, 0, 0, 0);
      acc1 = __builtin_amdgcn_mfma_f32_16x16x32_bf16(aL[1][1], bH1, acc1, 0, 0, 0);
      acc0 = __builtin_amdgcn_mfma_f32_16x16x32_bf16(aH[0][0], bL0, acc0, 0, 0, 0);
      acc1 = __builtin_amdgcn_mfma_f32_16x16x32_bf16(aH[1][0], bL0, acc1, 0, 0, 0);
      acc0 = __builtin_amdgcn_mfma_f32_16x16x32_bf16(aH[0][1], bL1, acc0, 0, 0, 0);
      acc1 = __builtin_amdgcn_mfma_f32_16x16x32_bf16(aH[1][1], bL1, acc1, 0, 0, 0);

      const int cd = jt * 16 + col;
#define UPD(T, E, V) { bool b = (V) < m1v[T][E]; \
        m2v[T][E] = b ? m1v[T][E] : fminf(m2v[T][E], (V)); \
        m1v[T][E] = b ? (V) : m1v[T][E]; \
        j1v[T][E] = b ? cd : j1v[T][E]; }
      {
        float v0 = fmaf(-2.f, acc0[0], kv);
        float v1 = fmaf(-2.f, acc0[1], kv);
        float v2 = fmaf(-2.f, acc0[2], kv);
        float v3 = fmaf(-2.f, acc0[3], kv);
        UPD(0, 0, v0) UPD(0, 1, v1) UPD(0, 2, v2) UPD(0, 3, v3)
        float u0 = fmaf(-2.f, acc1[0], kv);
        float u1 = fmaf(-2.f, acc1[1], kv);
        float u2 = fmaf(-2.f, acc1[2], kv);
        float u3 = fmaf(-2.f, acc1[3], kv);
        UPD(1, 0, u0) UPD(1, 1, u1) UPD(1, 2, u2) UPD(1, 3, u3)
      }
#undef UPD
    }
    // 4. barrier: chunk c+1 writes visible; buf[cur] free for reuse next iter
    __syncthreads();
  }
#undef PREF
#undef WRBUF

#pragma unroll
  for (int T = 0; T < 2; ++T)
#pragma unroll
    for (int e = 0; e < 4; ++e) {
      float m1 = m1v[T][e], m2 = m2v[T][e];
      int j1 = j1v[T][e];
#pragma unroll
      for (int d = 1; d < 16; d <<= 1) {
        float om1 = __shfl_xor(m1, d, 64);
        float om2 = __shfl_xor(m2, d, 64);
        int oj = __shfl_xor(j1, d, 64);
        bool take = (om1 < m1) || (om1 == m1 && oj < j1);
        float loser = take ? m1 : om1;
        m2 = fminf(fminf(m2, om2), loser);
        m1 = take ? om1 : m1;
        j1 = take ? oj : j1;
      }
      if (col == 0) {
        int row = blockIdx.x * 128 + wave * 32 + T * 16 + grp * 4 + e;
        ((float*)(wsb + M1_OFF))[row] = m1;
        ((float*)(wsb + M2_OFF))[row] = m2;
        ((int*)(wsb + J1_OFF))[row] = j1;
      }
    }
}

// ---------- K2: per-row finalize: verify j1, epilogue, flag + compact rescans ----------
__global__ __launch_bounds__(256, 4)
void vq_fin(const float* __restrict__ x, const float* __restrict__ k,
            float* __restrict__ out, char* __restrict__ wsb) {
  __shared__ double sred[16];
  const int tid = threadIdx.x;
  const int row = blockIdx.x * 256 + tid;
  const int n = row >> 13;
  const int t = row & (TD - 1);

  float m1r = ((const float*)(wsb + M1_OFF))[row];
  float m2r = ((const float*)(wsb + M2_OFF))[row];
  int j1r = ((const int*)(wsb + J1_OFF))[row];

  const float* xr = x + ((size_t)n * WD) * TD + t;
#define LOADX(w) float x##w = xr[(size_t)(w) * TD];
  REP64(LOADX)
#undef LOADX

  NP_SUMSQ64_NAMED(s)

  double xsum = 0.0, xsumsq = 0.0;
#define PRE(w) { double xd = (double)x##w; xsum += xd; xsumsq = fma(xd, xd, xsumsq); }
  REP64(PRE)
#undef PRE

  const float* kbr = k + (size_t)j1r * WD;
  float* xo = out + OFF_XD + ((size_t)n * WD) * TD + t;
  double commit = 0.0;
  float g = 0.f;
#define EPI(w) { \
    float kw = kbr[w]; \
    float diff = __fsub_rn(kw, x##w); \
    commit = fma((double)diff, (double)diff, commit); \
    g = __fmaf_rn(x##w, kw, g); \
    xo[(size_t)(w) * TD] = __fadd_rn(x##w, diff); }
  REP64(EPI)
#undef EPI

  float kn2j = ((const float*)(wsb + KN2_OFF))[j1r];
  float score = kn2j - 2.f * g;
  bool resc = (m2r - m1r < EPS_GAP) || (fabsf(score - m1r) > VEPS);
  float dist1 = __fadd_rn(__fsub_rn(s, __fmul_rn(2.f, g)), kn2j);

  out[OFF_XL + row] = (float)j1r;
  if (resc) {
    unsigned idx = atomicAdd((unsigned*)(wsb + CNT_OFF), 1u);
    ((int*)(wsb + LIST_OFF))[idx] = row;
    if (idx < XRCAP) {                                    // compact row for rescan
      float* xrw = (float*)(wsb + XR_OFF) + (size_t)idx * WD;
#define XWR(w) xrw[w] = x##w;
      REP64(XWR)
#undef XWR
    }
  }

  double v0 = xsum, v1 = xsumsq;
  double v2 = resc ? 0.0 : (double)dist1;
  double v3 = resc ? 0.0 : commit;
#pragma unroll
  for (int off = 32; off > 0; off >>= 1) {
    v0 += __shfl_down(v0, off, 64);
    v1 += __shfl_down(v1, off, 64);
    v2 += __shfl_down(v2, off, 64);
    v3 += __shfl_down(v3, off, 64);
  }
  if ((tid & 63) == 0) {
    int wv = tid >> 6;
    sred[wv * 4 + 0] = v0;
    sred[wv * 4 + 1] = v1;
    sred[wv * 4 + 2] = v2;
    sred[wv * 4 + 3] = v3;
  }
  __syncthreads();
  if (tid == 0) {
    double a0 = 0, a1 = 0, a2 = 0, a3 = 0;
#pragma unroll
    for (int w2 = 0; w2 < 4; ++w2) {
      a0 += sred[w2 * 4 + 0];
      a1 += sred[w2 * 4 + 1];
      a2 += sred[w2 * 4 + 2];
      a3 += sred[w2 * 4 + 3];
    }
    double* red = (double*)(wsb + RED_OFF);
    atomicAdd(&red[0], a0);
    atomicAdd(&red[1], a1);
    atomicAdd(&red[2], a2);
    atomicAdd(&red[3], a3);
  }
}

// ---------- K3: exact rescan, 4 rows/block, per-slot results (no hot atomics) ----------
__global__ __launch_bounds__(256)
void vq_rescan7(const float* __restrict__ x, const float* __restrict__ k,
                float* __restrict__ out, char* __restrict__ wsb) {
  __shared__ float xs[4][WD];
  __shared__ float ss[4];
  __shared__ unsigned long long wred[4][4];   // [row][wave]
  __shared__ unsigned long long bbest[4];
  const unsigned count = *(const unsigned*)(wsb + CNT_OFF);
  const int* list = (const int*)(wsb + LIST_OFF);
  const float* kn2 = (const float*)(wsb + KN2_OFF);
  const float* XR = (const float*)(wsb + XR_OFF);
  const float* kT = (const float*)(wsb + KT_OFF);
  double* fitv = (double*)(wsb + FITV_OFF);
  double* cmv = (double*)(wsb + CMV_OFF);
  const int tid = threadIdx.x;
  const int lane = tid & 63, wv = tid >> 6;
  const int c0 = tid * 8;

  for (unsigned base = blockIdx.x * 4u; base < count; base += gridDim.x * 4u) {
    __syncthreads();                       // xs/ss/wred reuse guard
    {                                      // stage up to 4 rows (256 thr = 4x64)
      const int r = tid >> 6, w = tid & 63;
      const unsigned li = base + (unsigned)r;
      if (li < count) {
        if (li < XRCAP) {
          xs[r][w] = XR[(size_t)li * WD + w];
        } else {
          const int row = list[li];
          const int n = row >> 13, t = row & (TD - 1);
          xs[r][w] = x[(size_t)n * WD * TD + (size_t)w * TD + t];
        }
      }
    }
    __syncthreads();
    if (lane == 0) ss[wv] = np_sumsq64_ptr(xs[wv]);   // 1x per row (wave-uniform)
    __syncthreads();
    const float s0 = ss[0], s1 = ss[1], s2 = ss[2], s3 = ss[3];

    float a00 = 0.f, a01 = 0.f, a02 = 0.f, a03 = 0.f, a04 = 0.f, a05 = 0.f, a06 = 0.f, a07 = 0.f;
    float a10 = 0.f, a11 = 0.f, a12 = 0.f, a13 = 0.f, a14 = 0.f, a15 = 0.f, a16 = 0.f, a17 = 0.f;
    float a20 = 0.f, a21 = 0.f, a22 = 0.f, a23 = 0.f, a24 = 0.f, a25 = 0.f, a26 = 0.f, a27 = 0.f;
    float a30 = 0.f, a31 = 0.f, a32 = 0.f, a33 = 0.f, a34 = 0.f, a35 = 0.f, a36 = 0.f, a37 = 0.f;
    const float* kt = kT + c0;
#pragma unroll 4
    for (int w = 0; w < WD; ++w) {
      const float4 ka = *(const float4*)(kt + (size_t)w * KB);
      const float4 kb = *(const float4*)(kt + (size_t)w * KB + 4);
      const float xw0 = xs[0][w], xw1 = xs[1][w], xw2 = xs[2][w], xw3 = xs[3][w];
      a00 = __fmaf_rn(xw0, ka.x, a00); a01 = __fmaf_rn(xw0, ka.y, a01);
      a02 = __fmaf_rn(xw0, ka.z, a02); a03 = __fmaf_rn(xw0, ka.w, a03);
      a04 = __fmaf_rn(xw0, kb.x, a04); a05 = __fmaf_rn(xw0, kb.y, a05);
      a06 = __fmaf_rn(xw0, kb.z, a06); a07 = __fmaf_rn(xw0, kb.w, a07);
      a10 = __fmaf_rn(xw1, ka.x, a10); a11 = __fmaf_rn(xw1, ka.y, a11);
      a12 = __fmaf_rn(xw1, ka.z, a12); a13 = __fmaf_rn(xw1, ka.w, a13);
      a14 = __fmaf_rn(xw1, kb.x, a14); a15 = __fmaf_rn(xw1, kb.y, a15);
      a16 = __fmaf_rn(xw1, kb.z, a16); a17 = __fmaf_rn(xw1, kb.w, a17);
      a20 = __fmaf_rn(xw2, ka.x, a20); a21 = __fmaf_rn(xw2, ka.y, a21);
      a22 = __fmaf_rn(xw2, ka.z, a22); a23 = __fmaf_rn(xw2, ka.w, a23);
      a24 = __fmaf_rn(xw2, kb.x, a24); a25 = __fmaf_rn(xw2, kb.y, a25);
      a26 = __fmaf_rn(xw2, kb.z, a26); a27 = __fmaf_rn(xw2, kb.w, a27);
      a30 = __fmaf_rn(xw3, ka.x, a30); a31 = __fmaf_rn(xw3, ka.y, a31);
      a32 = __fmaf_rn(xw3, ka.z, a32); a33 = __fmaf_rn(xw3, ka.w, a33);
      a34 = __fmaf_rn(xw3, kb.x, a34); a35 = __fmaf_rn(xw3, kb.y, a35);
      a36 = __fmaf_rn(xw3, kb.z, a36); a37 = __fmaf_rn(xw3, kb.w, a37);
    }

#define ROWBEST(R, SV, A0, A1, A2, A3, A4, A5, A6, A7) { \
      unsigned long long best = ~0ull; \
      float d; unsigned long long p; \
      d = __fadd_rn(__fsub_rn(SV, __fmul_rn(2.f, A0)), kn2[c0 + 0]); \
      p = ((unsigned long long)__float_as_uint(d) << 32) | (unsigned)(c0 + 0); best = p < best ? p : best; \
      d = __fadd_rn(__fsub_rn(SV, __fmul_rn(2.f, A1)), kn2[c0 + 1]); \
      p = ((unsigned long long)__float_as_uint(d) << 32) | (unsigned)(c0 + 1); best = p < best ? p : best; \
      d = __fadd_rn(__fsub_rn(SV, __fmul_rn(2.f, A2)), kn2[c0 + 2]); \
      p = ((unsigned long long)__float_as_uint(d) << 32) | (unsigned)(c0 + 2); best = p < best ? p : best; \
      d = __fadd_rn(__fsub_rn(SV, __fmul_rn(2.f, A3)), kn2[c0 + 3]); \
      p = ((unsigned long long)__float_as_uint(d) << 32) | (unsigned)(c0 + 3); best = p < best ? p : best; \
      d = __fadd_rn(__fsub_rn(SV, __fmul_rn(2.f, A4)), kn2[c0 + 4]); \
      p = ((unsigned long long)__float_as_uint(d) << 32) | (unsigned)(c0 + 4); best = p < best ? p : best; \
      d = __fadd_rn(__fsub_rn(SV, __fmul_rn(2.f, A5)), kn2[c0 + 5]); \
      p = ((unsigned long long)__float_as_uint(d) << 32) | (unsigned)(c0 + 5); best = p < best ? p : best; \
      d = __fadd_rn(__fsub_rn(SV, __fmul_rn(2.f, A6)), kn2[c0 + 6]); \
      p = ((unsigned long long)__float_as_uint(d) << 32) | (unsigned)(c0 + 6); best = p < best ? p : best; \
      d = __fadd_rn(__fsub_rn(SV, __fmul_rn(2.f, A7)), kn2[c0 + 7]); \
      p = ((unsigned long long)__float_as_uint(d) << 32) | (unsigned)(c0 + 7); best = p < best ? p : best; \
      _Pragma("unroll") \
      for (int dd = 1; dd < 64; dd <<= 1) { \
        unsigned lo = (unsigned)best, hi = (unsigned)(best >> 32); \
        unsigned olo = __shfl_xor(lo, dd, 64); \
        unsigned ohi = __shfl_xor(hi, dd, 64); \
        unsigned long long o = ((unsigned long long)ohi << 32) | olo; \
        best = o < best ? o : best; \
      } \
      if (lane == 0) wred[R][wv] = best; }
    ROWBEST(0, s0, a00, a01, a02, a03, a04, a05, a06, a07)
    ROWBEST(1, s1, a10, a11, a12, a13, a14, a15, a16, a17)
    ROWBEST(2, s2, a20, a21, a22, a23, a24, a25, a26, a27)
    ROWBEST(3, s3, a30, a31, a32, a33, a34, a35, a36, a37)
#undef ROWBEST
    __syncthreads();
    if (tid < 4) {
      unsigned long long b = wred[tid][0];
      b = wred[tid][1] < b ? wred[tid][1] : b;
      b = wred[tid][2] < b ? wred[tid][2] : b;
      b = wred[tid][3] < b ? wred[tid][3] : b;
      bbest[tid] = b;
    }
    __syncthreads();

    // epilogue: wave wv handles row base+wv, lane = w (one wave per row)
    {
      const int r = wv, w = lane;
      const unsigned li = base + (unsigned)r;
      if (li < count) {
        const int row = list[li];
        const int n = row >> 13, t = row & (TD - 1);
        const unsigned long long fb = bbest[r];
        const int bi = (int)(fb & 0xffffffffu);
        const float bv = __uint_as_float((unsigned)(fb >> 32));
        float kw = k[(size_t)bi * WD + w];
        float xw = xs[r][w];
        float diff = __fsub_rn(kw, xw);
        out[OFF_XD + (size_t)n * WD * TD + (size_t)w * TD + t] = __fadd_rn(xw, diff);
        double d2 = (double)diff * (double)diff;
#pragma unroll
        for (int dd = 32; dd > 0; dd >>= 1) d2 += __shfl_down(d2, dd, 64);
        if (w == 0) {
          out[OFF_XL + row] = (float)bi;
          fitv[li] = (double)bv;           // plain store, no contention
          cmv[li] = d2;
        }
      }
    }
  }
}

// ---------- K4: final scalars — reduce rescan arrays + red[] ----------
__global__ __launch_bounds__(256)
void vq_final(const char* __restrict__ wsb, float* __restrict__ out) {
  __shared__ double sred[8];
  const unsigned count = *(const unsigned*)(wsb + CNT_OFF);
  const double* fitv = (const double*)(wsb + FITV_OFF);
  const double* cmv = (const double*)(wsb + CMV_OFF);
  const double* red = (const double*)(wsb + RED_OFF);
  const int tid = threadIdx.x;

  double fa = 0.0, ca = 0.0;
  for (unsigned i = tid; i < count; i += 256) {
    fa += fitv[i];
    ca += cmv[i];
  }
#pragma unroll
  for (int off = 32; off > 0; off >>= 1) {
    fa += __shfl_down(fa, off, 64);
    ca += __shfl_down(ca, off, 64);
  }
  if ((tid & 63) == 0) {
    sred[(tid >> 6) * 2 + 0] = fa;
    sred[(tid >> 6) * 2 + 1] = ca;
  }
  __syncthreads();
  if (tid == 0) {
    double fit = red[2], cm = red[3];
#pragma unroll
    for (int i = 0; i < 4; ++i) {
      fit += sred[i * 2 + 0];
      cm += sred[i * 2 + 1];
    }
    double sum = red[0], sumsq = red[1];
    double mean = sum / 8388608.0;
    double ss = sumsq - sum * mean;
    if (ss < 0.0) ss = 0.0;
    out[OFF_SC + 0] = (float)(cm / 8388608.0);         // commit_loss
    out[OFF_SC + 1] = (float)(fit / 131072.0);         // fit
    out[OFF_SC + 2] = (float)sqrt(ss / 8388608.0);     // prenorm
  }
}

extern "C" void kernel_launch(void* const* d_in, const int* in_sizes, int n_in,
                              void* d_out, int out_size, void* d_ws, size_t ws_size,
                              hipStream_t stream) {
  const float* x = (const float*)d_in[0];
  const float* k = (const float*)d_in[1];
  float* out = (float*)d_out;
  char* wsb = (char*)d_ws;

  hipMemsetAsync(d_ws, 0, 64, stream);                 // red[4] + count
  vq_prep<<<KB / 256, 256, 0, stream>>>(k, wsb);
  vq_scan<<<NT / 128, 256, 0, stream>>>(x, wsb);
  vq_fin<<<NT / 256, 256, 0, stream>>>(x, k, out, wsb);
  vq_rescan7<<<1024, 256, 0, stream>>>(x, k, out, wsb);
  vq_final<<<1, 256, 0, stream>>>(wsb, out);
}

// Round 15
// 242.352 us; speedup vs baseline: 1.4947x; 1.0125x over previous
//
#include <hip/hip_runtime.h>
#include <math.h>

#define WD 64
#define TD 8192
#define NT 131072           // 16 * 8192 rows
#define KB 2048
// Output layout (float32, concatenated): x_l [NT], x_d [NT*WD], commit, fit, prenorm
#define OFF_XL 0
#define OFF_XD NT
#define OFF_SC (NT + NT * WD)

// ws layout (bytes)
#define RED_OFF   0                      // double[4]: xsum, xsumsq, fit, commit
#define CNT_OFF   32                     // uint: rescan count
#define KN2_OFF   4096                   // float[2048] np-exact ||k||^2
#define CB_OFF    16384                  // bf16 B-frags: 128jt * 4frag * 64lane * 16B = 512KB
#define M1_OFF    (16384 + 524288)       // float[NT]
#define M2_OFF    (M1_OFF + 4 * NT)      // float[NT]
#define J1_OFF    (M2_OFF + 4 * NT)      // int[NT]
#define LIST_OFF  (J1_OFF + 4 * NT)      // int[NT] rescan rows
#define KT_OFF    (LIST_OFF + 4 * NT)    // float[64][2048] transposed codebook (512KB)
#define XR_OFF    (KT_OFF + 8 * NT)      // float[XRCAP][64] compacted rescan rows (8MB)
#define FITV_OFF  (XR_OFF + XRCAP * WD * 4)  // double[NT] per-rescan-slot min dist
#define CMV_OFF   (FITV_OFF + 8 * NT)        // double[NT] per-rescan-slot commit part
#define XRCAP     32768                  // cap (count ~2.9k observed r5-r14)

#define EPS_GAP 4e-3f    // approx top-2 gap below this -> exact rescan (~2% rows)
#define VEPS    2e-3f    // |approx score(j1) - exact score(j1)| above this -> rescan (~0)

typedef __attribute__((ext_vector_type(8))) short bf16x8_t;  // 8 bf16 (4 VGPRs)
typedef __attribute__((ext_vector_type(4))) float f32x4_t;

__device__ __forceinline__ unsigned short bf16_rne(float f) {
  unsigned int u = __float_as_uint(f);
  unsigned int r = u + 0x7fffu + ((u >> 16) & 1u);
  return (unsigned short)(r >> 16);
}

#define REP64(F) F(0) F(1) F(2) F(3) F(4) F(5) F(6) F(7) \
  F(8) F(9) F(10) F(11) F(12) F(13) F(14) F(15) \
  F(16) F(17) F(18) F(19) F(20) F(21) F(22) F(23) \
  F(24) F(25) F(26) F(27) F(28) F(29) F(30) F(31) \
  F(32) F(33) F(34) F(35) F(36) F(37) F(38) F(39) \
  F(40) F(41) F(42) F(43) F(44) F(45) F(46) F(47) \
  F(48) F(49) F(50) F(51) F(52) F(53) F(54) F(55) \
  F(56) F(57) F(58) F(59) F(60) F(61) F(62) F(63)

// numpy pairwise_sum (scalar 8-accumulator, n=64) of PRE-ROUNDED squares; *_rn
// intrinsics forbid contraction. Bit-exact vs np.sum(a*a, -1) (verified r2-r14).
#define NP_SUMSQ64_NAMED(SVAR) \
  float r0 = __fmul_rn(x0, x0); \
  float r1 = __fmul_rn(x1, x1); \
  float r2 = __fmul_rn(x2, x2); \
  float r3 = __fmul_rn(x3, x3); \
  float r4 = __fmul_rn(x4, x4); \
  float r5 = __fmul_rn(x5, x5); \
  float r6 = __fmul_rn(x6, x6); \
  float r7 = __fmul_rn(x7, x7); \
  SQ8(8, 9, 10, 11, 12, 13, 14, 15) \
  SQ8(16, 17, 18, 19, 20, 21, 22, 23) \
  SQ8(24, 25, 26, 27, 28, 29, 30, 31) \
  SQ8(32, 33, 34, 35, 36, 37, 38, 39) \
  SQ8(40, 41, 42, 43, 44, 45, 46, 47) \
  SQ8(48, 49, 50, 51, 52, 53, 54, 55) \
  SQ8(56, 57, 58, 59, 60, 61, 62, 63) \
  const float SVAR = __fadd_rn(__fadd_rn(__fadd_rn(r0, r1), __fadd_rn(r2, r3)), \
                               __fadd_rn(__fadd_rn(r4, r5), __fadd_rn(r6, r7)));
#define SQ8(a,b,c,d,e,f,g,h) \
  r0 = __fadd_rn(r0, __fmul_rn(x##a, x##a)); \
  r1 = __fadd_rn(r1, __fmul_rn(x##b, x##b)); \
  r2 = __fadd_rn(r2, __fmul_rn(x##c, x##c)); \
  r3 = __fadd_rn(r3, __fmul_rn(x##d, x##d)); \
  r4 = __fadd_rn(r4, __fmul_rn(x##e, x##e)); \
  r5 = __fadd_rn(r5, __fmul_rn(x##f, x##f)); \
  r6 = __fadd_rn(r6, __fmul_rn(x##g, x##g)); \
  r7 = __fadd_rn(r7, __fmul_rn(x##h, x##h));

__device__ __forceinline__ float np_sumsq64_ptr(const float* a) {
  float r0 = __fmul_rn(a[0], a[0]);
  float r1 = __fmul_rn(a[1], a[1]);
  float r2 = __fmul_rn(a[2], a[2]);
  float r3 = __fmul_rn(a[3], a[3]);
  float r4 = __fmul_rn(a[4], a[4]);
  float r5 = __fmul_rn(a[5], a[5]);
  float r6 = __fmul_rn(a[6], a[6]);
  float r7 = __fmul_rn(a[7], a[7]);
#pragma unroll
  for (int i = 8; i < 64; i += 8) {
    r0 = __fadd_rn(r0, __fmul_rn(a[i + 0], a[i + 0]));
    r1 = __fadd_rn(r1, __fmul_rn(a[i + 1], a[i + 1]));
    r2 = __fadd_rn(r2, __fmul_rn(a[i + 2], a[i + 2]));
    r3 = __fadd_rn(r3, __fmul_rn(a[i + 3], a[i + 3]));
    r4 = __fadd_rn(r4, __fmul_rn(a[i + 4], a[i + 4]));
    r5 = __fadd_rn(r5, __fmul_rn(a[i + 5], a[i + 5]));
    r6 = __fadd_rn(r6, __fmul_rn(a[i + 6], a[i + 6]));
    r7 = __fadd_rn(r7, __fmul_rn(a[i + 7], a[i + 7]));
  }
  float t01 = __fadd_rn(r0, r1);
  float t23 = __fadd_rn(r2, r3);
  float t45 = __fadd_rn(r4, r5);
  float t67 = __fadd_rn(r6, r7);
  return __fadd_rn(__fadd_rn(t01, t23), __fadd_rn(t45, t67));
}

// ---------- K0: kn2_np + bf16 B-frags + transposed codebook kT[w][c] ----------
__global__ __launch_bounds__(256)
void vq_prep(const float* __restrict__ k, char* __restrict__ wsb) {
  int c = blockIdx.x * 256 + threadIdx.x;
  if (c >= KB) return;
  const float* kr = k + (size_t)c * WD;
  ((float*)(wsb + KN2_OFF))[c] = np_sumsq64_ptr(kr);
  float* kt = (float*)(wsb + KT_OFF);
#pragma unroll
  for (int w = 0; w < WD; ++w) kt[(size_t)w * KB + c] = kr[w];
  int jt = c >> 4, col = c & 15;
  unsigned short* cb = (unsigned short*)(wsb + CB_OFF);
#pragma unroll
  for (int w = 0; w < WD; ++w) {
    float f = kr[w];
    unsigned short hb = bf16_rne(f);
    float hf = __uint_as_float((unsigned int)hb << 16);
    unsigned short lb = bf16_rne(f - hf);
    int fH = w >> 5;                       // K-half: frag 0/1 (hi), 2/3 (lo)
    int lane = col | (((w >> 3) & 3) << 4);
    int e = w & 7;
    cb[((size_t)((jt * 4 + fH) * 64 + lane)) * 8 + e] = hb;
    cb[((size_t)((jt * 4 + 2 + fH) * 64 + lane)) * 8 + e] = lb;
  }
}

// ---------- K1: MFMA bf16x3 score scan, argmax domain, 8 waves ----------
// r13/r14 double-null -> bottleneck is the per-score VALU argmin (6 ops) at
// ~2 waves/SIMD. This version: (a) kn2 folded into MFMA C-init (acc = dot -
// kn2/2; argmax; *-2 once at writeout) kills the per-score fmaf; (b) med3
// second-max identity (M2=med3(M1,M2,v); M1=max) -> 4 ops/score; (c) 512-thr
// blocks, 1 tile/wave -> 32-waves/CU capacity for MFMA<->VALU overlap.
__global__ __launch_bounds__(512) __attribute__((amdgpu_waves_per_eu(4)))
void vq_scan(const float* __restrict__ x, char* __restrict__ wsb) {
  __shared__ float lkn2n[KB];         // 8KB: -0.5 * ||k||^2 (prescaled)
  __shared__ char cbuf[2][16384];     // 32KB: 2 x (4 jt x 4 frag x 64 lane x 16B)
  const int tid = threadIdx.x, lane = tid & 63, wave = tid >> 6;  // 8 waves
  const int col = lane & 15, grp = lane >> 4;

  for (int i = tid; i < KB; i += 512)
    lkn2n[i] = -0.5f * ((const float*)(wsb + KN2_OFF))[i];

  const int n = blockIdx.x >> 6;           // 64 blocks per n (8192/128)
  const int t0 = (blockIdx.x & 63) * 128;
  const float* xb = x + (size_t)n * WD * TD;

  // A-frags: wave owns ONE 16-row tile: rows t0 + wave*16 + (grp*4+e)
  bf16x8_t aH[2], aL[2];                   // [k-step]
  {
    const int trow = t0 + wave * 16 + col;
#pragma unroll
    for (int s = 0; s < 2; ++s) {
#pragma unroll
      for (int e = 0; e < 8; ++e) {
        int w = s * 32 + grp * 8 + e;
        float f = xb[(size_t)w * TD + trow];
        unsigned short hb = bf16_rne(f);
        float hf = __uint_as_float((unsigned int)hb << 16);
        unsigned short lb = bf16_rne(f - hf);
        aH[s][e] = (short)hb;
        aL[s][e] = (short)lb;
      }
    }
  }

  // argmax trackers in acc-domain (acc = dot - kn2/2; score = -2*acc)
  float M1[4], M2[4];
  int JT[4];
#pragma unroll
  for (int e = 0; e < 4; ++e) {
    M1[e] = -INFINITY; M2[e] = -INFINITY; JT[e] = 0;
  }

  const char* cbsrc = wsb + CB_OFF;
  float4 pf0, pf1;
#define PREF(c) { const float4* sp = (const float4*)(cbsrc + (size_t)(c) * 16384); \
    pf0 = sp[tid]; pf1 = sp[tid + 512]; }
#define WRBUF(b) { float4* dp = (float4*)cbuf[b]; \
    dp[tid] = pf0; dp[tid + 512] = pf1; }

  PREF(0)
  WRBUF(0)
  PREF(1)
  __syncthreads();                         // chunk0 + lkn2n visible

  for (int c = 0; c < 32; ++c) {
    const int cur = c & 1;
    if (c < 31) WRBUF(cur ^ 1)
    if (c < 30) PREF(c + 2)
#pragma unroll
    for (int jl = 0; jl < 4; ++jl) {
      const bf16x8_t* bp = (const bf16x8_t*)(cbuf[cur] + jl * 4096) + lane;
      bf16x8_t bH0 = bp[0], bH1 = bp[64], bL0 = bp[128], bL1 = bp[192];
      const int jt = c * 4 + jl;
      const float ci = lkn2n[jt * 16 + col];
      f32x4_t acc = {ci, ci, ci, ci};      // C-init = -kn2/2 (same col all 4 rows)
      acc = __builtin_amdgcn_mfma_f32_16x16x32_bf16(aH[0], bH0, acc, 0, 0, 0);
      acc = __builtin_amdgcn_mfma_f32_16x16x32_bf16(aH[1], bH1, acc, 0, 0, 0);
      acc = __builtin_amdgcn_mfma_f32_16x16x32_bf16(aL[0], bH0, acc, 0, 0, 0);
      acc = __builtin_amdgcn_mfma_f32_16x16x32_bf16(aL[1], bH1, acc, 0, 0, 0);
      acc = __builtin_amdgcn_mfma_f32_16x16x32_bf16(aH[0], bL0, acc, 0, 0, 0);
      acc = __builtin_amdgcn_mfma_f32_16x16x32_bf16(aH[1], bL1, acc, 0, 0, 0);
      // 4 ops/score: cmp, med3(second-max), max, cndmask(jt)
#pragma unroll
      for (int e = 0; e < 4; ++e) {
        float v = acc[e];
        bool b = v > M1[e];                            // strict: first-idx ties
        M2[e] = __builtin_amdgcn_fmed3f(M1[e], M2[e], v);
        M1[e] = fmaxf(M1[e], v);
        JT[e] = b ? jt : JT[e];
      }
    }
    __syncthreads();
  }
#undef PREF
#undef WRBUF

  // cross-lane reduce (max domain) + writeout in score domain (*-2)
#pragma unroll
  for (int e = 0; e < 4; ++e) {
    float m1 = M1[e], m2 = M2[e];
    int cd = JT[e] * 16 + col;
#pragma unroll
    for (int d = 1; d < 16; d <<= 1) {
      float om1 = __shfl_xor(m1, d, 64);
      float om2 = __shfl_xor(m2, d, 64);
      int ocd = __shfl_xor(cd, d, 64);
      bool take = (om1 > m1) || (om1 == m1 && ocd < cd);
      float loser = take ? m1 : om1;                   // smaller of the maxes
      m2 = fmaxf(fmaxf(m2, om2), loser);
      m1 = take ? om1 : m1;
      cd = take ? ocd : cd;
    }
    if (col == 0) {
      int row = blockIdx.x * 128 + wave * 16 + grp * 4 + e;
      ((float*)(wsb + M1_OFF))[row] = -2.f * m1;       // back to score domain
      ((float*)(wsb + M2_OFF))[row] = -2.f * m2;
      ((int*)(wsb + J1_OFF))[row] = cd;
    }
  }
}

// ---------- K2: per-row finalize: verify j1, epilogue, flag + compact rescans ----------
__global__ __launch_bounds__(256, 4)
void vq_fin(const float* __restrict__ x, const float* __restrict__ k,
            float* __restrict__ out, char* __restrict__ wsb) {
  __shared__ double sred[16];
  const int tid = threadIdx.x;
  const int row = blockIdx.x * 256 + tid;
  const int n = row >> 13;
  const int t = row & (TD - 1);

  float m1r = ((const float*)(wsb + M1_OFF))[row];
  float m2r = ((const float*)(wsb + M2_OFF))[row];
  int j1r = ((const int*)(wsb + J1_OFF))[row];

  const float* xr = x + ((size_t)n * WD) * TD + t;
#define LOADX(w) float x##w = xr[(size_t)(w) * TD];
  REP64(LOADX)
#undef LOADX

  NP_SUMSQ64_NAMED(s)

  double xsum = 0.0, xsumsq = 0.0;
#define PRE(w) { double xd = (double)x##w; xsum += xd; xsumsq = fma(xd, xd, xsumsq); }
  REP64(PRE)
#undef PRE

  const float* kbr = k + (size_t)j1r * WD;
  float* xo = out + OFF_XD + ((size_t)n * WD) * TD + t;
  double commit = 0.0;
  float g = 0.f;
#define EPI(w) { \
    float kw = kbr[w]; \
    float diff = __fsub_rn(kw, x##w); \
    commit = fma((double)diff, (double)diff, commit); \
    g = __fmaf_rn(x##w, kw, g); \
    xo[(size_t)(w) * TD] = __fadd_rn(x##w, diff); }
  REP64(EPI)
#undef EPI

  float kn2j = ((const float*)(wsb + KN2_OFF))[j1r];
  float score = kn2j - 2.f * g;
  bool resc = (m2r - m1r < EPS_GAP) || (fabsf(score - m1r) > VEPS);
  float dist1 = __fadd_rn(__fsub_rn(s, __fmul_rn(2.f, g)), kn2j);

  out[OFF_XL + row] = (float)j1r;
  if (resc) {
    unsigned idx = atomicAdd((unsigned*)(wsb + CNT_OFF), 1u);
    ((int*)(wsb + LIST_OFF))[idx] = row;
    if (idx < XRCAP) {                                    // compact row for rescan
      float* xrw = (float*)(wsb + XR_OFF) + (size_t)idx * WD;
#define XWR(w) xrw[w] = x##w;
      REP64(XWR)
#undef XWR
    }
  }

  double v0 = xsum, v1 = xsumsq;
  double v2 = resc ? 0.0 : (double)dist1;
  double v3 = resc ? 0.0 : commit;
#pragma unroll
  for (int off = 32; off > 0; off >>= 1) {
    v0 += __shfl_down(v0, off, 64);
    v1 += __shfl_down(v1, off, 64);
    v2 += __shfl_down(v2, off, 64);
    v3 += __shfl_down(v3, off, 64);
  }
  if ((tid & 63) == 0) {
    int wv = tid >> 6;
    sred[wv * 4 + 0] = v0;
    sred[wv * 4 + 1] = v1;
    sred[wv * 4 + 2] = v2;
    sred[wv * 4 + 3] = v3;
  }
  __syncthreads();
  if (tid == 0) {
    double a0 = 0, a1 = 0, a2 = 0, a3 = 0;
#pragma unroll
    for (int w2 = 0; w2 < 4; ++w2) {
      a0 += sred[w2 * 4 + 0];
      a1 += sred[w2 * 4 + 1];
      a2 += sred[w2 * 4 + 2];
      a3 += sred[w2 * 4 + 3];
    }
    double* red = (double*)(wsb + RED_OFF);
    atomicAdd(&red[0], a0);
    atomicAdd(&red[1], a1);
    atomicAdd(&red[2], a2);
    atomicAdd(&red[3], a3);
  }
}

// ---------- K3: exact rescan, 4 rows/block, per-slot results (no hot atomics) ----------
__global__ __launch_bounds__(256)
void vq_rescan7(const float* __restrict__ x, const float* __restrict__ k,
                float* __restrict__ out, char* __restrict__ wsb) {
  __shared__ float xs[4][WD];
  __shared__ float ss[4];
  __shared__ unsigned long long wred[4][4];   // [row][wave]
  __shared__ unsigned long long bbest[4];
  const unsigned count = *(const unsigned*)(wsb + CNT_OFF);
  const int* list = (const int*)(wsb + LIST_OFF);
  const float* kn2 = (const float*)(wsb + KN2_OFF);
  const float* XR = (const float*)(wsb + XR_OFF);
  const float* kT = (const float*)(wsb + KT_OFF);
  double* fitv = (double*)(wsb + FITV_OFF);
  double* cmv = (double*)(wsb + CMV_OFF);
  const int tid = threadIdx.x;
  const int lane = tid & 63, wv = tid >> 6;
  const int c0 = tid * 8;

  for (unsigned base = blockIdx.x * 4u; base < count; base += gridDim.x * 4u) {
    __syncthreads();                       // xs/ss/wred reuse guard
    {                                      // stage up to 4 rows (256 thr = 4x64)
      const int r = tid >> 6, w = tid & 63;
      const unsigned li = base + (unsigned)r;
      if (li < count) {
        if (li < XRCAP) {
          xs[r][w] = XR[(size_t)li * WD + w];
        } else {
          const int row = list[li];
          const int n = row >> 13, t = row & (TD - 1);
          xs[r][w] = x[(size_t)n * WD * TD + (size_t)w * TD + t];
        }
      }
    }
    __syncthreads();
    if (lane == 0) ss[wv] = np_sumsq64_ptr(xs[wv]);   // 1x per row (wave-uniform)
    __syncthreads();
    const float s0 = ss[0], s1 = ss[1], s2 = ss[2], s3 = ss[3];

    float a00 = 0.f, a01 = 0.f, a02 = 0.f, a03 = 0.f, a04 = 0.f, a05 = 0.f, a06 = 0.f, a07 = 0.f;
    float a10 = 0.f, a11 = 0.f, a12 = 0.f, a13 = 0.f, a14 = 0.f, a15 = 0.f, a16 = 0.f, a17 = 0.f;
    float a20 = 0.f, a21 = 0.f, a22 = 0.f, a23 = 0.f, a24 = 0.f, a25 = 0.f, a26 = 0.f, a27 = 0.f;
    float a30 = 0.f, a31 = 0.f, a32 = 0.f, a33 = 0.f, a34 = 0.f, a35 = 0.f, a36 = 0.f, a37 = 0.f;
    const float* kt = kT + c0;
#pragma unroll 4
    for (int w = 0; w < WD; ++w) {
      const float4 ka = *(const float4*)(kt + (size_t)w * KB);
      const float4 kb = *(const float4*)(kt + (size_t)w * KB + 4);
      const float xw0 = xs[0][w], xw1 = xs[1][w], xw2 = xs[2][w], xw3 = xs[3][w];
      a00 = __fmaf_rn(xw0, ka.x, a00); a01 = __fmaf_rn(xw0, ka.y, a01);
      a02 = __fmaf_rn(xw0, ka.z, a02); a03 = __fmaf_rn(xw0, ka.w, a03);
      a04 = __fmaf_rn(xw0, kb.x, a04); a05 = __fmaf_rn(xw0, kb.y, a05);
      a06 = __fmaf_rn(xw0, kb.z, a06); a07 = __fmaf_rn(xw0, kb.w, a07);
      a10 = __fmaf_rn(xw1, ka.x, a10); a11 = __fmaf_rn(xw1, ka.y, a11);
      a12 = __fmaf_rn(xw1, ka.z, a12); a13 = __fmaf_rn(xw1, ka.w, a13);
      a14 = __fmaf_rn(xw1, kb.x, a14); a15 = __fmaf_rn(xw1, kb.y, a15);
      a16 = __fmaf_rn(xw1, kb.z, a16); a17 = __fmaf_rn(xw1, kb.w, a17);
      a20 = __fmaf_rn(xw2, ka.x, a20); a21 = __fmaf_rn(xw2, ka.y, a21);
      a22 = __fmaf_rn(xw2, ka.z, a22); a23 = __fmaf_rn(xw2, ka.w, a23);
      a24 = __fmaf_rn(xw2, kb.x, a24); a25 = __fmaf_rn(xw2, kb.y, a25);
      a26 = __fmaf_rn(xw2, kb.z, a26); a27 = __fmaf_rn(xw2, kb.w, a27);
      a30 = __fmaf_rn(xw3, ka.x, a30); a31 = __fmaf_rn(xw3, ka.y, a31);
      a32 = __fmaf_rn(xw3, ka.z, a32); a33 = __fmaf_rn(xw3, ka.w, a33);
      a34 = __fmaf_rn(xw3, kb.x, a34); a35 = __fmaf_rn(xw3, kb.y, a35);
      a36 = __fmaf_rn(xw3, kb.z, a36); a37 = __fmaf_rn(xw3, kb.w, a37);
    }

#define ROWBEST(R, SV, A0, A1, A2, A3, A4, A5, A6, A7) { \
      unsigned long long best = ~0ull; \
      float d; unsigned long long p; \
      d = __fadd_rn(__fsub_rn(SV, __fmul_rn(2.f, A0)), kn2[c0 + 0]); \
      p = ((unsigned long long)__float_as_uint(d) << 32) | (unsigned)(c0 + 0); best = p < best ? p : best; \
      d = __fadd_rn(__fsub_rn(SV, __fmul_rn(2.f, A1)), kn2[c0 + 1]); \
      p = ((unsigned long long)__float_as_uint(d) << 32) | (unsigned)(c0 + 1); best = p < best ? p : best; \
      d = __fadd_rn(__fsub_rn(SV, __fmul_rn(2.f, A2)), kn2[c0 + 2]); \
      p = ((unsigned long long)__float_as_uint(d) << 32) | (unsigned)(c0 + 2); best = p < best ? p : best; \
      d = __fadd_rn(__fsub_rn(SV, __fmul_rn(2.f, A3)), kn2[c0 + 3]); \
      p = ((unsigned long long)__float_as_uint(d) << 32) | (unsigned)(c0 + 3); best = p < best ? p : best; \
      d = __fadd_rn(__fsub_rn(SV, __fmul_rn(2.f, A4)), kn2[c0 + 4]); \
      p = ((unsigned long long)__float_as_uint(d) << 32) | (unsigned)(c0 + 4); best = p < best ? p : best; \
      d = __fadd_rn(__fsub_rn(SV, __fmul_rn(2.f, A5)), kn2[c0 + 5]); \
      p = ((unsigned long long)__float_as_uint(d) << 32) | (unsigned)(c0 + 5); best = p < best ? p : best; \
      d = __fadd_rn(__fsub_rn(SV, __fmul_rn(2.f, A6)), kn2[c0 + 6]); \
      p = ((unsigned long long)__float_as_uint(d) << 32) | (unsigned)(c0 + 6); best = p < best ? p : best; \
      d = __fadd_rn(__fsub_rn(SV, __fmul_rn(2.f, A7)), kn2[c0 + 7]); \
      p = ((unsigned long long)__float_as_uint(d) << 32) | (unsigned)(c0 + 7); best = p < best ? p : best; \
      _Pragma("unroll") \
      for (int dd = 1; dd < 64; dd <<= 1) { \
        unsigned lo = (unsigned)best, hi = (unsigned)(best >> 32); \
        unsigned olo = __shfl_xor(lo, dd, 64); \
        unsigned ohi = __shfl_xor(hi, dd, 64); \
        unsigned long long o = ((unsigned long long)ohi << 32) | olo; \
        best = o < best ? o : best; \
      } \
      if (lane == 0) wred[R][wv] = best; }
    ROWBEST(0, s0, a00, a01, a02, a03, a04, a05, a06, a07)
    ROWBEST(1, s1, a10, a11, a12, a13, a14, a15, a16, a17)
    ROWBEST(2, s2, a20, a21, a22, a23, a24, a25, a26, a27)
    ROWBEST(3, s3, a30, a31, a32, a33, a34, a35, a36, a37)
#undef ROWBEST
    __syncthreads();
    if (tid < 4) {
      unsigned long long b = wred[tid][0];
      b = wred[tid][1] < b ? wred[tid][1] : b;
      b = wred[tid][2] < b ? wred[tid][2] : b;
      b = wred[tid][3] < b ? wred[tid][3] : b;
      bbest[tid] = b;
    }
    __syncthreads();

    // epilogue: wave wv handles row base+wv, lane = w (one wave per row)
    {
      const int r = wv, w = lane;
      const unsigned li = base + (unsigned)r;
      if (li < count) {
        const int row = list[li];
        const int n = row >> 13, t = row & (TD - 1);
        const unsigned long long fb = bbest[r];
        const int bi = (int)(fb & 0xffffffffu);
        const float bv = __uint_as_float((unsigned)(fb >> 32));
        float kw = k[(size_t)bi * WD + w];
        float xw = xs[r][w];
        float diff = __fsub_rn(kw, xw);
        out[OFF_XD + (size_t)n * WD * TD + (size_t)w * TD + t] = __fadd_rn(xw, diff);
        double d2 = (double)diff * (double)diff;
#pragma unroll
        for (int dd = 32; dd > 0; dd >>= 1) d2 += __shfl_down(d2, dd, 64);
        if (w == 0) {
          out[OFF_XL + row] = (float)bi;
          fitv[li] = (double)bv;           // plain store, no contention
          cmv[li] = d2;
        }
      }
    }
  }
}

// ---------- K4: final scalars — reduce rescan arrays + red[] ----------
__global__ __launch_bounds__(256)
void vq_final(const char* __restrict__ wsb, float* __restrict__ out) {
  __shared__ double sred[8];
  const unsigned count = *(const unsigned*)(wsb + CNT_OFF);
  const double* fitv = (const double*)(wsb + FITV_OFF);
  const double* cmv = (const double*)(wsb + CMV_OFF);
  const double* red = (const double*)(wsb + RED_OFF);
  const int tid = threadIdx.x;

  double fa = 0.0, ca = 0.0;
  for (unsigned i = tid; i < count; i += 256) {
    fa += fitv[i];
    ca += cmv[i];
  }
#pragma unroll
  for (int off = 32; off > 0; off >>= 1) {
    fa += __shfl_down(fa, off, 64);
    ca += __shfl_down(ca, off, 64);
  }
  if ((tid & 63) == 0) {
    sred[(tid >> 6) * 2 + 0] = fa;
    sred[(tid >> 6) * 2 + 1] = ca;
  }
  __syncthreads();
  if (tid == 0) {
    double fit = red[2], cm = red[3];
#pragma unroll
    for (int i = 0; i < 4; ++i) {
      fit += sred[i * 2 + 0];
      cm += sred[i * 2 + 1];
    }
    double sum = red[0], sumsq = red[1];
    double mean = sum / 8388608.0;
    double ss = sumsq - sum * mean;
    if (ss < 0.0) ss = 0.0;
    out[OFF_SC + 0] = (float)(cm / 8388608.0);         // commit_loss
    out[OFF_SC + 1] = (float)(fit / 131072.0);         // fit
    out[OFF_SC + 2] = (float)sqrt(ss / 8388608.0);     // prenorm
  }
}

extern "C" void kernel_launch(void* const* d_in, const int* in_sizes, int n_in,
                              void* d_out, int out_size, void* d_ws, size_t ws_size,
                              hipStream_t stream) {
  const float* x = (const float*)d_in[0];
  const float* k = (const float*)d_in[1];
  float* out = (float*)d_out;
  char* wsb = (char*)d_ws;

  hipMemsetAsync(d_ws, 0, 64, stream);                 // red[4] + count
  vq_prep<<<KB / 256, 256, 0, stream>>>(k, wsb);
  vq_scan<<<NT / 128, 512, 0, stream>>>(x, wsb);
  vq_fin<<<NT / 256, 256, 0, stream>>>(x, k, out, wsb);
  vq_rescan7<<<1024, 256, 0, stream>>>(x, k, out, wsb);
  vq_final<<<1, 256, 0, stream>>>(wsb, out);
}

// Round 16
// 234.481 us; speedup vs baseline: 1.5449x; 1.0336x over previous
//
#include <hip/hip_runtime.h>
#include <math.h>

#define WD 64
#define TD 8192
#define NT 131072           // 16 * 8192 rows
#define KB 2048
// Output layout (float32, concatenated): x_l [NT], x_d [NT*WD], commit, fit, prenorm
#define OFF_XL 0
#define OFF_XD NT
#define OFF_SC (NT + NT * WD)

// ws layout (bytes)
#define RED_OFF   0                      // double[4]: xsum, xsumsq, fit, commit
#define CNT_OFF   32                     // uint: rescan count
#define KN2_OFF   4096                   // float[2048] np-exact ||k||^2
#define CB_OFF    16384                  // bf16 B-frags: 128jt * 4frag * 64lane * 16B = 512KB
#define M1_OFF    (16384 + 524288)       // float[NT]
#define M2_OFF    (M1_OFF + 4 * NT)      // float[NT]
#define J1_OFF    (M2_OFF + 4 * NT)      // int[NT]
#define LIST_OFF  (J1_OFF + 4 * NT)      // int[NT] rescan rows
#define KT_OFF    (LIST_OFF + 4 * NT)    // float[64][2048] transposed codebook (512KB)
#define XR_OFF    (KT_OFF + 8 * NT)      // float[XRCAP][64] compacted rescan rows (8MB)
#define FITV_OFF  (XR_OFF + XRCAP * WD * 4)  // double[NT] per-rescan-slot min dist
#define CMV_OFF   (FITV_OFF + 8 * NT)        // double[NT] per-rescan-slot commit part
#define XRCAP     32768                  // cap (count ~2.9k observed r5-r15)

#define EPS_GAP 4e-3f    // approx top-2 gap below this -> exact rescan (~2% rows)
#define VEPS    2e-3f    // |approx score(j1) - exact score(j1)| above this -> rescan (~0)

typedef __attribute__((ext_vector_type(8))) short bf16x8_t;  // 8 bf16 (4 VGPRs)
typedef __attribute__((ext_vector_type(4))) float f32x4_t;

__device__ __forceinline__ unsigned short bf16_rne(float f) {
  unsigned int u = __float_as_uint(f);
  unsigned int r = u + 0x7fffu + ((u >> 16) & 1u);
  return (unsigned short)(r >> 16);
}

#define REP64(F) F(0) F(1) F(2) F(3) F(4) F(5) F(6) F(7) \
  F(8) F(9) F(10) F(11) F(12) F(13) F(14) F(15) \
  F(16) F(17) F(18) F(19) F(20) F(21) F(22) F(23) \
  F(24) F(25) F(26) F(27) F(28) F(29) F(30) F(31) \
  F(32) F(33) F(34) F(35) F(36) F(37) F(38) F(39) \
  F(40) F(41) F(42) F(43) F(44) F(45) F(46) F(47) \
  F(48) F(49) F(50) F(51) F(52) F(53) F(54) F(55) \
  F(56) F(57) F(58) F(59) F(60) F(61) F(62) F(63)

// numpy pairwise_sum (scalar 8-accumulator, n=64) of PRE-ROUNDED squares; *_rn
// intrinsics forbid contraction. Bit-exact vs np.sum(a*a, -1) (verified r2-r15).
#define NP_SUMSQ64_NAMED(SVAR) \
  float r0 = __fmul_rn(x0, x0); \
  float r1 = __fmul_rn(x1, x1); \
  float r2 = __fmul_rn(x2, x2); \
  float r3 = __fmul_rn(x3, x3); \
  float r4 = __fmul_rn(x4, x4); \
  float r5 = __fmul_rn(x5, x5); \
  float r6 = __fmul_rn(x6, x6); \
  float r7 = __fmul_rn(x7, x7); \
  SQ8(8, 9, 10, 11, 12, 13, 14, 15) \
  SQ8(16, 17, 18, 19, 20, 21, 22, 23) \
  SQ8(24, 25, 26, 27, 28, 29, 30, 31) \
  SQ8(32, 33, 34, 35, 36, 37, 38, 39) \
  SQ8(40, 41, 42, 43, 44, 45, 46, 47) \
  SQ8(48, 49, 50, 51, 52, 53, 54, 55) \
  SQ8(56, 57, 58, 59, 60, 61, 62, 63) \
  const float SVAR = __fadd_rn(__fadd_rn(__fadd_rn(r0, r1), __fadd_rn(r2, r3)), \
                               __fadd_rn(__fadd_rn(r4, r5), __fadd_rn(r6, r7)));
#define SQ8(a,b,c,d,e,f,g,h) \
  r0 = __fadd_rn(r0, __fmul_rn(x##a, x##a)); \
  r1 = __fadd_rn(r1, __fmul_rn(x##b, x##b)); \
  r2 = __fadd_rn(r2, __fmul_rn(x##c, x##c)); \
  r3 = __fadd_rn(r3, __fmul_rn(x##d, x##d)); \
  r4 = __fadd_rn(r4, __fmul_rn(x##e, x##e)); \
  r5 = __fadd_rn(r5, __fmul_rn(x##f, x##f)); \
  r6 = __fadd_rn(r6, __fmul_rn(x##g, x##g)); \
  r7 = __fadd_rn(r7, __fmul_rn(x##h, x##h));

__device__ __forceinline__ float np_sumsq64_ptr(const float* a) {
  float r0 = __fmul_rn(a[0], a[0]);
  float r1 = __fmul_rn(a[1], a[1]);
  float r2 = __fmul_rn(a[2], a[2]);
  float r3 = __fmul_rn(a[3], a[3]);
  float r4 = __fmul_rn(a[4], a[4]);
  float r5 = __fmul_rn(a[5], a[5]);
  float r6 = __fmul_rn(a[6], a[6]);
  float r7 = __fmul_rn(a[7], a[7]);
#pragma unroll
  for (int i = 8; i < 64; i += 8) {
    r0 = __fadd_rn(r0, __fmul_rn(a[i + 0], a[i + 0]));
    r1 = __fadd_rn(r1, __fmul_rn(a[i + 1], a[i + 1]));
    r2 = __fadd_rn(r2, __fmul_rn(a[i + 2], a[i + 2]));
    r3 = __fadd_rn(r3, __fmul_rn(a[i + 3], a[i + 3]));
    r4 = __fadd_rn(r4, __fmul_rn(a[i + 4], a[i + 4]));
    r5 = __fadd_rn(r5, __fmul_rn(a[i + 5], a[i + 5]));
    r6 = __fadd_rn(r6, __fmul_rn(a[i + 6], a[i + 6]));
    r7 = __fadd_rn(r7, __fmul_rn(a[i + 7], a[i + 7]));
  }
  float t01 = __fadd_rn(r0, r1);
  float t23 = __fadd_rn(r2, r3);
  float t45 = __fadd_rn(r4, r5);
  float t67 = __fadd_rn(r6, r7);
  return __fadd_rn(__fadd_rn(t01, t23), __fadd_rn(t45, t67));
}

// ---------- K0: kn2_np + bf16 B-frags + transposed codebook kT[w][c] ----------
__global__ __launch_bounds__(256)
void vq_prep(const float* __restrict__ k, char* __restrict__ wsb) {
  int c = blockIdx.x * 256 + threadIdx.x;
  if (c >= KB) return;
  const float* kr = k + (size_t)c * WD;
  ((float*)(wsb + KN2_OFF))[c] = np_sumsq64_ptr(kr);
  float* kt = (float*)(wsb + KT_OFF);
#pragma unroll
  for (int w = 0; w < WD; ++w) kt[(size_t)w * KB + c] = kr[w];
  int jt = c >> 4, col = c & 15;
  unsigned short* cb = (unsigned short*)(wsb + CB_OFF);
#pragma unroll
  for (int w = 0; w < WD; ++w) {
    float f = kr[w];
    unsigned short hb = bf16_rne(f);
    float hf = __uint_as_float((unsigned int)hb << 16);
    unsigned short lb = bf16_rne(f - hf);
    int fH = w >> 5;                       // K-half: frag 0/1 (hi), 2/3 (lo)
    int lane = col | (((w >> 3) & 3) << 4);
    int e = w & 7;
    cb[((size_t)((jt * 4 + fH) * 64 + lane)) * 8 + e] = hb;
    cb[((size_t)((jt * 4 + 2 + fH) * 64 + lane)) * 8 + e] = lb;
  }
}

// ---------- K1: MFMA bf16x3 score scan, 4 tiles/wave (B-reuse x4) ----------
// r15 diagnosis: invariant cost was B-fragment movement — each wave privately
// read 512KB (LDS 4.3GB total ~ 80us at b128 ceiling). Fix: wave owns FOUR
// 16-row tiles; same 4KB of B-frags per jt now feeds 24 MFMA (4 indep 6-deep
// chains). LDS traffic /4 (~20us); MFMA floor ~50us dominates. Keeps r15's
// argmax-domain kn2-folded C-init + med3 second-max (4 VALU/score).
__global__ __launch_bounds__(256) __attribute__((amdgpu_waves_per_eu(2)))
void vq_scan(const float* __restrict__ x, char* __restrict__ wsb) {
  __shared__ float lkn2n[KB];         // 8KB: -0.5 * ||k||^2 (prescaled)
  __shared__ char cbuf[2][16384];     // 32KB: 2 x (4 jt x 4 frag x 64 lane x 16B)
  const int tid = threadIdx.x, lane = tid & 63, wave = tid >> 6;  // 4 waves
  const int col = lane & 15, grp = lane >> 4;

  for (int i = tid; i < KB; i += 256)
    lkn2n[i] = -0.5f * ((const float*)(wsb + KN2_OFF))[i];

  const int n = blockIdx.x >> 5;           // 32 blocks per n (8192/256)
  const int t0 = (blockIdx.x & 31) * 256;
  const float* xb = x + (size_t)n * WD * TD;

  // A-frags: wave owns 4 tiles (64 rows): rows t0 + wave*64 + T*16 + (grp*4+e)
  bf16x8_t aH[4][2], aL[4][2];             // [tile][k-step], 64 VGPR
#pragma unroll
  for (int T = 0; T < 4; ++T) {
    const int trow = t0 + wave * 64 + T * 16 + col;
#pragma unroll
    for (int s = 0; s < 2; ++s) {
#pragma unroll
      for (int e = 0; e < 8; ++e) {
        int w = s * 32 + grp * 8 + e;
        float f = xb[(size_t)w * TD + trow];
        unsigned short hb = bf16_rne(f);
        float hf = __uint_as_float((unsigned int)hb << 16);
        unsigned short lb = bf16_rne(f - hf);
        aH[T][s][e] = (short)hb;
        aL[T][s][e] = (short)lb;
      }
    }
  }

  // argmax trackers in acc-domain (acc = dot - kn2/2; score = -2*acc)
  float M1[4][4], M2[4][4];
  int JT[4][4];
#pragma unroll
  for (int T = 0; T < 4; ++T)
#pragma unroll
    for (int e = 0; e < 4; ++e) {
      M1[T][e] = -INFINITY; M2[T][e] = -INFINITY; JT[T][e] = 0;
    }

  const char* cbsrc = wsb + CB_OFF;
  float4 pf0, pf1, pf2, pf3;
#define PREF(c) { const float4* sp = (const float4*)(cbsrc + (size_t)(c) * 16384); \
    pf0 = sp[tid]; pf1 = sp[tid + 256]; pf2 = sp[tid + 512]; pf3 = sp[tid + 768]; }
#define WRBUF(b) { float4* dp = (float4*)cbuf[b]; \
    dp[tid] = pf0; dp[tid + 256] = pf1; dp[tid + 512] = pf2; dp[tid + 768] = pf3; }

  PREF(0)
  WRBUF(0)
  PREF(1)
  __syncthreads();                         // chunk0 + lkn2n visible

  for (int c = 0; c < 32; ++c) {
    const int cur = c & 1;
    if (c < 31) WRBUF(cur ^ 1)
    if (c < 30) PREF(c + 2)
#pragma unroll
    for (int jl = 0; jl < 4; ++jl) {
      const bf16x8_t* bp = (const bf16x8_t*)(cbuf[cur] + jl * 4096) + lane;
      bf16x8_t bH0 = bp[0], bH1 = bp[64], bL0 = bp[128], bL1 = bp[192];
      const int jt = c * 4 + jl;
      const float ci = lkn2n[jt * 16 + col];
#pragma unroll
      for (int T = 0; T < 4; ++T) {
        f32x4_t acc = {ci, ci, ci, ci};    // C-init = -kn2/2 (same col, 4 rows)
        acc = __builtin_amdgcn_mfma_f32_16x16x32_bf16(aH[T][0], bH0, acc, 0, 0, 0);
        acc = __builtin_amdgcn_mfma_f32_16x16x32_bf16(aH[T][1], bH1, acc, 0, 0, 0);
        acc = __builtin_amdgcn_mfma_f32_16x16x32_bf16(aL[T][0], bH0, acc, 0, 0, 0);
        acc = __builtin_amdgcn_mfma_f32_16x16x32_bf16(aL[T][1], bH1, acc, 0, 0, 0);
        acc = __builtin_amdgcn_mfma_f32_16x16x32_bf16(aH[T][0], bL0, acc, 0, 0, 0);
        acc = __builtin_amdgcn_mfma_f32_16x16x32_bf16(aH[T][1], bL1, acc, 0, 0, 0);
        // 4 ops/score: cmp, med3(second-max), max, cndmask(jt)
#pragma unroll
        for (int e = 0; e < 4; ++e) {
          float v = acc[e];
          bool b = v > M1[T][e];                       // strict: first-idx ties
          M2[T][e] = __builtin_amdgcn_fmed3f(M1[T][e], M2[T][e], v);
          M1[T][e] = fmaxf(M1[T][e], v);
          JT[T][e] = b ? jt : JT[T][e];
        }
      }
    }
    __syncthreads();
  }
#undef PREF
#undef WRBUF

  // cross-lane reduce (max domain) + writeout in score domain (*-2)
#pragma unroll
  for (int T = 0; T < 4; ++T)
#pragma unroll
    for (int e = 0; e < 4; ++e) {
      float m1 = M1[T][e], m2 = M2[T][e];
      int cd = JT[T][e] * 16 + col;
#pragma unroll
      for (int d = 1; d < 16; d <<= 1) {
        float om1 = __shfl_xor(m1, d, 64);
        float om2 = __shfl_xor(m2, d, 64);
        int ocd = __shfl_xor(cd, d, 64);
        bool take = (om1 > m1) || (om1 == m1 && ocd < cd);
        float loser = take ? m1 : om1;                 // smaller of the maxes
        m2 = fmaxf(fmaxf(m2, om2), loser);
        m1 = take ? om1 : m1;
        cd = take ? ocd : cd;
      }
      if (col == 0) {
        int row = blockIdx.x * 256 + wave * 64 + T * 16 + grp * 4 + e;
        ((float*)(wsb + M1_OFF))[row] = -2.f * m1;     // back to score domain
        ((float*)(wsb + M2_OFF))[row] = -2.f * m2;
        ((int*)(wsb + J1_OFF))[row] = cd;
      }
    }
}

// ---------- K2: per-row finalize: verify j1, epilogue, flag + compact rescans ----------
__global__ __launch_bounds__(256, 4)
void vq_fin(const float* __restrict__ x, const float* __restrict__ k,
            float* __restrict__ out, char* __restrict__ wsb) {
  __shared__ double sred[16];
  const int tid = threadIdx.x;
  const int row = blockIdx.x * 256 + tid;
  const int n = row >> 13;
  const int t = row & (TD - 1);

  float m1r = ((const float*)(wsb + M1_OFF))[row];
  float m2r = ((const float*)(wsb + M2_OFF))[row];
  int j1r = ((const int*)(wsb + J1_OFF))[row];

  const float* xr = x + ((size_t)n * WD) * TD + t;
#define LOADX(w) float x##w = xr[(size_t)(w) * TD];
  REP64(LOADX)
#undef LOADX

  NP_SUMSQ64_NAMED(s)

  double xsum = 0.0, xsumsq = 0.0;
#define PRE(w) { double xd = (double)x##w; xsum += xd; xsumsq = fma(xd, xd, xsumsq); }
  REP64(PRE)
#undef PRE

  const float* kbr = k + (size_t)j1r * WD;
  float* xo = out + OFF_XD + ((size_t)n * WD) * TD + t;
  double commit = 0.0;
  float g = 0.f;
#define EPI(w) { \
    float kw = kbr[w]; \
    float diff = __fsub_rn(kw, x##w); \
    commit = fma((double)diff, (double)diff, commit); \
    g = __fmaf_rn(x##w, kw, g); \
    xo[(size_t)(w) * TD] = __fadd_rn(x##w, diff); }
  REP64(EPI)
#undef EPI

  float kn2j = ((const float*)(wsb + KN2_OFF))[j1r];
  float score = kn2j - 2.f * g;
  bool resc = (m2r - m1r < EPS_GAP) || (fabsf(score - m1r) > VEPS);
  float dist1 = __fadd_rn(__fsub_rn(s, __fmul_rn(2.f, g)), kn2j);

  out[OFF_XL + row] = (float)j1r;
  if (resc) {
    unsigned idx = atomicAdd((unsigned*)(wsb + CNT_OFF), 1u);
    ((int*)(wsb + LIST_OFF))[idx] = row;
    if (idx < XRCAP) {                                    // compact row for rescan
      float* xrw = (float*)(wsb + XR_OFF) + (size_t)idx * WD;
#define XWR(w) xrw[w] = x##w;
      REP64(XWR)
#undef XWR
    }
  }

  double v0 = xsum, v1 = xsumsq;
  double v2 = resc ? 0.0 : (double)dist1;
  double v3 = resc ? 0.0 : commit;
#pragma unroll
  for (int off = 32; off > 0; off >>= 1) {
    v0 += __shfl_down(v0, off, 64);
    v1 += __shfl_down(v1, off, 64);
    v2 += __shfl_down(v2, off, 64);
    v3 += __shfl_down(v3, off, 64);
  }
  if ((tid & 63) == 0) {
    int wv = tid >> 6;
    sred[wv * 4 + 0] = v0;
    sred[wv * 4 + 1] = v1;
    sred[wv * 4 + 2] = v2;
    sred[wv * 4 + 3] = v3;
  }
  __syncthreads();
  if (tid == 0) {
    double a0 = 0, a1 = 0, a2 = 0, a3 = 0;
#pragma unroll
    for (int w2 = 0; w2 < 4; ++w2) {
      a0 += sred[w2 * 4 + 0];
      a1 += sred[w2 * 4 + 1];
      a2 += sred[w2 * 4 + 2];
      a3 += sred[w2 * 4 + 3];
    }
    double* red = (double*)(wsb + RED_OFF);
    atomicAdd(&red[0], a0);
    atomicAdd(&red[1], a1);
    atomicAdd(&red[2], a2);
    atomicAdd(&red[3], a3);
  }
}

// ---------- K3: exact rescan, 4 rows/block, per-slot results (no hot atomics) ----------
__global__ __launch_bounds__(256)
void vq_rescan7(const float* __restrict__ x, const float* __restrict__ k,
                float* __restrict__ out, char* __restrict__ wsb) {
  __shared__ float xs[4][WD];
  __shared__ float ss[4];
  __shared__ unsigned long long wred[4][4];   // [row][wave]
  __shared__ unsigned long long bbest[4];
  const unsigned count = *(const unsigned*)(wsb + CNT_OFF);
  const int* list = (const int*)(wsb + LIST_OFF);
  const float* kn2 = (const float*)(wsb + KN2_OFF);
  const float* XR = (const float*)(wsb + XR_OFF);
  const float* kT = (const float*)(wsb + KT_OFF);
  double* fitv = (double*)(wsb + FITV_OFF);
  double* cmv = (double*)(wsb + CMV_OFF);
  const int tid = threadIdx.x;
  const int lane = tid & 63, wv = tid >> 6;
  const int c0 = tid * 8;

  for (unsigned base = blockIdx.x * 4u; base < count; base += gridDim.x * 4u) {
    __syncthreads();                       // xs/ss/wred reuse guard
    {                                      // stage up to 4 rows (256 thr = 4x64)
      const int r = tid >> 6, w = tid & 63;
      const unsigned li = base + (unsigned)r;
      if (li < count) {
        if (li < XRCAP) {
          xs[r][w] = XR[(size_t)li * WD + w];
        } else {
          const int row = list[li];
          const int n = row >> 13, t = row & (TD - 1);
          xs[r][w] = x[(size_t)n * WD * TD + (size_t)w * TD + t];
        }
      }
    }
    __syncthreads();
    if (lane == 0) ss[wv] = np_sumsq64_ptr(xs[wv]);   // 1x per row (wave-uniform)
    __syncthreads();
    const float s0 = ss[0], s1 = ss[1], s2 = ss[2], s3 = ss[3];

    float a00 = 0.f, a01 = 0.f, a02 = 0.f, a03 = 0.f, a04 = 0.f, a05 = 0.f, a06 = 0.f, a07 = 0.f;
    float a10 = 0.f, a11 = 0.f, a12 = 0.f, a13 = 0.f, a14 = 0.f, a15 = 0.f, a16 = 0.f, a17 = 0.f;
    float a20 = 0.f, a21 = 0.f, a22 = 0.f, a23 = 0.f, a24 = 0.f, a25 = 0.f, a26 = 0.f, a27 = 0.f;
    float a30 = 0.f, a31 = 0.f, a32 = 0.f, a33 = 0.f, a34 = 0.f, a35 = 0.f, a36 = 0.f, a37 = 0.f;
    const float* kt = kT + c0;
#pragma unroll 4
    for (int w = 0; w < WD; ++w) {
      const float4 ka = *(const float4*)(kt + (size_t)w * KB);
      const float4 kb = *(const float4*)(kt + (size_t)w * KB + 4);
      const float xw0 = xs[0][w], xw1 = xs[1][w], xw2 = xs[2][w], xw3 = xs[3][w];
      a00 = __fmaf_rn(xw0, ka.x, a00); a01 = __fmaf_rn(xw0, ka.y, a01);
      a02 = __fmaf_rn(xw0, ka.z, a02); a03 = __fmaf_rn(xw0, ka.w, a03);
      a04 = __fmaf_rn(xw0, kb.x, a04); a05 = __fmaf_rn(xw0, kb.y, a05);
      a06 = __fmaf_rn(xw0, kb.z, a06); a07 = __fmaf_rn(xw0, kb.w, a07);
      a10 = __fmaf_rn(xw1, ka.x, a10); a11 = __fmaf_rn(xw1, ka.y, a11);
      a12 = __fmaf_rn(xw1, ka.z, a12); a13 = __fmaf_rn(xw1, ka.w, a13);
      a14 = __fmaf_rn(xw1, kb.x, a14); a15 = __fmaf_rn(xw1, kb.y, a15);
      a16 = __fmaf_rn(xw1, kb.z, a16); a17 = __fmaf_rn(xw1, kb.w, a17);
      a20 = __fmaf_rn(xw2, ka.x, a20); a21 = __fmaf_rn(xw2, ka.y, a21);
      a22 = __fmaf_rn(xw2, ka.z, a22); a23 = __fmaf_rn(xw2, ka.w, a23);
      a24 = __fmaf_rn(xw2, kb.x, a24); a25 = __fmaf_rn(xw2, kb.y, a25);
      a26 = __fmaf_rn(xw2, kb.z, a26); a27 = __fmaf_rn(xw2, kb.w, a27);
      a30 = __fmaf_rn(xw3, ka.x, a30); a31 = __fmaf_rn(xw3, ka.y, a31);
      a32 = __fmaf_rn(xw3, ka.z, a32); a33 = __fmaf_rn(xw3, ka.w, a33);
      a34 = __fmaf_rn(xw3, kb.x, a34); a35 = __fmaf_rn(xw3, kb.y, a35);
      a36 = __fmaf_rn(xw3, kb.z, a36); a37 = __fmaf_rn(xw3, kb.w, a37);
    }

#define ROWBEST(R, SV, A0, A1, A2, A3, A4, A5, A6, A7) { \
      unsigned long long best = ~0ull; \
      float d; unsigned long long p; \
      d = __fadd_rn(__fsub_rn(SV, __fmul_rn(2.f, A0)), kn2[c0 + 0]); \
      p = ((unsigned long long)__float_as_uint(d) << 32) | (unsigned)(c0 + 0); best = p < best ? p : best; \
      d = __fadd_rn(__fsub_rn(SV, __fmul_rn(2.f, A1)), kn2[c0 + 1]); \
      p = ((unsigned long long)__float_as_uint(d) << 32) | (unsigned)(c0 + 1); best = p < best ? p : best; \
      d = __fadd_rn(__fsub_rn(SV, __fmul_rn(2.f, A2)), kn2[c0 + 2]); \
      p = ((unsigned long long)__float_as_uint(d) << 32) | (unsigned)(c0 + 2); best = p < best ? p : best; \
      d = __fadd_rn(__fsub_rn(SV, __fmul_rn(2.f, A3)), kn2[c0 + 3]); \
      p = ((unsigned long long)__float_as_uint(d) << 32) | (unsigned)(c0 + 3); best = p < best ? p : best; \
      d = __fadd_rn(__fsub_rn(SV, __fmul_rn(2.f, A4)), kn2[c0 + 4]); \
      p = ((unsigned long long)__float_as_uint(d) << 32) | (unsigned)(c0 + 4); best = p < best ? p : best; \
      d = __fadd_rn(__fsub_rn(SV, __fmul_rn(2.f, A5)), kn2[c0 + 5]); \
      p = ((unsigned long long)__float_as_uint(d) << 32) | (unsigned)(c0 + 5); best = p < best ? p : best; \
      d = __fadd_rn(__fsub_rn(SV, __fmul_rn(2.f, A6)), kn2[c0 + 6]); \
      p = ((unsigned long long)__float_as_uint(d) << 32) | (unsigned)(c0 + 6); best = p < best ? p : best; \
      d = __fadd_rn(__fsub_rn(SV, __fmul_rn(2.f, A7)), kn2[c0 + 7]); \
      p = ((unsigned long long)__float_as_uint(d) << 32) | (unsigned)(c0 + 7); best = p < best ? p : best; \
      _Pragma("unroll") \
      for (int dd = 1; dd < 64; dd <<= 1) { \
        unsigned lo = (unsigned)best, hi = (unsigned)(best >> 32); \
        unsigned olo = __shfl_xor(lo, dd, 64); \
        unsigned ohi = __shfl_xor(hi, dd, 64); \
        unsigned long long o = ((unsigned long long)ohi << 32) | olo; \
        best = o < best ? o : best; \
      } \
      if (lane == 0) wred[R][wv] = best; }
    ROWBEST(0, s0, a00, a01, a02, a03, a04, a05, a06, a07)
    ROWBEST(1, s1, a10, a11, a12, a13, a14, a15, a16, a17)
    ROWBEST(2, s2, a20, a21, a22, a23, a24, a25, a26, a27)
    ROWBEST(3, s3, a30, a31, a32, a33, a34, a35, a36, a37)
#undef ROWBEST
    __syncthreads();
    if (tid < 4) {
      unsigned long long b = wred[tid][0];
      b = wred[tid][1] < b ? wred[tid][1] : b;
      b = wred[tid][2] < b ? wred[tid][2] : b;
      b = wred[tid][3] < b ? wred[tid][3] : b;
      bbest[tid] = b;
    }
    __syncthreads();

    // epilogue: wave wv handles row base+wv, lane = w (one wave per row)
    {
      const int r = wv, w = lane;
      const unsigned li = base + (unsigned)r;
      if (li < count) {
        const int row = list[li];
        const int n = row >> 13, t = row & (TD - 1);
        const unsigned long long fb = bbest[r];
        const int bi = (int)(fb & 0xffffffffu);
        const float bv = __uint_as_float((unsigned)(fb >> 32));
        float kw = k[(size_t)bi * WD + w];
        float xw = xs[r][w];
        float diff = __fsub_rn(kw, xw);
        out[OFF_XD + (size_t)n * WD * TD + (size_t)w * TD + t] = __fadd_rn(xw, diff);
        double d2 = (double)diff * (double)diff;
#pragma unroll
        for (int dd = 32; dd > 0; dd >>= 1) d2 += __shfl_down(d2, dd, 64);
        if (w == 0) {
          out[OFF_XL + row] = (float)bi;
          fitv[li] = (double)bv;           // plain store, no contention
          cmv[li] = d2;
        }
      }
    }
  }
}

// ---------- K4: final scalars — reduce rescan arrays + red[] ----------
__global__ __launch_bounds__(256)
void vq_final(const char* __restrict__ wsb, float* __restrict__ out) {
  __shared__ double sred[8];
  const unsigned count = *(const unsigned*)(wsb + CNT_OFF);
  const double* fitv = (const double*)(wsb + FITV_OFF);
  const double* cmv = (const double*)(wsb + CMV_OFF);
  const double* red = (const double*)(wsb + RED_OFF);
  const int tid = threadIdx.x;

  double fa = 0.0, ca = 0.0;
  for (unsigned i = tid; i < count; i += 256) {
    fa += fitv[i];
    ca += cmv[i];
  }
#pragma unroll
  for (int off = 32; off > 0; off >>= 1) {
    fa += __shfl_down(fa, off, 64);
    ca += __shfl_down(ca, off, 64);
  }
  if ((tid & 63) == 0) {
    sred[(tid >> 6) * 2 + 0] = fa;
    sred[(tid >> 6) * 2 + 1] = ca;
  }
  __syncthreads();
  if (tid == 0) {
    double fit = red[2], cm = red[3];
#pragma unroll
    for (int i = 0; i < 4; ++i) {
      fit += sred[i * 2 + 0];
      cm += sred[i * 2 + 1];
    }
    double sum = red[0], sumsq = red[1];
    double mean = sum / 8388608.0;
    double ss = sumsq - sum * mean;
    if (ss < 0.0) ss = 0.0;
    out[OFF_SC + 0] = (float)(cm / 8388608.0);         // commit_loss
    out[OFF_SC + 1] = (float)(fit / 131072.0);         // fit
    out[OFF_SC + 2] = (float)sqrt(ss / 8388608.0);     // prenorm
  }
}

extern "C" void kernel_launch(void* const* d_in, const int* in_sizes, int n_in,
                              void* d_out, int out_size, void* d_ws, size_t ws_size,
                              hipStream_t stream) {
  const float* x = (const float*)d_in[0];
  const float* k = (const float*)d_in[1];
  float* out = (float*)d_out;
  char* wsb = (char*)d_ws;

  hipMemsetAsync(d_ws, 0, 64, stream);                 // red[4] + count
  vq_prep<<<KB / 256, 256, 0, stream>>>(k, wsb);
  vq_scan<<<NT / 256, 256, 0, stream>>>(x, wsb);
  vq_fin<<<NT / 256, 256, 0, stream>>>(x, k, out, wsb);
  vq_rescan7<<<1024, 256, 0, stream>>>(x, k, out, wsb);
  vq_final<<<1, 256, 0, stream>>>(wsb, out);
}

// Round 17
// 232.849 us; speedup vs baseline: 1.5557x; 1.0070x over previous
//
#include <hip/hip_runtime.h>
#include <math.h>

#define WD 64
#define TD 8192
#define NT 131072           // 16 * 8192 rows
#define KB 2048
// Output layout (float32, concatenated): x_l [NT], x_d [NT*WD], commit, fit, prenorm
#define OFF_XL 0
#define OFF_XD NT
#define OFF_SC (NT + NT * WD)

// ws layout (bytes)
#define RED_OFF   0                      // double[4]: xsum, xsumsq, fit, commit
#define CNT_OFF   32                     // uint: rescan count
#define KN2_OFF   4096                   // float[2048] np-exact ||k||^2
#define CB_OFF    16384                  // bf16 B-frags: 128jt * 4frag * 64lane * 16B = 512KB
#define M1_OFF    (16384 + 524288)       // float[NT]
#define M2_OFF    (M1_OFF + 4 * NT)      // float[NT]
#define J1_OFF    (M2_OFF + 4 * NT)      // int[NT]
#define LIST_OFF  (J1_OFF + 4 * NT)      // int[NT] rescan rows
#define KT_OFF    (LIST_OFF + 4 * NT)    // float[64][2048] transposed codebook (512KB)
#define XR_OFF    (KT_OFF + 8 * NT)      // float[XRCAP][64] compacted rescan rows (8MB)
#define FITV_OFF  (XR_OFF + XRCAP * WD * 4)  // double[NT] per-rescan-slot min dist
#define CMV_OFF   (FITV_OFF + 8 * NT)        // double[NT] per-rescan-slot commit part
#define XRCAP     32768                  // cap (count ~2.9k observed r5-r16)

#define EPS_GAP 4e-3f    // approx top-2 gap below this -> exact rescan (~2% rows)
#define VEPS    2e-3f    // |approx score(j1) - exact score(j1)| above this -> rescan (~0)

typedef __attribute__((ext_vector_type(8))) short bf16x8_t;  // 8 bf16 (4 VGPRs)
typedef __attribute__((ext_vector_type(4))) float f32x4_t;

__device__ __forceinline__ unsigned short bf16_rne(float f) {
  unsigned int u = __float_as_uint(f);
  unsigned int r = u + 0x7fffu + ((u >> 16) & 1u);
  return (unsigned short)(r >> 16);
}

#define REP64(F) F(0) F(1) F(2) F(3) F(4) F(5) F(6) F(7) \
  F(8) F(9) F(10) F(11) F(12) F(13) F(14) F(15) \
  F(16) F(17) F(18) F(19) F(20) F(21) F(22) F(23) \
  F(24) F(25) F(26) F(27) F(28) F(29) F(30) F(31) \
  F(32) F(33) F(34) F(35) F(36) F(37) F(38) F(39) \
  F(40) F(41) F(42) F(43) F(44) F(45) F(46) F(47) \
  F(48) F(49) F(50) F(51) F(52) F(53) F(54) F(55) \
  F(56) F(57) F(58) F(59) F(60) F(61) F(62) F(63)

// numpy pairwise_sum (scalar 8-accumulator, n=64) of PRE-ROUNDED squares; *_rn
// intrinsics forbid contraction. Bit-exact vs np.sum(a*a, -1) (verified r2-r16).
#define NP_SUMSQ64_NAMED(SVAR) \
  float r0 = __fmul_rn(x0, x0); \
  float r1 = __fmul_rn(x1, x1); \
  float r2 = __fmul_rn(x2, x2); \
  float r3 = __fmul_rn(x3, x3); \
  float r4 = __fmul_rn(x4, x4); \
  float r5 = __fmul_rn(x5, x5); \
  float r6 = __fmul_rn(x6, x6); \
  float r7 = __fmul_rn(x7, x7); \
  SQ8(8, 9, 10, 11, 12, 13, 14, 15) \
  SQ8(16, 17, 18, 19, 20, 21, 22, 23) \
  SQ8(24, 25, 26, 27, 28, 29, 30, 31) \
  SQ8(32, 33, 34, 35, 36, 37, 38, 39) \
  SQ8(40, 41, 42, 43, 44, 45, 46, 47) \
  SQ8(48, 49, 50, 51, 52, 53, 54, 55) \
  SQ8(56, 57, 58, 59, 60, 61, 62, 63) \
  const float SVAR = __fadd_rn(__fadd_rn(__fadd_rn(r0, r1), __fadd_rn(r2, r3)), \
                               __fadd_rn(__fadd_rn(r4, r5), __fadd_rn(r6, r7)));
#define SQ8(a,b,c,d,e,f,g,h) \
  r0 = __fadd_rn(r0, __fmul_rn(x##a, x##a)); \
  r1 = __fadd_rn(r1, __fmul_rn(x##b, x##b)); \
  r2 = __fadd_rn(r2, __fmul_rn(x##c, x##c)); \
  r3 = __fadd_rn(r3, __fmul_rn(x##d, x##d)); \
  r4 = __fadd_rn(r4, __fmul_rn(x##e, x##e)); \
  r5 = __fadd_rn(r5, __fmul_rn(x##f, x##f)); \
  r6 = __fadd_rn(r6, __fmul_rn(x##g, x##g)); \
  r7 = __fadd_rn(r7, __fmul_rn(x##h, x##h));

__device__ __forceinline__ float np_sumsq64_ptr(const float* a) {
  float r0 = __fmul_rn(a[0], a[0]);
  float r1 = __fmul_rn(a[1], a[1]);
  float r2 = __fmul_rn(a[2], a[2]);
  float r3 = __fmul_rn(a[3], a[3]);
  float r4 = __fmul_rn(a[4], a[4]);
  float r5 = __fmul_rn(a[5], a[5]);
  float r6 = __fmul_rn(a[6], a[6]);
  float r7 = __fmul_rn(a[7], a[7]);
#pragma unroll
  for (int i = 8; i < 64; i += 8) {
    r0 = __fadd_rn(r0, __fmul_rn(a[i + 0], a[i + 0]));
    r1 = __fadd_rn(r1, __fmul_rn(a[i + 1], a[i + 1]));
    r2 = __fadd_rn(r2, __fmul_rn(a[i + 2], a[i + 2]));
    r3 = __fadd_rn(r3, __fmul_rn(a[i + 3], a[i + 3]));
    r4 = __fadd_rn(r4, __fmul_rn(a[i + 4], a[i + 4]));
    r5 = __fadd_rn(r5, __fmul_rn(a[i + 5], a[i + 5]));
    r6 = __fadd_rn(r6, __fmul_rn(a[i + 6], a[i + 6]));
    r7 = __fadd_rn(r7, __fmul_rn(a[i + 7], a[i + 7]));
  }
  float t01 = __fadd_rn(r0, r1);
  float t23 = __fadd_rn(r2, r3);
  float t45 = __fadd_rn(r4, r5);
  float t67 = __fadd_rn(r6, r7);
  return __fadd_rn(__fadd_rn(t01, t23), __fadd_rn(t45, t67));
}

// ---------- K0: kn2_np + bf16 B-frags + transposed codebook kT[w][c] ----------
__global__ __launch_bounds__(256)
void vq_prep(const float* __restrict__ k, char* __restrict__ wsb) {
  int c = blockIdx.x * 256 + threadIdx.x;
  if (c >= KB) return;
  const float* kr = k + (size_t)c * WD;
  ((float*)(wsb + KN2_OFF))[c] = np_sumsq64_ptr(kr);
  float* kt = (float*)(wsb + KT_OFF);
#pragma unroll
  for (int w = 0; w < WD; ++w) kt[(size_t)w * KB + c] = kr[w];
  int jt = c >> 4, col = c & 15;
  unsigned short* cb = (unsigned short*)(wsb + CB_OFF);
#pragma unroll
  for (int w = 0; w < WD; ++w) {
    float f = kr[w];
    unsigned short hb = bf16_rne(f);
    float hf = __uint_as_float((unsigned int)hb << 16);
    unsigned short lb = bf16_rne(f - hf);
    int fH = w >> 5;                       // K-half: frag 0/1 (hi), 2/3 (lo)
    int lane = col | (((w >> 3) & 3) << 4);
    int e = w & 7;
    cb[((size_t)((jt * 4 + fH) * 64 + lane)) * 8 + e] = hb;
    cb[((size_t)((jt * 4 + 2 + fH) * 64 + lane)) * 8 + e] = lb;
  }
}

// ---------- K1: MFMA bf16x3 score scan, packed-index trackers ----------
// r16 diagnosis: issue-bound; tracker VALU (4 ops/score x 2cyc) dominates the
// issue stream 2.7:1 over MFMA. Fix: pack jt into score's low 7 bits
// (v_and_or_b32, 1 op) -> track via med3+max only = 3 ops/score, JT regs gone.
// Packing error ~2^-17 rel; any flipped pick => gap ~1e-5 << EPS_GAP => the
// gap-trigger rescans it exactly. 4 tiles/wave B-reuse kept from r16.
__global__ __launch_bounds__(256) __attribute__((amdgpu_waves_per_eu(2)))
void vq_scan(const float* __restrict__ x, char* __restrict__ wsb) {
  __shared__ float lkn2n[KB];         // 8KB: -0.5 * ||k||^2 (prescaled)
  __shared__ char cbuf[2][16384];     // 32KB: 2 x (4 jt x 4 frag x 64 lane x 16B)
  const int tid = threadIdx.x, lane = tid & 63, wave = tid >> 6;  // 4 waves
  const int col = lane & 15, grp = lane >> 4;

  for (int i = tid; i < KB; i += 256)
    lkn2n[i] = -0.5f * ((const float*)(wsb + KN2_OFF))[i];

  const int n = blockIdx.x >> 5;           // 32 blocks per n (8192/256)
  const int t0 = (blockIdx.x & 31) * 256;
  const float* xb = x + (size_t)n * WD * TD;

  // A-frags: wave owns 4 tiles (64 rows): rows t0 + wave*64 + T*16 + (grp*4+e)
  bf16x8_t aH[4][2], aL[4][2];             // [tile][k-step], 64 VGPR
#pragma unroll
  for (int T = 0; T < 4; ++T) {
    const int trow = t0 + wave * 64 + T * 16 + col;
#pragma unroll
    for (int s = 0; s < 2; ++s) {
#pragma unroll
      for (int e = 0; e < 8; ++e) {
        int w = s * 32 + grp * 8 + e;
        float f = xb[(size_t)w * TD + trow];
        unsigned short hb = bf16_rne(f);
        float hf = __uint_as_float((unsigned int)hb << 16);
        unsigned short lb = bf16_rne(f - hf);
        aH[T][s][e] = (short)hb;
        aL[T][s][e] = (short)lb;
      }
    }
  }

  // packed argmax trackers: value bits [31:7], jt in bits [6:0]
  float M1[4][4], M2[4][4];
#pragma unroll
  for (int T = 0; T < 4; ++T)
#pragma unroll
    for (int e = 0; e < 4; ++e) {
      M1[T][e] = -INFINITY; M2[T][e] = -INFINITY;
    }

  const char* cbsrc = wsb + CB_OFF;
  float4 pf0, pf1, pf2, pf3;
#define PREF(c) { const float4* sp = (const float4*)(cbsrc + (size_t)(c) * 16384); \
    pf0 = sp[tid]; pf1 = sp[tid + 256]; pf2 = sp[tid + 512]; pf3 = sp[tid + 768]; }
#define WRBUF(b) { float4* dp = (float4*)cbuf[b]; \
    dp[tid] = pf0; dp[tid + 256] = pf1; dp[tid + 512] = pf2; dp[tid + 768] = pf3; }

  PREF(0)
  WRBUF(0)
  PREF(1)
  __syncthreads();                         // chunk0 + lkn2n visible

  for (int c = 0; c < 32; ++c) {
    const int cur = c & 1;
    if (c < 31) WRBUF(cur ^ 1)
    if (c < 30) PREF(c + 2)
#pragma unroll
    for (int jl = 0; jl < 4; ++jl) {
      const bf16x8_t* bp = (const bf16x8_t*)(cbuf[cur] + jl * 4096) + lane;
      bf16x8_t bH0 = bp[0], bH1 = bp[64], bL0 = bp[128], bL1 = bp[192];
      const int jt = c * 4 + jl;
      const float ci = lkn2n[jt * 16 + col];
#pragma unroll
      for (int T = 0; T < 4; ++T) {
        f32x4_t acc = {ci, ci, ci, ci};    // C-init = -kn2/2 (same col, 4 rows)
        acc = __builtin_amdgcn_mfma_f32_16x16x32_bf16(aH[T][0], bH0, acc, 0, 0, 0);
        acc = __builtin_amdgcn_mfma_f32_16x16x32_bf16(aH[T][1], bH1, acc, 0, 0, 0);
        acc = __builtin_amdgcn_mfma_f32_16x16x32_bf16(aL[T][0], bH0, acc, 0, 0, 0);
        acc = __builtin_amdgcn_mfma_f32_16x16x32_bf16(aL[T][1], bH1, acc, 0, 0, 0);
        acc = __builtin_amdgcn_mfma_f32_16x16x32_bf16(aH[T][0], bL0, acc, 0, 0, 0);
        acc = __builtin_amdgcn_mfma_f32_16x16x32_bf16(aH[T][1], bL1, acc, 0, 0, 0);
        // 3 ops/score: and_or(pack jt), med3(second-max), max
#pragma unroll
        for (int e = 0; e < 4; ++e) {
          float vp = __uint_as_float(
              (__float_as_uint(acc[e]) & 0xFFFFFF80u) | (unsigned)jt);
          M2[T][e] = __builtin_amdgcn_fmed3f(M1[T][e], M2[T][e], vp);
          M1[T][e] = fmaxf(M1[T][e], vp);
        }
      }
    }
    __syncthreads();
  }
#undef PREF
#undef WRBUF

  // extract jt from packed M1, cross-lane reduce (max domain), writeout (*-2)
#pragma unroll
  for (int T = 0; T < 4; ++T)
#pragma unroll
    for (int e = 0; e < 4; ++e) {
      float m1 = M1[T][e], m2 = M2[T][e];
      int cd = (int)(__float_as_uint(m1) & 0x7Fu) * 16 + col;
#pragma unroll
      for (int d = 1; d < 16; d <<= 1) {
        float om1 = __shfl_xor(m1, d, 64);
        float om2 = __shfl_xor(m2, d, 64);
        int ocd = __shfl_xor(cd, d, 64);
        bool take = (om1 > m1) || (om1 == m1 && ocd < cd);
        float loser = take ? m1 : om1;                 // smaller of the maxes
        m2 = fmaxf(fmaxf(m2, om2), loser);
        m1 = take ? om1 : m1;
        cd = take ? ocd : cd;
      }
      if (col == 0) {
        int row = blockIdx.x * 256 + wave * 64 + T * 16 + grp * 4 + e;
        ((float*)(wsb + M1_OFF))[row] = -2.f * m1;     // back to score domain
        ((float*)(wsb + M2_OFF))[row] = -2.f * m2;
        ((int*)(wsb + J1_OFF))[row] = cd;
      }
    }
}

// ---------- K2: per-row finalize: verify j1, epilogue, flag + compact rescans ----------
__global__ __launch_bounds__(256, 4)
void vq_fin(const float* __restrict__ x, const float* __restrict__ k,
            float* __restrict__ out, char* __restrict__ wsb) {
  __shared__ double sred[16];
  const int tid = threadIdx.x;
  const int row = blockIdx.x * 256 + tid;
  const int n = row >> 13;
  const int t = row & (TD - 1);

  float m1r = ((const float*)(wsb + M1_OFF))[row];
  float m2r = ((const float*)(wsb + M2_OFF))[row];
  int j1r = ((const int*)(wsb + J1_OFF))[row];

  const float* xr = x + ((size_t)n * WD) * TD + t;
#define LOADX(w) float x##w = xr[(size_t)(w) * TD];
  REP64(LOADX)
#undef LOADX

  NP_SUMSQ64_NAMED(s)

  double xsum = 0.0, xsumsq = 0.0;
#define PRE(w) { double xd = (double)x##w; xsum += xd; xsumsq = fma(xd, xd, xsumsq); }
  REP64(PRE)
#undef PRE

  // Epilogue: k[j1] gather via float4 (16 dwordx4 gathers vs 64 scalar),
  // consumed in 4 groups of 16 (bounded live regs). Arithmetic order and
  // rounding identical to the scalar version (only load width changed).
  const float4* k4 = (const float4*)(k + (size_t)j1r * WD);
  float* xo = out + OFF_XD + ((size_t)n * WD) * TD + t;
  double commit = 0.0;
  float g = 0.f;
#define EPI1(w, KW) { \
    float kw = KW; \
    float diff = __fsub_rn(kw, x##w); \
    commit = fma((double)diff, (double)diff, commit); \
    g = __fmaf_rn(x##w, kw, g); \
    xo[(size_t)(w) * TD] = __fadd_rn(x##w, diff); }
  {
    float4 ka = k4[0], kb = k4[1], kc = k4[2], kd = k4[3];
    EPI1(0, ka.x) EPI1(1, ka.y) EPI1(2, ka.z) EPI1(3, ka.w)
    EPI1(4, kb.x) EPI1(5, kb.y) EPI1(6, kb.z) EPI1(7, kb.w)
    EPI1(8, kc.x) EPI1(9, kc.y) EPI1(10, kc.z) EPI1(11, kc.w)
    EPI1(12, kd.x) EPI1(13, kd.y) EPI1(14, kd.z) EPI1(15, kd.w)
  }
  {
    float4 ka = k4[4], kb = k4[5], kc = k4[6], kd = k4[7];
    EPI1(16, ka.x) EPI1(17, ka.y) EPI1(18, ka.z) EPI1(19, ka.w)
    EPI1(20, kb.x) EPI1(21, kb.y) EPI1(22, kb.z) EPI1(23, kb.w)
    EPI1(24, kc.x) EPI1(25, kc.y) EPI1(26, kc.z) EPI1(27, kc.w)
    EPI1(28, kd.x) EPI1(29, kd.y) EPI1(30, kd.z) EPI1(31, kd.w)
  }
  {
    float4 ka = k4[8], kb = k4[9], kc = k4[10], kd = k4[11];
    EPI1(32, ka.x) EPI1(33, ka.y) EPI1(34, ka.z) EPI1(35, ka.w)
    EPI1(36, kb.x) EPI1(37, kb.y) EPI1(38, kb.z) EPI1(39, kb.w)
    EPI1(40, kc.x) EPI1(41, kc.y) EPI1(42, kc.z) EPI1(43, kc.w)
    EPI1(44, kd.x) EPI1(45, kd.y) EPI1(46, kd.z) EPI1(47, kd.w)
  }
  {
    float4 ka = k4[12], kb = k4[13], kc = k4[14], kd = k4[15];
    EPI1(48, ka.x) EPI1(49, ka.y) EPI1(50, ka.z) EPI1(51, ka.w)
    EPI1(52, kb.x) EPI1(53, kb.y) EPI1(54, kb.z) EPI1(55, kb.w)
    EPI1(56, kc.x) EPI1(57, kc.y) EPI1(58, kc.z) EPI1(59, kc.w)
    EPI1(60, kd.x) EPI1(61, kd.y) EPI1(62, kd.z) EPI1(63, kd.w)
  }
#undef EPI1

  float kn2j = ((const float*)(wsb + KN2_OFF))[j1r];
  float score = kn2j - 2.f * g;
  bool resc = (m2r - m1r < EPS_GAP) || (fabsf(score - m1r) > VEPS);
  float dist1 = __fadd_rn(__fsub_rn(s, __fmul_rn(2.f, g)), kn2j);

  out[OFF_XL + row] = (float)j1r;
  if (resc) {
    unsigned idx = atomicAdd((unsigned*)(wsb + CNT_OFF), 1u);
    ((int*)(wsb + LIST_OFF))[idx] = row;
    if (idx < XRCAP) {                                    // compact row for rescan
      float* xrw = (float*)(wsb + XR_OFF) + (size_t)idx * WD;
#define XWR(w) xrw[w] = x##w;
      REP64(XWR)
#undef XWR
    }
  }

  double v0 = xsum, v1 = xsumsq;
  double v2 = resc ? 0.0 : (double)dist1;
  double v3 = resc ? 0.0 : commit;
#pragma unroll
  for (int off = 32; off > 0; off >>= 1) {
    v0 += __shfl_down(v0, off, 64);
    v1 += __shfl_down(v1, off, 64);
    v2 += __shfl_down(v2, off, 64);
    v3 += __shfl_down(v3, off, 64);
  }
  if ((tid & 63) == 0) {
    int wv = tid >> 6;
    sred[wv * 4 + 0] = v0;
    sred[wv * 4 + 1] = v1;
    sred[wv * 4 + 2] = v2;
    sred[wv * 4 + 3] = v3;
  }
  __syncthreads();
  if (tid == 0) {
    double a0 = 0, a1 = 0, a2 = 0, a3 = 0;
#pragma unroll
    for (int w2 = 0; w2 < 4; ++w2) {
      a0 += sred[w2 * 4 + 0];
      a1 += sred[w2 * 4 + 1];
      a2 += sred[w2 * 4 + 2];
      a3 += sred[w2 * 4 + 3];
    }
    double* red = (double*)(wsb + RED_OFF);
    atomicAdd(&red[0], a0);
    atomicAdd(&red[1], a1);
    atomicAdd(&red[2], a2);
    atomicAdd(&red[3], a3);
  }
}

// ---------- K3: exact rescan, 4 rows/block, per-slot results (no hot atomics) ----------
__global__ __launch_bounds__(256)
void vq_rescan7(const float* __restrict__ x, const float* __restrict__ k,
                float* __restrict__ out, char* __restrict__ wsb) {
  __shared__ float xs[4][WD];
  __shared__ float ss[4];
  __shared__ unsigned long long wred[4][4];   // [row][wave]
  __shared__ unsigned long long bbest[4];
  const unsigned count = *(const unsigned*)(wsb + CNT_OFF);
  const int* list = (const int*)(wsb + LIST_OFF);
  const float* kn2 = (const float*)(wsb + KN2_OFF);
  const float* XR = (const float*)(wsb + XR_OFF);
  const float* kT = (const float*)(wsb + KT_OFF);
  double* fitv = (double*)(wsb + FITV_OFF);
  double* cmv = (double*)(wsb + CMV_OFF);
  const int tid = threadIdx.x;
  const int lane = tid & 63, wv = tid >> 6;
  const int c0 = tid * 8;

  for (unsigned base = blockIdx.x * 4u; base < count; base += gridDim.x * 4u) {
    __syncthreads();                       // xs/ss/wred reuse guard
    {                                      // stage up to 4 rows (256 thr = 4x64)
      const int r = tid >> 6, w = tid & 63;
      const unsigned li = base + (unsigned)r;
      if (li < count) {
        if (li < XRCAP) {
          xs[r][w] = XR[(size_t)li * WD + w];
        } else {
          const int row = list[li];
          const int n = row >> 13, t = row & (TD - 1);
          xs[r][w] = x[(size_t)n * WD * TD + (size_t)w * TD + t];
        }
      }
    }
    __syncthreads();
    if (lane == 0) ss[wv] = np_sumsq64_ptr(xs[wv]);   // 1x per row (wave-uniform)
    __syncthreads();
    const float s0 = ss[0], s1 = ss[1], s2 = ss[2], s3 = ss[3];

    float a00 = 0.f, a01 = 0.f, a02 = 0.f, a03 = 0.f, a04 = 0.f, a05 = 0.f, a06 = 0.f, a07 = 0.f;
    float a10 = 0.f, a11 = 0.f, a12 = 0.f, a13 = 0.f, a14 = 0.f, a15 = 0.f, a16 = 0.f, a17 = 0.f;
    float a20 = 0.f, a21 = 0.f, a22 = 0.f, a23 = 0.f, a24 = 0.f, a25 = 0.f, a26 = 0.f, a27 = 0.f;
    float a30 = 0.f, a31 = 0.f, a32 = 0.f, a33 = 0.f, a34 = 0.f, a35 = 0.f, a36 = 0.f, a37 = 0.f;
    const float* kt = kT + c0;
#pragma unroll 4
    for (int w = 0; w < WD; ++w) {
      const float4 ka = *(const float4*)(kt + (size_t)w * KB);
      const float4 kb = *(const float4*)(kt + (size_t)w * KB + 4);
      const float xw0 = xs[0][w], xw1 = xs[1][w], xw2 = xs[2][w], xw3 = xs[3][w];
      a00 = __fmaf_rn(xw0, ka.x, a00); a01 = __fmaf_rn(xw0, ka.y, a01);
      a02 = __fmaf_rn(xw0, ka.z, a02); a03 = __fmaf_rn(xw0, ka.w, a03);
      a04 = __fmaf_rn(xw0, kb.x, a04); a05 = __fmaf_rn(xw0, kb.y, a05);
      a06 = __fmaf_rn(xw0, kb.z, a06); a07 = __fmaf_rn(xw0, kb.w, a07);
      a10 = __fmaf_rn(xw1, ka.x, a10); a11 = __fmaf_rn(xw1, ka.y, a11);
      a12 = __fmaf_rn(xw1, ka.z, a12); a13 = __fmaf_rn(xw1, ka.w, a13);
      a14 = __fmaf_rn(xw1, kb.x, a14); a15 = __fmaf_rn(xw1, kb.y, a15);
      a16 = __fmaf_rn(xw1, kb.z, a16); a17 = __fmaf_rn(xw1, kb.w, a17);
      a20 = __fmaf_rn(xw2, ka.x, a20); a21 = __fmaf_rn(xw2, ka.y, a21);
      a22 = __fmaf_rn(xw2, ka.z, a22); a23 = __fmaf_rn(xw2, ka.w, a23);
      a24 = __fmaf_rn(xw2, kb.x, a24); a25 = __fmaf_rn(xw2, kb.y, a25);
      a26 = __fmaf_rn(xw2, kb.z, a26); a27 = __fmaf_rn(xw2, kb.w, a27);
      a30 = __fmaf_rn(xw3, ka.x, a30); a31 = __fmaf_rn(xw3, ka.y, a31);
      a32 = __fmaf_rn(xw3, ka.z, a32); a33 = __fmaf_rn(xw3, ka.w, a33);
      a34 = __fmaf_rn(xw3, kb.x, a34); a35 = __fmaf_rn(xw3, kb.y, a35);
      a36 = __fmaf_rn(xw3, kb.z, a36); a37 = __fmaf_rn(xw3, kb.w, a37);
    }

#define ROWBEST(R, SV, A0, A1, A2, A3, A4, A5, A6, A7) { \
      unsigned long long best = ~0ull; \
      float d; unsigned long long p; \
      d = __fadd_rn(__fsub_rn(SV, __fmul_rn(2.f, A0)), kn2[c0 + 0]); \
      p = ((unsigned long long)__float_as_uint(d) << 32) | (unsigned)(c0 + 0); best = p < best ? p : best; \
      d = __fadd_rn(__fsub_rn(SV, __fmul_rn(2.f, A1)), kn2[c0 + 1]); \
      p = ((unsigned long long)__float_as_uint(d) << 32) | (unsigned)(c0 + 1); best = p < best ? p : best; \
      d = __fadd_rn(__fsub_rn(SV, __fmul_rn(2.f, A2)), kn2[c0 + 2]); \
      p = ((unsigned long long)__float_as_uint(d) << 32) | (unsigned)(c0 + 2); best = p < best ? p : best; \
      d = __fadd_rn(__fsub_rn(SV, __fmul_rn(2.f, A3)), kn2[c0 + 3]); \
      p = ((unsigned long long)__float_as_uint(d) << 32) | (unsigned)(c0 + 3); best = p < best ? p : best; \
      d = __fadd_rn(__fsub_rn(SV, __fmul_rn(2.f, A4)), kn2[c0 + 4]); \
      p = ((unsigned long long)__float_as_uint(d) << 32) | (unsigned)(c0 + 4); best = p < best ? p : best; \
      d = __fadd_rn(__fsub_rn(SV, __fmul_rn(2.f, A5)), kn2[c0 + 5]); \
      p = ((unsigned long long)__float_as_uint(d) << 32) | (unsigned)(c0 + 5); best = p < best ? p : best; \
      d = __fadd_rn(__fsub_rn(SV, __fmul_rn(2.f, A6)), kn2[c0 + 6]); \
      p = ((unsigned long long)__float_as_uint(d) << 32) | (unsigned)(c0 + 6); best = p < best ? p : best; \
      d = __fadd_rn(__fsub_rn(SV, __fmul_rn(2.f, A7)), kn2[c0 + 7]); \
      p = ((unsigned long long)__float_as_uint(d) << 32) | (unsigned)(c0 + 7); best = p < best ? p : best; \
      _Pragma("unroll") \
      for (int dd = 1; dd < 64; dd <<= 1) { \
        unsigned lo = (unsigned)best, hi = (unsigned)(best >> 32); \
        unsigned olo = __shfl_xor(lo, dd, 64); \
        unsigned ohi = __shfl_xor(hi, dd, 64); \
        unsigned long long o = ((unsigned long long)ohi << 32) | olo; \
        best = o < best ? o : best; \
      } \
      if (lane == 0) wred[R][wv] = best; }
    ROWBEST(0, s0, a00, a01, a02, a03, a04, a05, a06, a07)
    ROWBEST(1, s1, a10, a11, a12, a13, a14, a15, a16, a17)
    ROWBEST(2, s2, a20, a21, a22, a23, a24, a25, a26, a27)
    ROWBEST(3, s3, a30, a31, a32, a33, a34, a35, a36, a37)
#undef ROWBEST
    __syncthreads();
    if (tid < 4) {
      unsigned long long b = wred[tid][0];
      b = wred[tid][1] < b ? wred[tid][1] : b;
      b = wred[tid][2] < b ? wred[tid][2] : b;
      b = wred[tid][3] < b ? wred[tid][3] : b;
      bbest[tid] = b;
    }
    __syncthreads();

    // epilogue: wave wv handles row base+wv, lane = w (one wave per row)
    {
      const int r = wv, w = lane;
      const unsigned li = base + (unsigned)r;
      if (li < count) {
        const int row = list[li];
        const int n = row >> 13, t = row & (TD - 1);
        const unsigned long long fb = bbest[r];
        const int bi = (int)(fb & 0xffffffffu);
        const float bv = __uint_as_float((unsigned)(fb >> 32));
        float kw = k[(size_t)bi * WD + w];
        float xw = xs[r][w];
        float diff = __fsub_rn(kw, xw);
        out[OFF_XD + (size_t)n * WD * TD + (size_t)w * TD + t] = __fadd_rn(xw, diff);
        double d2 = (double)diff * (double)diff;
#pragma unroll
        for (int dd = 32; dd > 0; dd >>= 1) d2 += __shfl_down(d2, dd, 64);
        if (w == 0) {
          out[OFF_XL + row] = (float)bi;
          fitv[li] = (double)bv;           // plain store, no contention
          cmv[li] = d2;
        }
      }
    }
  }
}

// ---------- K4: final scalars — reduce rescan arrays + red[] ----------
__global__ __launch_bounds__(256)
void vq_final(const char* __restrict__ wsb, float* __restrict__ out) {
  __shared__ double sred[8];
  const unsigned count = *(const unsigned*)(wsb + CNT_OFF);
  const double* fitv = (const double*)(wsb + FITV_OFF);
  const double* cmv = (const double*)(wsb + CMV_OFF);
  const double* red = (const double*)(wsb + RED_OFF);
  const int tid = threadIdx.x;

  double fa = 0.0, ca = 0.0;
  for (unsigned i = tid; i < count; i += 256) {
    fa += fitv[i];
    ca += cmv[i];
  }
#pragma unroll
  for (int off = 32; off > 0; off >>= 1) {
    fa += __shfl_down(fa, off, 64);
    ca += __shfl_down(ca, off, 64);
  }
  if ((tid & 63) == 0) {
    sred[(tid >> 6) * 2 + 0] = fa;
    sred[(tid >> 6) * 2 + 1] = ca;
  }
  __syncthreads();
  if (tid == 0) {
    double fit = red[2], cm = red[3];
#pragma unroll
    for (int i = 0; i < 4; ++i) {
      fit += sred[i * 2 + 0];
      cm += sred[i * 2 + 1];
    }
    double sum = red[0], sumsq = red[1];
    double mean = sum / 8388608.0;
    double ss = sumsq - sum * mean;
    if (ss < 0.0) ss = 0.0;
    out[OFF_SC + 0] = (float)(cm / 8388608.0);         // commit_loss
    out[OFF_SC + 1] = (float)(fit / 131072.0);         // fit
    out[OFF_SC + 2] = (float)sqrt(ss / 8388608.0);     // prenorm
  }
}

extern "C" void kernel_launch(void* const* d_in, const int* in_sizes, int n_in,
                              void* d_out, int out_size, void* d_ws, size_t ws_size,
                              hipStream_t stream) {
  const float* x = (const float*)d_in[0];
  const float* k = (const float*)d_in[1];
  float* out = (float*)d_out;
  char* wsb = (char*)d_ws;

  hipMemsetAsync(d_ws, 0, 64, stream);                 // red[4] + count
  vq_prep<<<KB / 256, 256, 0, stream>>>(k, wsb);
  vq_scan<<<NT / 256, 256, 0, stream>>>(x, wsb);
  vq_fin<<<NT / 256, 256, 0, stream>>>(x, k, out, wsb);
  vq_rescan7<<<1024, 256, 0, stream>>>(x, k, out, wsb);
  vq_final<<<1, 256, 0, stream>>>(wsb, out);
}

// Round 18
// 193.154 us; speedup vs baseline: 1.8754x; 1.2055x over previous
//
#include <hip/hip_runtime.h>
#include <math.h>

#define WD 64
#define TD 8192
#define NT 131072           // 16 * 8192 rows
#define KB 2048
// Output layout (float32, concatenated): x_l [NT], x_d [NT*WD], commit, fit, prenorm
#define OFF_XL 0
#define OFF_XD NT
#define OFF_SC (NT + NT * WD)

// ws layout (bytes)
#define CNT_OFF   32                     // uint: rescan count
#define KN2_OFF   4096                   // float[2048] np-exact ||k||^2
#define CB_OFF    16384                  // bf16 B-frags: 128jt * 4frag * 64lane * 16B = 512KB
#define LIST_OFF  (16384 + 524288)       // int[NT] rescan rows
#define KT_OFF    (LIST_OFF + 4 * NT)    // float[64][2048] transposed codebook (512KB)
#define XR_OFF    (KT_OFF + 8 * NT)      // float[XRCAP][64] compacted rescan rows (8MB)
#define FITV_OFF  (XR_OFF + XRCAP * WD * 4)  // double[NT] per-rescan-slot min dist
#define CMV_OFF   (FITV_OFF + 8 * NT)        // double[NT] per-rescan-slot commit part
#define PB_OFF    (CMV_OFF + 8 * NT)         // double[512][4] per-block partials
#define XRCAP     32768                  // cap (count ~2.9k observed r5-r17)

#define EPS_GAP 4e-3f    // approx top-2 gap below this -> exact rescan (~2% rows)
#define VEPS    2e-3f    // |approx score(j1) - exact score(j1)| above this -> rescan (~0)

typedef __attribute__((ext_vector_type(8))) short bf16x8_t;  // 8 bf16 (4 VGPRs)
typedef __attribute__((ext_vector_type(4))) float f32x4_t;

__device__ __forceinline__ unsigned short bf16_rne(float f) {
  unsigned int u = __float_as_uint(f);
  unsigned int r = u + 0x7fffu + ((u >> 16) & 1u);
  return (unsigned short)(r >> 16);
}

#define REP64(F) F(0) F(1) F(2) F(3) F(4) F(5) F(6) F(7) \
  F(8) F(9) F(10) F(11) F(12) F(13) F(14) F(15) \
  F(16) F(17) F(18) F(19) F(20) F(21) F(22) F(23) \
  F(24) F(25) F(26) F(27) F(28) F(29) F(30) F(31) \
  F(32) F(33) F(34) F(35) F(36) F(37) F(38) F(39) \
  F(40) F(41) F(42) F(43) F(44) F(45) F(46) F(47) \
  F(48) F(49) F(50) F(51) F(52) F(53) F(54) F(55) \
  F(56) F(57) F(58) F(59) F(60) F(61) F(62) F(63)

// numpy pairwise_sum (scalar 8-accumulator, n=64) of PRE-ROUNDED squares; *_rn
// intrinsics forbid contraction. Bit-exact vs np.sum(a*a, -1) (verified r2-r17).
#define NP_SUMSQ64_NAMED(SVAR) \
  float r0 = __fmul_rn(x0, x0); \
  float r1 = __fmul_rn(x1, x1); \
  float r2 = __fmul_rn(x2, x2); \
  float r3 = __fmul_rn(x3, x3); \
  float r4 = __fmul_rn(x4, x4); \
  float r5 = __fmul_rn(x5, x5); \
  float r6 = __fmul_rn(x6, x6); \
  float r7 = __fmul_rn(x7, x7); \
  SQ8(8, 9, 10, 11, 12, 13, 14, 15) \
  SQ8(16, 17, 18, 19, 20, 21, 22, 23) \
  SQ8(24, 25, 26, 27, 28, 29, 30, 31) \
  SQ8(32, 33, 34, 35, 36, 37, 38, 39) \
  SQ8(40, 41, 42, 43, 44, 45, 46, 47) \
  SQ8(48, 49, 50, 51, 52, 53, 54, 55) \
  SQ8(56, 57, 58, 59, 60, 61, 62, 63) \
  const float SVAR = __fadd_rn(__fadd_rn(__fadd_rn(r0, r1), __fadd_rn(r2, r3)), \
                               __fadd_rn(__fadd_rn(r4, r5), __fadd_rn(r6, r7)));
#define SQ8(a,b,c,d,e,f,g,h) \
  r0 = __fadd_rn(r0, __fmul_rn(x##a, x##a)); \
  r1 = __fadd_rn(r1, __fmul_rn(x##b, x##b)); \
  r2 = __fadd_rn(r2, __fmul_rn(x##c, x##c)); \
  r3 = __fadd_rn(r3, __fmul_rn(x##d, x##d)); \
  r4 = __fadd_rn(r4, __fmul_rn(x##e, x##e)); \
  r5 = __fadd_rn(r5, __fmul_rn(x##f, x##f)); \
  r6 = __fadd_rn(r6, __fmul_rn(x##g, x##g)); \
  r7 = __fadd_rn(r7, __fmul_rn(x##h, x##h));

__device__ __forceinline__ float np_sumsq64_ptr(const float* a) {
  float r0 = __fmul_rn(a[0], a[0]);
  float r1 = __fmul_rn(a[1], a[1]);
  float r2 = __fmul_rn(a[2], a[2]);
  float r3 = __fmul_rn(a[3], a[3]);
  float r4 = __fmul_rn(a[4], a[4]);
  float r5 = __fmul_rn(a[5], a[5]);
  float r6 = __fmul_rn(a[6], a[6]);
  float r7 = __fmul_rn(a[7], a[7]);
#pragma unroll
  for (int i = 8; i < 64; i += 8) {
    r0 = __fadd_rn(r0, __fmul_rn(a[i + 0], a[i + 0]));
    r1 = __fadd_rn(r1, __fmul_rn(a[i + 1], a[i + 1]));
    r2 = __fadd_rn(r2, __fmul_rn(a[i + 2], a[i + 2]));
    r3 = __fadd_rn(r3, __fmul_rn(a[i + 3], a[i + 3]));
    r4 = __fadd_rn(r4, __fmul_rn(a[i + 4], a[i + 4]));
    r5 = __fadd_rn(r5, __fmul_rn(a[i + 5], a[i + 5]));
    r6 = __fadd_rn(r6, __fmul_rn(a[i + 6], a[i + 6]));
    r7 = __fadd_rn(r7, __fmul_rn(a[i + 7], a[i + 7]));
  }
  float t01 = __fadd_rn(r0, r1);
  float t23 = __fadd_rn(r2, r3);
  float t45 = __fadd_rn(r4, r5);
  float t67 = __fadd_rn(r6, r7);
  return __fadd_rn(__fadd_rn(t01, t23), __fadd_rn(t45, t67));
}

// ---------- K0: kn2_np + bf16 B-frags + transposed codebook kT[w][c] ----------
__global__ __launch_bounds__(256)
void vq_prep(const float* __restrict__ k, char* __restrict__ wsb) {
  int c = blockIdx.x * 256 + threadIdx.x;
  if (c >= KB) return;
  const float* kr = k + (size_t)c * WD;
  ((float*)(wsb + KN2_OFF))[c] = np_sumsq64_ptr(kr);
  float* kt = (float*)(wsb + KT_OFF);
#pragma unroll
  for (int w = 0; w < WD; ++w) kt[(size_t)w * KB + c] = kr[w];
  int jt = c >> 4, col = c & 15;
  unsigned short* cb = (unsigned short*)(wsb + CB_OFF);
#pragma unroll
  for (int w = 0; w < WD; ++w) {
    float f = kr[w];
    unsigned short hb = bf16_rne(f);
    float hf = __uint_as_float((unsigned int)hb << 16);
    unsigned short lb = bf16_rne(f - hf);
    int fH = w >> 5;                       // K-half: frag 0/1 (hi), 2/3 (lo)
    int lane = col | (((w >> 3) & 3) << 4);
    int e = w & 7;
    cb[((size_t)((jt * 4 + fH) * 64 + lane)) * 8 + e] = hb;
    cb[((size_t)((jt * 4 + 2 + fH) * 64 + lane)) * 8 + e] = lb;
  }
}

// ---------- K1: FUSED scan + finalize ----------
// r17 lesson: scan is pinned at the 2-barrier plain-HIP plateau; the lever is
// fin's 80-90us of redundant work. Fuse: after the MFMA scan + cross-lane
// reduce, drop (m1,m2,j1) into LDS; each thread then finalizes ONE row
// (fin's body verbatim: np-exact s, fp64 prenorm/commit, float4 k[j1] gather,
// x_d/x_l writes, rescan flag + XR compaction). Saves a full 33MB x re-read,
// the M1/M2/J1 HBM round-trip, and a launch. Block partials via plain stores
// (PB array), reduced in vq_final — no device atomics (r12 lesson).
__global__ __launch_bounds__(256) __attribute__((amdgpu_waves_per_eu(2)))
void vq_scan(const float* __restrict__ x, const float* __restrict__ k,
             float* __restrict__ out, char* __restrict__ wsb) {
  __shared__ float lkn2n[KB];         // 8KB: -0.5 * ||k||^2 (prescaled)
  __shared__ char cbuf[2][16384];     // 32KB double-buffered B-frag chunks
  __shared__ float sm1[256], sm2[256];
  __shared__ int sj1[256];
  __shared__ double sred[16];
  const int tid = threadIdx.x, lane = tid & 63, wave = tid >> 6;  // 4 waves
  const int col = lane & 15, grp = lane >> 4;

  for (int i = tid; i < KB; i += 256)
    lkn2n[i] = -0.5f * ((const float*)(wsb + KN2_OFF))[i];

  const int n = blockIdx.x >> 5;           // 32 blocks per n (8192/256)
  const int t0 = (blockIdx.x & 31) * 256;
  const float* xb = x + (size_t)n * WD * TD;

  // A-frags: wave owns 4 tiles (64 rows): rows t0 + wave*64 + T*16 + (grp*4+e)
  bf16x8_t aH[4][2], aL[4][2];
#pragma unroll
  for (int T = 0; T < 4; ++T) {
    const int trow = t0 + wave * 64 + T * 16 + col;
#pragma unroll
    for (int s = 0; s < 2; ++s) {
#pragma unroll
      for (int e = 0; e < 8; ++e) {
        int w = s * 32 + grp * 8 + e;
        float f = xb[(size_t)w * TD + trow];
        unsigned short hb = bf16_rne(f);
        float hf = __uint_as_float((unsigned int)hb << 16);
        unsigned short lb = bf16_rne(f - hf);
        aH[T][s][e] = (short)hb;
        aL[T][s][e] = (short)lb;
      }
    }
  }

  // packed argmax trackers: value bits [31:7], jt in bits [6:0]
  float M1[4][4], M2[4][4];
#pragma unroll
  for (int T = 0; T < 4; ++T)
#pragma unroll
    for (int e = 0; e < 4; ++e) {
      M1[T][e] = -INFINITY; M2[T][e] = -INFINITY;
    }

  const char* cbsrc = wsb + CB_OFF;
  float4 pf0, pf1, pf2, pf3;
#define PREF(c) { const float4* sp = (const float4*)(cbsrc + (size_t)(c) * 16384); \
    pf0 = sp[tid]; pf1 = sp[tid + 256]; pf2 = sp[tid + 512]; pf3 = sp[tid + 768]; }
#define WRBUF(b) { float4* dp = (float4*)cbuf[b]; \
    dp[tid] = pf0; dp[tid + 256] = pf1; dp[tid + 512] = pf2; dp[tid + 768] = pf3; }

  PREF(0)
  WRBUF(0)
  PREF(1)
  __syncthreads();

  for (int c = 0; c < 32; ++c) {
    const int cur = c & 1;
    if (c < 31) WRBUF(cur ^ 1)
    if (c < 30) PREF(c + 2)
#pragma unroll
    for (int jl = 0; jl < 4; ++jl) {
      const bf16x8_t* bp = (const bf16x8_t*)(cbuf[cur] + jl * 4096) + lane;
      bf16x8_t bH0 = bp[0], bH1 = bp[64], bL0 = bp[128], bL1 = bp[192];
      const int jt = c * 4 + jl;
      const float ci = lkn2n[jt * 16 + col];
#pragma unroll
      for (int T = 0; T < 4; ++T) {
        f32x4_t acc = {ci, ci, ci, ci};
        acc = __builtin_amdgcn_mfma_f32_16x16x32_bf16(aH[T][0], bH0, acc, 0, 0, 0);
        acc = __builtin_amdgcn_mfma_f32_16x16x32_bf16(aH[T][1], bH1, acc, 0, 0, 0);
        acc = __builtin_amdgcn_mfma_f32_16x16x32_bf16(aL[T][0], bH0, acc, 0, 0, 0);
        acc = __builtin_amdgcn_mfma_f32_16x16x32_bf16(aL[T][1], bH1, acc, 0, 0, 0);
        acc = __builtin_amdgcn_mfma_f32_16x16x32_bf16(aH[T][0], bL0, acc, 0, 0, 0);
        acc = __builtin_amdgcn_mfma_f32_16x16x32_bf16(aH[T][1], bL1, acc, 0, 0, 0);
#pragma unroll
        for (int e = 0; e < 4; ++e) {
          float vp = __uint_as_float(
              (__float_as_uint(acc[e]) & 0xFFFFFF80u) | (unsigned)jt);
          M2[T][e] = __builtin_amdgcn_fmed3f(M1[T][e], M2[T][e], vp);
          M1[T][e] = fmaxf(M1[T][e], vp);
        }
      }
    }
    __syncthreads();
  }
#undef PREF
#undef WRBUF

  // cross-lane reduce -> per-row (m1,m2,j1) into LDS
#pragma unroll
  for (int T = 0; T < 4; ++T)
#pragma unroll
    for (int e = 0; e < 4; ++e) {
      float m1 = M1[T][e], m2 = M2[T][e];
      int cd = (int)(__float_as_uint(m1) & 0x7Fu) * 16 + col;
#pragma unroll
      for (int d = 1; d < 16; d <<= 1) {
        float om1 = __shfl_xor(m1, d, 64);
        float om2 = __shfl_xor(m2, d, 64);
        int ocd = __shfl_xor(cd, d, 64);
        bool take = (om1 > m1) || (om1 == m1 && ocd < cd);
        float loser = take ? m1 : om1;
        m2 = fmaxf(fmaxf(m2, om2), loser);
        m1 = take ? om1 : m1;
        cd = take ? ocd : cd;
      }
      if (col == 0) {
        int r = wave * 64 + T * 16 + grp * 4 + e;
        sm1[r] = -2.f * m1;                // score domain
        sm2[r] = -2.f * m2;
        sj1[r] = cd;
      }
    }
  __syncthreads();

  // ---- fused finalize: one row per thread (fin's body verbatim) ----
  const int row = blockIdx.x * 256 + tid;
  const int t = row & (TD - 1);
  const float m1r = sm1[tid], m2r = sm2[tid];
  const int j1r = sj1[tid];

  const float* xr = x + ((size_t)n * WD) * TD + t;
#define LOADX(w) float x##w = xr[(size_t)(w) * TD];
  REP64(LOADX)
#undef LOADX

  NP_SUMSQ64_NAMED(s)

  double xsum = 0.0, xsumsq = 0.0;
#define PRE(w) { double xd = (double)x##w; xsum += xd; xsumsq = fma(xd, xd, xsumsq); }
  REP64(PRE)
#undef PRE

  const float4* k4 = (const float4*)(k + (size_t)j1r * WD);
  float* xo = out + OFF_XD + ((size_t)n * WD) * TD + t;
  double commit = 0.0;
  float g = 0.f;
#define EPI1(w, KW) { \
    float kw = KW; \
    float diff = __fsub_rn(kw, x##w); \
    commit = fma((double)diff, (double)diff, commit); \
    g = __fmaf_rn(x##w, kw, g); \
    xo[(size_t)(w) * TD] = __fadd_rn(x##w, diff); }
  {
    float4 ka = k4[0], kb = k4[1], kc = k4[2], kd = k4[3];
    EPI1(0, ka.x) EPI1(1, ka.y) EPI1(2, ka.z) EPI1(3, ka.w)
    EPI1(4, kb.x) EPI1(5, kb.y) EPI1(6, kb.z) EPI1(7, kb.w)
    EPI1(8, kc.x) EPI1(9, kc.y) EPI1(10, kc.z) EPI1(11, kc.w)
    EPI1(12, kd.x) EPI1(13, kd.y) EPI1(14, kd.z) EPI1(15, kd.w)
  }
  {
    float4 ka = k4[4], kb = k4[5], kc = k4[6], kd = k4[7];
    EPI1(16, ka.x) EPI1(17, ka.y) EPI1(18, ka.z) EPI1(19, ka.w)
    EPI1(20, kb.x) EPI1(21, kb.y) EPI1(22, kb.z) EPI1(23, kb.w)
    EPI1(24, kc.x) EPI1(25, kc.y) EPI1(26, kc.z) EPI1(27, kc.w)
    EPI1(28, kd.x) EPI1(29, kd.y) EPI1(30, kd.z) EPI1(31, kd.w)
  }
  {
    float4 ka = k4[8], kb = k4[9], kc = k4[10], kd = k4[11];
    EPI1(32, ka.x) EPI1(33, ka.y) EPI1(34, ka.z) EPI1(35, ka.w)
    EPI1(36, kb.x) EPI1(37, kb.y) EPI1(38, kb.z) EPI1(39, kb.w)
    EPI1(40, kc.x) EPI1(41, kc.y) EPI1(42, kc.z) EPI1(43, kc.w)
    EPI1(44, kd.x) EPI1(45, kd.y) EPI1(46, kd.z) EPI1(47, kd.w)
  }
  {
    float4 ka = k4[12], kb = k4[13], kc = k4[14], kd = k4[15];
    EPI1(48, ka.x) EPI1(49, ka.y) EPI1(50, ka.z) EPI1(51, ka.w)
    EPI1(52, kb.x) EPI1(53, kb.y) EPI1(54, kb.z) EPI1(55, kb.w)
    EPI1(56, kc.x) EPI1(57, kc.y) EPI1(58, kc.z) EPI1(59, kc.w)
    EPI1(60, kd.x) EPI1(61, kd.y) EPI1(62, kd.z) EPI1(63, kd.w)
  }
#undef EPI1

  float kn2j = ((const float*)(wsb + KN2_OFF))[j1r];
  float score = kn2j - 2.f * g;
  bool resc = (m2r - m1r < EPS_GAP) || (fabsf(score - m1r) > VEPS);
  float dist1 = __fadd_rn(__fsub_rn(s, __fmul_rn(2.f, g)), kn2j);

  out[OFF_XL + row] = (float)j1r;
  if (resc) {
    unsigned idx = atomicAdd((unsigned*)(wsb + CNT_OFF), 1u);
    ((int*)(wsb + LIST_OFF))[idx] = row;
    if (idx < XRCAP) {
      float* xrw = (float*)(wsb + XR_OFF) + (size_t)idx * WD;
#define XWR(w) xrw[w] = x##w;
      REP64(XWR)
#undef XWR
    }
  }

  // block reduction of 4 fp64 partials -> plain stores (no atomics)
  double v0 = xsum, v1 = xsumsq;
  double v2 = resc ? 0.0 : (double)dist1;
  double v3 = resc ? 0.0 : commit;
#pragma unroll
  for (int off = 32; off > 0; off >>= 1) {
    v0 += __shfl_down(v0, off, 64);
    v1 += __shfl_down(v1, off, 64);
    v2 += __shfl_down(v2, off, 64);
    v3 += __shfl_down(v3, off, 64);
  }
  if ((tid & 63) == 0) {
    int wv = tid >> 6;
    sred[wv * 4 + 0] = v0;
    sred[wv * 4 + 1] = v1;
    sred[wv * 4 + 2] = v2;
    sred[wv * 4 + 3] = v3;
  }
  __syncthreads();
  if (tid == 0) {
    double a0 = 0, a1 = 0, a2 = 0, a3 = 0;
#pragma unroll
    for (int w2 = 0; w2 < 4; ++w2) {
      a0 += sred[w2 * 4 + 0];
      a1 += sred[w2 * 4 + 1];
      a2 += sred[w2 * 4 + 2];
      a3 += sred[w2 * 4 + 3];
    }
    double* pb = (double*)(wsb + PB_OFF) + (size_t)blockIdx.x * 4;
    pb[0] = a0; pb[1] = a1; pb[2] = a2; pb[3] = a3;
  }
}

// ---------- K3: exact rescan, 4 rows/block, per-slot results (no hot atomics) ----------
__global__ __launch_bounds__(256)
void vq_rescan7(const float* __restrict__ x, const float* __restrict__ k,
                float* __restrict__ out, char* __restrict__ wsb) {
  __shared__ float xs[4][WD];
  __shared__ float ss[4];
  __shared__ unsigned long long wred[4][4];   // [row][wave]
  __shared__ unsigned long long bbest[4];
  const unsigned count = *(const unsigned*)(wsb + CNT_OFF);
  const int* list = (const int*)(wsb + LIST_OFF);
  const float* kn2 = (const float*)(wsb + KN2_OFF);
  const float* XR = (const float*)(wsb + XR_OFF);
  const float* kT = (const float*)(wsb + KT_OFF);
  double* fitv = (double*)(wsb + FITV_OFF);
  double* cmv = (double*)(wsb + CMV_OFF);
  const int tid = threadIdx.x;
  const int lane = tid & 63, wv = tid >> 6;
  const int c0 = tid * 8;

  for (unsigned base = blockIdx.x * 4u; base < count; base += gridDim.x * 4u) {
    __syncthreads();                       // xs/ss/wred reuse guard
    {
      const int r = tid >> 6, w = tid & 63;
      const unsigned li = base + (unsigned)r;
      if (li < count) {
        if (li < XRCAP) {
          xs[r][w] = XR[(size_t)li * WD + w];
        } else {
          const int row = list[li];
          const int n = row >> 13, t = row & (TD - 1);
          xs[r][w] = x[(size_t)n * WD * TD + (size_t)w * TD + t];
        }
      }
    }
    __syncthreads();
    if (lane == 0) ss[wv] = np_sumsq64_ptr(xs[wv]);
    __syncthreads();
    const float s0 = ss[0], s1 = ss[1], s2 = ss[2], s3 = ss[3];

    float a00 = 0.f, a01 = 0.f, a02 = 0.f, a03 = 0.f, a04 = 0.f, a05 = 0.f, a06 = 0.f, a07 = 0.f;
    float a10 = 0.f, a11 = 0.f, a12 = 0.f, a13 = 0.f, a14 = 0.f, a15 = 0.f, a16 = 0.f, a17 = 0.f;
    float a20 = 0.f, a21 = 0.f, a22 = 0.f, a23 = 0.f, a24 = 0.f, a25 = 0.f, a26 = 0.f, a27 = 0.f;
    float a30 = 0.f, a31 = 0.f, a32 = 0.f, a33 = 0.f, a34 = 0.f, a35 = 0.f, a36 = 0.f, a37 = 0.f;
    const float* kt = kT + c0;
#pragma unroll 4
    for (int w = 0; w < WD; ++w) {
      const float4 ka = *(const float4*)(kt + (size_t)w * KB);
      const float4 kb = *(const float4*)(kt + (size_t)w * KB + 4);
      const float xw0 = xs[0][w], xw1 = xs[1][w], xw2 = xs[2][w], xw3 = xs[3][w];
      a00 = __fmaf_rn(xw0, ka.x, a00); a01 = __fmaf_rn(xw0, ka.y, a01);
      a02 = __fmaf_rn(xw0, ka.z, a02); a03 = __fmaf_rn(xw0, ka.w, a03);
      a04 = __fmaf_rn(xw0, kb.x, a04); a05 = __fmaf_rn(xw0, kb.y, a05);
      a06 = __fmaf_rn(xw0, kb.z, a06); a07 = __fmaf_rn(xw0, kb.w, a07);
      a10 = __fmaf_rn(xw1, ka.x, a10); a11 = __fmaf_rn(xw1, ka.y, a11);
      a12 = __fmaf_rn(xw1, ka.z, a12); a13 = __fmaf_rn(xw1, ka.w, a13);
      a14 = __fmaf_rn(xw1, kb.x, a14); a15 = __fmaf_rn(xw1, kb.y, a15);
      a16 = __fmaf_rn(xw1, kb.z, a16); a17 = __fmaf_rn(xw1, kb.w, a17);
      a20 = __fmaf_rn(xw2, ka.x, a20); a21 = __fmaf_rn(xw2, ka.y, a21);
      a22 = __fmaf_rn(xw2, ka.z, a22); a23 = __fmaf_rn(xw2, ka.w, a23);
      a24 = __fmaf_rn(xw2, kb.x, a24); a25 = __fmaf_rn(xw2, kb.y, a25);
      a26 = __fmaf_rn(xw2, kb.z, a26); a27 = __fmaf_rn(xw2, kb.w, a27);
      a30 = __fmaf_rn(xw3, ka.x, a30); a31 = __fmaf_rn(xw3, ka.y, a31);
      a32 = __fmaf_rn(xw3, ka.z, a32); a33 = __fmaf_rn(xw3, ka.w, a33);
      a34 = __fmaf_rn(xw3, kb.x, a34); a35 = __fmaf_rn(xw3, kb.y, a35);
      a36 = __fmaf_rn(xw3, kb.z, a36); a37 = __fmaf_rn(xw3, kb.w, a37);
    }

#define ROWBEST(R, SV, A0, A1, A2, A3, A4, A5, A6, A7) { \
      unsigned long long best = ~0ull; \
      float d; unsigned long long p; \
      d = __fadd_rn(__fsub_rn(SV, __fmul_rn(2.f, A0)), kn2[c0 + 0]); \
      p = ((unsigned long long)__float_as_uint(d) << 32) | (unsigned)(c0 + 0); best = p < best ? p : best; \
      d = __fadd_rn(__fsub_rn(SV, __fmul_rn(2.f, A1)), kn2[c0 + 1]); \
      p = ((unsigned long long)__float_as_uint(d) << 32) | (unsigned)(c0 + 1); best = p < best ? p : best; \
      d = __fadd_rn(__fsub_rn(SV, __fmul_rn(2.f, A2)), kn2[c0 + 2]); \
      p = ((unsigned long long)__float_as_uint(d) << 32) | (unsigned)(c0 + 2); best = p < best ? p : best; \
      d = __fadd_rn(__fsub_rn(SV, __fmul_rn(2.f, A3)), kn2[c0 + 3]); \
      p = ((unsigned long long)__float_as_uint(d) << 32) | (unsigned)(c0 + 3); best = p < best ? p : best; \
      d = __fadd_rn(__fsub_rn(SV, __fmul_rn(2.f, A4)), kn2[c0 + 4]); \
      p = ((unsigned long long)__float_as_uint(d) << 32) | (unsigned)(c0 + 4); best = p < best ? p : best; \
      d = __fadd_rn(__fsub_rn(SV, __fmul_rn(2.f, A5)), kn2[c0 + 5]); \
      p = ((unsigned long long)__float_as_uint(d) << 32) | (unsigned)(c0 + 5); best = p < best ? p : best; \
      d = __fadd_rn(__fsub_rn(SV, __fmul_rn(2.f, A6)), kn2[c0 + 6]); \
      p = ((unsigned long long)__float_as_uint(d) << 32) | (unsigned)(c0 + 6); best = p < best ? p : best; \
      d = __fadd_rn(__fsub_rn(SV, __fmul_rn(2.f, A7)), kn2[c0 + 7]); \
      p = ((unsigned long long)__float_as_uint(d) << 32) | (unsigned)(c0 + 7); best = p < best ? p : best; \
      _Pragma("unroll") \
      for (int dd = 1; dd < 64; dd <<= 1) { \
        unsigned lo = (unsigned)best, hi = (unsigned)(best >> 32); \
        unsigned olo = __shfl_xor(lo, dd, 64); \
        unsigned ohi = __shfl_xor(hi, dd, 64); \
        unsigned long long o = ((unsigned long long)ohi << 32) | olo; \
        best = o < best ? o : best; \
      } \
      if (lane == 0) wred[R][wv] = best; }
    ROWBEST(0, s0, a00, a01, a02, a03, a04, a05, a06, a07)
    ROWBEST(1, s1, a10, a11, a12, a13, a14, a15, a16, a17)
    ROWBEST(2, s2, a20, a21, a22, a23, a24, a25, a26, a27)
    ROWBEST(3, s3, a30, a31, a32, a33, a34, a35, a36, a37)
#undef ROWBEST
    __syncthreads();
    if (tid < 4) {
      unsigned long long b = wred[tid][0];
      b = wred[tid][1] < b ? wred[tid][1] : b;
      b = wred[tid][2] < b ? wred[tid][2] : b;
      b = wred[tid][3] < b ? wred[tid][3] : b;
      bbest[tid] = b;
    }
    __syncthreads();

    {
      const int r = wv, w = lane;
      const unsigned li = base + (unsigned)r;
      if (li < count) {
        const int row = list[li];
        const int n = row >> 13, t = row & (TD - 1);
        const unsigned long long fb = bbest[r];
        const int bi = (int)(fb & 0xffffffffu);
        const float bv = __uint_as_float((unsigned)(fb >> 32));
        float kw = k[(size_t)bi * WD + w];
        float xw = xs[r][w];
        float diff = __fsub_rn(kw, xw);
        out[OFF_XD + (size_t)n * WD * TD + (size_t)w * TD + t] = __fadd_rn(xw, diff);
        double d2 = (double)diff * (double)diff;
#pragma unroll
        for (int dd = 32; dd > 0; dd >>= 1) d2 += __shfl_down(d2, dd, 64);
        if (w == 0) {
          out[OFF_XL + row] = (float)bi;
          fitv[li] = (double)bv;
          cmv[li] = d2;
        }
      }
    }
  }
}

// ---------- K4: final scalars — reduce PB partials + rescan arrays ----------
__global__ __launch_bounds__(256)
void vq_final(const char* __restrict__ wsb, float* __restrict__ out) {
  __shared__ double sred[24];
  const unsigned count = *(const unsigned*)(wsb + CNT_OFF);
  const double* fitv = (const double*)(wsb + FITV_OFF);
  const double* cmv = (const double*)(wsb + CMV_OFF);
  const double* pb = (const double*)(wsb + PB_OFF);
  const int tid = threadIdx.x;

  double fa = 0.0, ca = 0.0;
  for (unsigned i = tid; i < count; i += 256) {
    fa += fitv[i];
    ca += cmv[i];
  }
  double b0 = 0.0, b1 = 0.0, b2 = 0.0, b3 = 0.0;
  for (int i = tid; i < 512; i += 256) {
    b0 += pb[i * 4 + 0];
    b1 += pb[i * 4 + 1];
    b2 += pb[i * 4 + 2];
    b3 += pb[i * 4 + 3];
  }
#pragma unroll
  for (int off = 32; off > 0; off >>= 1) {
    fa += __shfl_down(fa, off, 64);
    ca += __shfl_down(ca, off, 64);
    b0 += __shfl_down(b0, off, 64);
    b1 += __shfl_down(b1, off, 64);
    b2 += __shfl_down(b2, off, 64);
    b3 += __shfl_down(b3, off, 64);
  }
  if ((tid & 63) == 0) {
    int wv = tid >> 6;
    sred[wv * 6 + 0] = fa;
    sred[wv * 6 + 1] = ca;
    sred[wv * 6 + 2] = b0;
    sred[wv * 6 + 3] = b1;
    sred[wv * 6 + 4] = b2;
    sred[wv * 6 + 5] = b3;
  }
  __syncthreads();
  if (tid == 0) {
    double fit = 0, cm = 0, sum = 0, sumsq = 0;
#pragma unroll
    for (int i = 0; i < 4; ++i) {
      fit += sred[i * 6 + 0] + sred[i * 6 + 4];   // rescan fit + block fit
      cm += sred[i * 6 + 1] + sred[i * 6 + 5];    // rescan commit + block commit
      sum += sred[i * 6 + 2];
      sumsq += sred[i * 6 + 3];
    }
    double mean = sum / 8388608.0;
    double ss = sumsq - sum * mean;
    if (ss < 0.0) ss = 0.0;
    out[OFF_SC + 0] = (float)(cm / 8388608.0);         // commit_loss
    out[OFF_SC + 1] = (float)(fit / 131072.0);         // fit
    out[OFF_SC + 2] = (float)sqrt(ss / 8388608.0);     // prenorm
  }
}

extern "C" void kernel_launch(void* const* d_in, const int* in_sizes, int n_in,
                              void* d_out, int out_size, void* d_ws, size_t ws_size,
                              hipStream_t stream) {
  const float* x = (const float*)d_in[0];
  const float* k = (const float*)d_in[1];
  float* out = (float*)d_out;
  char* wsb = (char*)d_ws;

  hipMemsetAsync(d_ws, 0, 64, stream);                 // count (+ reserved)
  vq_prep<<<KB / 256, 256, 0, stream>>>(k, wsb);
  vq_scan<<<NT / 256, 256, 0, stream>>>(x, k, out, wsb);
  vq_rescan7<<<1024, 256, 0, stream>>>(x, k, out, wsb);
  vq_final<<<1, 256, 0, stream>>>(wsb, out);
}

// Round 19
// 160.756 us; speedup vs baseline: 2.2533x; 1.2015x over previous
//
#include <hip/hip_runtime.h>
#include <math.h>

#define WD 64
#define TD 8192
#define NT 131072           // 16 * 8192 rows
#define KB 2048
// Output layout (float32, concatenated): x_l [NT], x_d [NT*WD], commit, fit, prenorm
#define OFF_XL 0
#define OFF_XD NT
#define OFF_SC (NT + NT * WD)

// ws layout (bytes)
#define CNT_OFF   32                     // uint: rescan count
#define KN2_OFF   4096                   // float[2048] np-exact ||k||^2
#define CB_OFF    16384                  // bf16 B-frags: 128jt * 4frag * 64lane * 16B = 512KB
#define LIST_OFF  (16384 + 524288)       // int[NT] rescan rows
#define KT_OFF    (LIST_OFF + 4 * NT)    // float[64][2048] transposed codebook (512KB)
#define XR_OFF    (KT_OFF + 8 * NT)      // float[XRCAP][64] compacted rescan rows (8MB)
#define FITV_OFF  (XR_OFF + XRCAP * WD * 4)  // double[NT] per-rescan-slot min dist
#define CMV_OFF   (FITV_OFF + 8 * NT)        // double[NT] per-rescan-slot commit part
#define PB_OFF    (CMV_OFF + 8 * NT)         // double[512][4] per-block partials
#define XRCAP     32768                  // cap (count ~700 expected at 1e-3 gap)

// r18->r19: EPS_GAP 4e-3 -> 1e-3. Error budget: bf16x3 split residual
// (|x||k|*2^-16 ~ 2e-5) + MFMA fp32 accum (~1e-6) + packed-index truncation
// (2^-17*|acc| ~ 1e-5) => max score error ~4e-5; argmin flip needs true gap
// < ~1e-4; 1e-3 keeps 10x margin. VEPS backstop unchanged.
#define EPS_GAP 1e-3f
#define VEPS    2e-3f

typedef __attribute__((ext_vector_type(8))) short bf16x8_t;  // 8 bf16 (4 VGPRs)
typedef __attribute__((ext_vector_type(4))) float f32x4_t;

__device__ __forceinline__ unsigned short bf16_rne(float f) {
  unsigned int u = __float_as_uint(f);
  unsigned int r = u + 0x7fffu + ((u >> 16) & 1u);
  return (unsigned short)(r >> 16);
}

#define REP64(F) F(0) F(1) F(2) F(3) F(4) F(5) F(6) F(7) \
  F(8) F(9) F(10) F(11) F(12) F(13) F(14) F(15) \
  F(16) F(17) F(18) F(19) F(20) F(21) F(22) F(23) \
  F(24) F(25) F(26) F(27) F(28) F(29) F(30) F(31) \
  F(32) F(33) F(34) F(35) F(36) F(37) F(38) F(39) \
  F(40) F(41) F(42) F(43) F(44) F(45) F(46) F(47) \
  F(48) F(49) F(50) F(51) F(52) F(53) F(54) F(55) \
  F(56) F(57) F(58) F(59) F(60) F(61) F(62) F(63)

// numpy pairwise_sum (scalar 8-accumulator, n=64) of PRE-ROUNDED squares; *_rn
// intrinsics forbid contraction. Bit-exact vs np.sum(a*a, -1) (verified r2-r18).
#define NP_SUMSQ64_NAMED(SVAR) \
  float r0 = __fmul_rn(x0, x0); \
  float r1 = __fmul_rn(x1, x1); \
  float r2 = __fmul_rn(x2, x2); \
  float r3 = __fmul_rn(x3, x3); \
  float r4 = __fmul_rn(x4, x4); \
  float r5 = __fmul_rn(x5, x5); \
  float r6 = __fmul_rn(x6, x6); \
  float r7 = __fmul_rn(x7, x7); \
  SQ8(8, 9, 10, 11, 12, 13, 14, 15) \
  SQ8(16, 17, 18, 19, 20, 21, 22, 23) \
  SQ8(24, 25, 26, 27, 28, 29, 30, 31) \
  SQ8(32, 33, 34, 35, 36, 37, 38, 39) \
  SQ8(40, 41, 42, 43, 44, 45, 46, 47) \
  SQ8(48, 49, 50, 51, 52, 53, 54, 55) \
  SQ8(56, 57, 58, 59, 60, 61, 62, 63) \
  const float SVAR = __fadd_rn(__fadd_rn(__fadd_rn(r0, r1), __fadd_rn(r2, r3)), \
                               __fadd_rn(__fadd_rn(r4, r5), __fadd_rn(r6, r7)));
#define SQ8(a,b,c,d,e,f,g,h) \
  r0 = __fadd_rn(r0, __fmul_rn(x##a, x##a)); \
  r1 = __fadd_rn(r1, __fmul_rn(x##b, x##b)); \
  r2 = __fadd_rn(r2, __fmul_rn(x##c, x##c)); \
  r3 = __fadd_rn(r3, __fmul_rn(x##d, x##d)); \
  r4 = __fadd_rn(r4, __fmul_rn(x##e, x##e)); \
  r5 = __fadd_rn(r5, __fmul_rn(x##f, x##f)); \
  r6 = __fadd_rn(r6, __fmul_rn(x##g, x##g)); \
  r7 = __fadd_rn(r7, __fmul_rn(x##h, x##h));

__device__ __forceinline__ float np_sumsq64_ptr(const float* a) {
  float r0 = __fmul_rn(a[0], a[0]);
  float r1 = __fmul_rn(a[1], a[1]);
  float r2 = __fmul_rn(a[2], a[2]);
  float r3 = __fmul_rn(a[3], a[3]);
  float r4 = __fmul_rn(a[4], a[4]);
  float r5 = __fmul_rn(a[5], a[5]);
  float r6 = __fmul_rn(a[6], a[6]);
  float r7 = __fmul_rn(a[7], a[7]);
#pragma unroll
  for (int i = 8; i < 64; i += 8) {
    r0 = __fadd_rn(r0, __fmul_rn(a[i + 0], a[i + 0]));
    r1 = __fadd_rn(r1, __fmul_rn(a[i + 1], a[i + 1]));
    r2 = __fadd_rn(r2, __fmul_rn(a[i + 2], a[i + 2]));
    r3 = __fadd_rn(r3, __fmul_rn(a[i + 3], a[i + 3]));
    r4 = __fadd_rn(r4, __fmul_rn(a[i + 4], a[i + 4]));
    r5 = __fadd_rn(r5, __fmul_rn(a[i + 5], a[i + 5]));
    r6 = __fadd_rn(r6, __fmul_rn(a[i + 6], a[i + 6]));
    r7 = __fadd_rn(r7, __fmul_rn(a[i + 7], a[i + 7]));
  }
  float t01 = __fadd_rn(r0, r1);
  float t23 = __fadd_rn(r2, r3);
  float t45 = __fadd_rn(r4, r5);
  float t67 = __fadd_rn(r6, r7);
  return __fadd_rn(__fadd_rn(t01, t23), __fadd_rn(t45, t67));
}

// ---------- K0: kn2_np + bf16 B-frags + transposed codebook kT[w][c] ----------
__global__ __launch_bounds__(256)
void vq_prep(const float* __restrict__ k, char* __restrict__ wsb) {
  int c = blockIdx.x * 256 + threadIdx.x;
  if (c >= KB) return;
  const float* kr = k + (size_t)c * WD;
  ((float*)(wsb + KN2_OFF))[c] = np_sumsq64_ptr(kr);
  float* kt = (float*)(wsb + KT_OFF);
#pragma unroll
  for (int w = 0; w < WD; ++w) kt[(size_t)w * KB + c] = kr[w];
  int jt = c >> 4, col = c & 15;
  unsigned short* cb = (unsigned short*)(wsb + CB_OFF);
#pragma unroll
  for (int w = 0; w < WD; ++w) {
    float f = kr[w];
    unsigned short hb = bf16_rne(f);
    float hf = __uint_as_float((unsigned int)hb << 16);
    unsigned short lb = bf16_rne(f - hf);
    int fH = w >> 5;                       // K-half: frag 0/1 (hi), 2/3 (lo)
    int lane = col | (((w >> 3) & 3) << 4);
    int e = w & 7;
    cb[((size_t)((jt * 4 + fH) * 64 + lane)) * 8 + e] = hb;
    cb[((size_t)((jt * 4 + 2 + fH) * 64 + lane)) * 8 + e] = lb;
  }
}

// ---------- K1: FUSED scan + finalize (8-jt chunks) ----------
// r18 fusion kept; r19: chunks of 8 jt (2x32KB dbuf) halve barrier count
// (32 -> 16 drains of the staging pipeline).
__global__ __launch_bounds__(256) __attribute__((amdgpu_waves_per_eu(2)))
void vq_scan(const float* __restrict__ x, const float* __restrict__ k,
             float* __restrict__ out, char* __restrict__ wsb) {
  __shared__ float lkn2n[KB];         // 8KB: -0.5 * ||k||^2 (prescaled)
  __shared__ char cbuf[2][32768];     // 64KB double-buffered B-frag chunks (8 jt)
  __shared__ float sm1[256], sm2[256];
  __shared__ int sj1[256];
  __shared__ double sred[16];
  const int tid = threadIdx.x, lane = tid & 63, wave = tid >> 6;  // 4 waves
  const int col = lane & 15, grp = lane >> 4;

  for (int i = tid; i < KB; i += 256)
    lkn2n[i] = -0.5f * ((const float*)(wsb + KN2_OFF))[i];

  const int n = blockIdx.x >> 5;           // 32 blocks per n (8192/256)
  const int t0 = (blockIdx.x & 31) * 256;
  const float* xb = x + (size_t)n * WD * TD;

  // A-frags: wave owns 4 tiles (64 rows): rows t0 + wave*64 + T*16 + (grp*4+e)
  bf16x8_t aH[4][2], aL[4][2];
#pragma unroll
  for (int T = 0; T < 4; ++T) {
    const int trow = t0 + wave * 64 + T * 16 + col;
#pragma unroll
    for (int s = 0; s < 2; ++s) {
#pragma unroll
      for (int e = 0; e < 8; ++e) {
        int w = s * 32 + grp * 8 + e;
        float f = xb[(size_t)w * TD + trow];
        unsigned short hb = bf16_rne(f);
        float hf = __uint_as_float((unsigned int)hb << 16);
        unsigned short lb = bf16_rne(f - hf);
        aH[T][s][e] = (short)hb;
        aL[T][s][e] = (short)lb;
      }
    }
  }

  // packed argmax trackers: value bits [31:7], jt in bits [6:0]
  float M1[4][4], M2[4][4];
#pragma unroll
  for (int T = 0; T < 4; ++T)
#pragma unroll
    for (int e = 0; e < 4; ++e) {
      M1[T][e] = -INFINITY; M2[T][e] = -INFINITY;
    }

  const char* cbsrc = wsb + CB_OFF;
  float4 pf0, pf1, pf2, pf3, pf4, pf5, pf6, pf7;
#define PREF(c) { const float4* sp = (const float4*)(cbsrc + (size_t)(c) * 32768); \
    pf0 = sp[tid]; pf1 = sp[tid + 256]; pf2 = sp[tid + 512]; pf3 = sp[tid + 768]; \
    pf4 = sp[tid + 1024]; pf5 = sp[tid + 1280]; pf6 = sp[tid + 1536]; pf7 = sp[tid + 1792]; }
#define WRBUF(b) { float4* dp = (float4*)cbuf[b]; \
    dp[tid] = pf0; dp[tid + 256] = pf1; dp[tid + 512] = pf2; dp[tid + 768] = pf3; \
    dp[tid + 1024] = pf4; dp[tid + 1280] = pf5; dp[tid + 1536] = pf6; dp[tid + 1792] = pf7; }

  PREF(0)
  WRBUF(0)
  PREF(1)
  __syncthreads();

  for (int c = 0; c < 16; ++c) {
    const int cur = c & 1;
    if (c < 15) WRBUF(cur ^ 1)
    if (c < 14) PREF(c + 2)
#pragma unroll
    for (int jl = 0; jl < 8; ++jl) {
      const bf16x8_t* bp = (const bf16x8_t*)(cbuf[cur] + jl * 4096) + lane;
      bf16x8_t bH0 = bp[0], bH1 = bp[64], bL0 = bp[128], bL1 = bp[192];
      const int jt = c * 8 + jl;
      const float ci = lkn2n[jt * 16 + col];
#pragma unroll
      for (int T = 0; T < 4; ++T) {
        f32x4_t acc = {ci, ci, ci, ci};
        acc = __builtin_amdgcn_mfma_f32_16x16x32_bf16(aH[T][0], bH0, acc, 0, 0, 0);
        acc = __builtin_amdgcn_mfma_f32_16x16x32_bf16(aH[T][1], bH1, acc, 0, 0, 0);
        acc = __builtin_amdgcn_mfma_f32_16x16x32_bf16(aL[T][0], bH0, acc, 0, 0, 0);
        acc = __builtin_amdgcn_mfma_f32_16x16x32_bf16(aL[T][1], bH1, acc, 0, 0, 0);
        acc = __builtin_amdgcn_mfma_f32_16x16x32_bf16(aH[T][0], bL0, acc, 0, 0, 0);
        acc = __builtin_amdgcn_mfma_f32_16x16x32_bf16(aH[T][1], bL1, acc, 0, 0, 0);
#pragma unroll
        for (int e = 0; e < 4; ++e) {
          float vp = __uint_as_float(
              (__float_as_uint(acc[e]) & 0xFFFFFF80u) | (unsigned)jt);
          M2[T][e] = __builtin_amdgcn_fmed3f(M1[T][e], M2[T][e], vp);
          M1[T][e] = fmaxf(M1[T][e], vp);
        }
      }
    }
    __syncthreads();
  }
#undef PREF
#undef WRBUF

  // cross-lane reduce -> per-row (m1,m2,j1) into LDS
#pragma unroll
  for (int T = 0; T < 4; ++T)
#pragma unroll
    for (int e = 0; e < 4; ++e) {
      float m1 = M1[T][e], m2 = M2[T][e];
      int cd = (int)(__float_as_uint(m1) & 0x7Fu) * 16 + col;
#pragma unroll
      for (int d = 1; d < 16; d <<= 1) {
        float om1 = __shfl_xor(m1, d, 64);
        float om2 = __shfl_xor(m2, d, 64);
        int ocd = __shfl_xor(cd, d, 64);
        bool take = (om1 > m1) || (om1 == m1 && ocd < cd);
        float loser = take ? m1 : om1;
        m2 = fmaxf(fmaxf(m2, om2), loser);
        m1 = take ? om1 : m1;
        cd = take ? ocd : cd;
      }
      if (col == 0) {
        int r = wave * 64 + T * 16 + grp * 4 + e;
        sm1[r] = -2.f * m1;                // score domain
        sm2[r] = -2.f * m2;
        sj1[r] = cd;
      }
    }
  __syncthreads();

  // ---- fused finalize: one row per thread ----
  const int row = blockIdx.x * 256 + tid;
  const int t = row & (TD - 1);
  const float m1r = sm1[tid], m2r = sm2[tid];
  const int j1r = sj1[tid];

  const float* xr = x + ((size_t)n * WD) * TD + t;
#define LOADX(w) float x##w = xr[(size_t)(w) * TD];
  REP64(LOADX)
#undef LOADX

  NP_SUMSQ64_NAMED(s)

  double xsum = 0.0, xsumsq = 0.0;
#define PRE(w) { double xd = (double)x##w; xsum += xd; xsumsq = fma(xd, xd, xsumsq); }
  REP64(PRE)
#undef PRE

  const float4* k4 = (const float4*)(k + (size_t)j1r * WD);
  float* xo = out + OFF_XD + ((size_t)n * WD) * TD + t;
  double commit = 0.0;
  float g = 0.f;
#define EPI1(w, KW) { \
    float kw = KW; \
    float diff = __fsub_rn(kw, x##w); \
    commit = fma((double)diff, (double)diff, commit); \
    g = __fmaf_rn(x##w, kw, g); \
    xo[(size_t)(w) * TD] = __fadd_rn(x##w, diff); }
  {
    float4 ka = k4[0], kb = k4[1], kc = k4[2], kd = k4[3];
    EPI1(0, ka.x) EPI1(1, ka.y) EPI1(2, ka.z) EPI1(3, ka.w)
    EPI1(4, kb.x) EPI1(5, kb.y) EPI1(6, kb.z) EPI1(7, kb.w)
    EPI1(8, kc.x) EPI1(9, kc.y) EPI1(10, kc.z) EPI1(11, kc.w)
    EPI1(12, kd.x) EPI1(13, kd.y) EPI1(14, kd.z) EPI1(15, kd.w)
  }
  {
    float4 ka = k4[4], kb = k4[5], kc = k4[6], kd = k4[7];
    EPI1(16, ka.x) EPI1(17, ka.y) EPI1(18, ka.z) EPI1(19, ka.w)
    EPI1(20, kb.x) EPI1(21, kb.y) EPI1(22, kb.z) EPI1(23, kb.w)
    EPI1(24, kc.x) EPI1(25, kc.y) EPI1(26, kc.z) EPI1(27, kc.w)
    EPI1(28, kd.x) EPI1(29, kd.y) EPI1(30, kd.z) EPI1(31, kd.w)
  }
  {
    float4 ka = k4[8], kb = k4[9], kc = k4[10], kd = k4[11];
    EPI1(32, ka.x) EPI1(33, ka.y) EPI1(34, ka.z) EPI1(35, ka.w)
    EPI1(36, kb.x) EPI1(37, kb.y) EPI1(38, kb.z) EPI1(39, kb.w)
    EPI1(40, kc.x) EPI1(41, kc.y) EPI1(42, kc.z) EPI1(43, kc.w)
    EPI1(44, kd.x) EPI1(45, kd.y) EPI1(46, kd.z) EPI1(47, kd.w)
  }
  {
    float4 ka = k4[12], kb = k4[13], kc = k4[14], kd = k4[15];
    EPI1(48, ka.x) EPI1(49, ka.y) EPI1(50, ka.z) EPI1(51, ka.w)
    EPI1(52, kb.x) EPI1(53, kb.y) EPI1(54, kb.z) EPI1(55, kb.w)
    EPI1(56, kc.x) EPI1(57, kc.y) EPI1(58, kc.z) EPI1(59, kc.w)
    EPI1(60, kd.x) EPI1(61, kd.y) EPI1(62, kd.z) EPI1(63, kd.w)
  }
#undef EPI1

  float kn2j = ((const float*)(wsb + KN2_OFF))[j1r];
  float score = kn2j - 2.f * g;
  bool resc = (m2r - m1r < EPS_GAP) || (fabsf(score - m1r) > VEPS);
  float dist1 = __fadd_rn(__fsub_rn(s, __fmul_rn(2.f, g)), kn2j);

  out[OFF_XL + row] = (float)j1r;
  if (resc) {
    unsigned idx = atomicAdd((unsigned*)(wsb + CNT_OFF), 1u);
    ((int*)(wsb + LIST_OFF))[idx] = row;
    if (idx < XRCAP) {
      float* xrw = (float*)(wsb + XR_OFF) + (size_t)idx * WD;
#define XWR(w) xrw[w] = x##w;
      REP64(XWR)
#undef XWR
    }
  }

  // block reduction of 4 fp64 partials -> plain stores (no atomics)
  double v0 = xsum, v1 = xsumsq;
  double v2 = resc ? 0.0 : (double)dist1;
  double v3 = resc ? 0.0 : commit;
#pragma unroll
  for (int off = 32; off > 0; off >>= 1) {
    v0 += __shfl_down(v0, off, 64);
    v1 += __shfl_down(v1, off, 64);
    v2 += __shfl_down(v2, off, 64);
    v3 += __shfl_down(v3, off, 64);
  }
  if ((tid & 63) == 0) {
    int wv = tid >> 6;
    sred[wv * 4 + 0] = v0;
    sred[wv * 4 + 1] = v1;
    sred[wv * 4 + 2] = v2;
    sred[wv * 4 + 3] = v3;
  }
  __syncthreads();
  if (tid == 0) {
    double a0 = 0, a1 = 0, a2 = 0, a3 = 0;
#pragma unroll
    for (int w2 = 0; w2 < 4; ++w2) {
      a0 += sred[w2 * 4 + 0];
      a1 += sred[w2 * 4 + 1];
      a2 += sred[w2 * 4 + 2];
      a3 += sred[w2 * 4 + 3];
    }
    double* pb = (double*)(wsb + PB_OFF) + (size_t)blockIdx.x * 4;
    pb[0] = a0; pb[1] = a1; pb[2] = a2; pb[3] = a3;
  }
}

// ---------- K3: exact rescan, 4 rows/block, per-slot results (no hot atomics) ----------
__global__ __launch_bounds__(256)
void vq_rescan7(const float* __restrict__ x, const float* __restrict__ k,
                float* __restrict__ out, char* __restrict__ wsb) {
  __shared__ float xs[4][WD];
  __shared__ float ss[4];
  __shared__ unsigned long long wred[4][4];   // [row][wave]
  __shared__ unsigned long long bbest[4];
  const unsigned count = *(const unsigned*)(wsb + CNT_OFF);
  const int* list = (const int*)(wsb + LIST_OFF);
  const float* kn2 = (const float*)(wsb + KN2_OFF);
  const float* XR = (const float*)(wsb + XR_OFF);
  const float* kT = (const float*)(wsb + KT_OFF);
  double* fitv = (double*)(wsb + FITV_OFF);
  double* cmv = (double*)(wsb + CMV_OFF);
  const int tid = threadIdx.x;
  const int lane = tid & 63, wv = tid >> 6;
  const int c0 = tid * 8;

  for (unsigned base = blockIdx.x * 4u; base < count; base += gridDim.x * 4u) {
    __syncthreads();                       // xs/ss/wred reuse guard
    {
      const int r = tid >> 6, w = tid & 63;
      const unsigned li = base + (unsigned)r;
      if (li < count) {
        if (li < XRCAP) {
          xs[r][w] = XR[(size_t)li * WD + w];
        } else {
          const int row = list[li];
          const int n = row >> 13, t = row & (TD - 1);
          xs[r][w] = x[(size_t)n * WD * TD + (size_t)w * TD + t];
        }
      }
    }
    __syncthreads();
    if (lane == 0) ss[wv] = np_sumsq64_ptr(xs[wv]);
    __syncthreads();
    const float s0 = ss[0], s1 = ss[1], s2 = ss[2], s3 = ss[3];

    float a00 = 0.f, a01 = 0.f, a02 = 0.f, a03 = 0.f, a04 = 0.f, a05 = 0.f, a06 = 0.f, a07 = 0.f;
    float a10 = 0.f, a11 = 0.f, a12 = 0.f, a13 = 0.f, a14 = 0.f, a15 = 0.f, a16 = 0.f, a17 = 0.f;
    float a20 = 0.f, a21 = 0.f, a22 = 0.f, a23 = 0.f, a24 = 0.f, a25 = 0.f, a26 = 0.f, a27 = 0.f;
    float a30 = 0.f, a31 = 0.f, a32 = 0.f, a33 = 0.f, a34 = 0.f, a35 = 0.f, a36 = 0.f, a37 = 0.f;
    const float* kt = kT + c0;
#pragma unroll 4
    for (int w = 0; w < WD; ++w) {
      const float4 ka = *(const float4*)(kt + (size_t)w * KB);
      const float4 kb = *(const float4*)(kt + (size_t)w * KB + 4);
      const float xw0 = xs[0][w], xw1 = xs[1][w], xw2 = xs[2][w], xw3 = xs[3][w];
      a00 = __fmaf_rn(xw0, ka.x, a00); a01 = __fmaf_rn(xw0, ka.y, a01);
      a02 = __fmaf_rn(xw0, ka.z, a02); a03 = __fmaf_rn(xw0, ka.w, a03);
      a04 = __fmaf_rn(xw0, kb.x, a04); a05 = __fmaf_rn(xw0, kb.y, a05);
      a06 = __fmaf_rn(xw0, kb.z, a06); a07 = __fmaf_rn(xw0, kb.w, a07);
      a10 = __fmaf_rn(xw1, ka.x, a10); a11 = __fmaf_rn(xw1, ka.y, a11);
      a12 = __fmaf_rn(xw1, ka.z, a12); a13 = __fmaf_rn(xw1, ka.w, a13);
      a14 = __fmaf_rn(xw1, kb.x, a14); a15 = __fmaf_rn(xw1, kb.y, a15);
      a16 = __fmaf_rn(xw1, kb.z, a16); a17 = __fmaf_rn(xw1, kb.w, a17);
      a20 = __fmaf_rn(xw2, ka.x, a20); a21 = __fmaf_rn(xw2, ka.y, a21);
      a22 = __fmaf_rn(xw2, ka.z, a22); a23 = __fmaf_rn(xw2, ka.w, a23);
      a24 = __fmaf_rn(xw2, kb.x, a24); a25 = __fmaf_rn(xw2, kb.y, a25);
      a26 = __fmaf_rn(xw2, kb.z, a26); a27 = __fmaf_rn(xw2, kb.w, a27);
      a30 = __fmaf_rn(xw3, ka.x, a30); a31 = __fmaf_rn(xw3, ka.y, a31);
      a32 = __fmaf_rn(xw3, ka.z, a32); a33 = __fmaf_rn(xw3, ka.w, a33);
      a34 = __fmaf_rn(xw3, kb.x, a34); a35 = __fmaf_rn(xw3, kb.y, a35);
      a36 = __fmaf_rn(xw3, kb.z, a36); a37 = __fmaf_rn(xw3, kb.w, a37);
    }

#define ROWBEST(R, SV, A0, A1, A2, A3, A4, A5, A6, A7) { \
      unsigned long long best = ~0ull; \
      float d; unsigned long long p; \
      d = __fadd_rn(__fsub_rn(SV, __fmul_rn(2.f, A0)), kn2[c0 + 0]); \
      p = ((unsigned long long)__float_as_uint(d) << 32) | (unsigned)(c0 + 0); best = p < best ? p : best; \
      d = __fadd_rn(__fsub_rn(SV, __fmul_rn(2.f, A1)), kn2[c0 + 1]); \
      p = ((unsigned long long)__float_as_uint(d) << 32) | (unsigned)(c0 + 1); best = p < best ? p : best; \
      d = __fadd_rn(__fsub_rn(SV, __fmul_rn(2.f, A2)), kn2[c0 + 2]); \
      p = ((unsigned long long)__float_as_uint(d) << 32) | (unsigned)(c0 + 2); best = p < best ? p : best; \
      d = __fadd_rn(__fsub_rn(SV, __fmul_rn(2.f, A3)), kn2[c0 + 3]); \
      p = ((unsigned long long)__float_as_uint(d) << 32) | (unsigned)(c0 + 3); best = p < best ? p : best; \
      d = __fadd_rn(__fsub_rn(SV, __fmul_rn(2.f, A4)), kn2[c0 + 4]); \
      p = ((unsigned long long)__float_as_uint(d) << 32) | (unsigned)(c0 + 4); best = p < best ? p : best; \
      d = __fadd_rn(__fsub_rn(SV, __fmul_rn(2.f, A5)), kn2[c0 + 5]); \
      p = ((unsigned long long)__float_as_uint(d) << 32) | (unsigned)(c0 + 5); best = p < best ? p : best; \
      d = __fadd_rn(__fsub_rn(SV, __fmul_rn(2.f, A6)), kn2[c0 + 6]); \
      p = ((unsigned long long)__float_as_uint(d) << 32) | (unsigned)(c0 + 6); best = p < best ? p : best; \
      d = __fadd_rn(__fsub_rn(SV, __fmul_rn(2.f, A7)), kn2[c0 + 7]); \
      p = ((unsigned long long)__float_as_uint(d) << 32) | (unsigned)(c0 + 7); best = p < best ? p : best; \
      _Pragma("unroll") \
      for (int dd = 1; dd < 64; dd <<= 1) { \
        unsigned lo = (unsigned)best, hi = (unsigned)(best >> 32); \
        unsigned olo = __shfl_xor(lo, dd, 64); \
        unsigned ohi = __shfl_xor(hi, dd, 64); \
        unsigned long long o = ((unsigned long long)ohi << 32) | olo; \
        best = o < best ? o : best; \
      } \
      if (lane == 0) wred[R][wv] = best; }
    ROWBEST(0, s0, a00, a01, a02, a03, a04, a05, a06, a07)
    ROWBEST(1, s1, a10, a11, a12, a13, a14, a15, a16, a17)
    ROWBEST(2, s2, a20, a21, a22, a23, a24, a25, a26, a27)
    ROWBEST(3, s3, a30, a31, a32, a33, a34, a35, a36, a37)
#undef ROWBEST
    __syncthreads();
    if (tid < 4) {
      unsigned long long b = wred[tid][0];
      b = wred[tid][1] < b ? wred[tid][1] : b;
      b = wred[tid][2] < b ? wred[tid][2] : b;
      b = wred[tid][3] < b ? wred[tid][3] : b;
      bbest[tid] = b;
    }
    __syncthreads();

    {
      const int r = wv, w = lane;
      const unsigned li = base + (unsigned)r;
      if (li < count) {
        const int row = list[li];
        const int n = row >> 13, t = row & (TD - 1);
        const unsigned long long fb = bbest[r];
        const int bi = (int)(fb & 0xffffffffu);
        const float bv = __uint_as_float((unsigned)(fb >> 32));
        float kw = k[(size_t)bi * WD + w];
        float xw = xs[r][w];
        float diff = __fsub_rn(kw, xw);
        out[OFF_XD + (size_t)n * WD * TD + (size_t)w * TD + t] = __fadd_rn(xw, diff);
        double d2 = (double)diff * (double)diff;
#pragma unroll
        for (int dd = 32; dd > 0; dd >>= 1) d2 += __shfl_down(d2, dd, 64);
        if (w == 0) {
          out[OFF_XL + row] = (float)bi;
          fitv[li] = (double)bv;
          cmv[li] = d2;
        }
      }
    }
  }
}

// ---------- K4: final scalars — reduce PB partials + rescan arrays ----------
__global__ __launch_bounds__(256)
void vq_final(const char* __restrict__ wsb, float* __restrict__ out) {
  __shared__ double sred[24];
  const unsigned count = *(const unsigned*)(wsb + CNT_OFF);
  const double* fitv = (const double*)(wsb + FITV_OFF);
  const double* cmv = (const double*)(wsb + CMV_OFF);
  const double* pb = (const double*)(wsb + PB_OFF);
  const int tid = threadIdx.x;

  double fa = 0.0, ca = 0.0;
  for (unsigned i = tid; i < count; i += 256) {
    fa += fitv[i];
    ca += cmv[i];
  }
  double b0 = 0.0, b1 = 0.0, b2 = 0.0, b3 = 0.0;
  for (int i = tid; i < 512; i += 256) {
    b0 += pb[i * 4 + 0];
    b1 += pb[i * 4 + 1];
    b2 += pb[i * 4 + 2];
    b3 += pb[i * 4 + 3];
  }
#pragma unroll
  for (int off = 32; off > 0; off >>= 1) {
    fa += __shfl_down(fa, off, 64);
    ca += __shfl_down(ca, off, 64);
    b0 += __shfl_down(b0, off, 64);
    b1 += __shfl_down(b1, off, 64);
    b2 += __shfl_down(b2, off, 64);
    b3 += __shfl_down(b3, off, 64);
  }
  if ((tid & 63) == 0) {
    int wv = tid >> 6;
    sred[wv * 6 + 0] = fa;
    sred[wv * 6 + 1] = ca;
    sred[wv * 6 + 2] = b0;
    sred[wv * 6 + 3] = b1;
    sred[wv * 6 + 4] = b2;
    sred[wv * 6 + 5] = b3;
  }
  __syncthreads();
  if (tid == 0) {
    double fit = 0, cm = 0, sum = 0, sumsq = 0;
#pragma unroll
    for (int i = 0; i < 4; ++i) {
      fit += sred[i * 6 + 0] + sred[i * 6 + 4];   // rescan fit + block fit
      cm += sred[i * 6 + 1] + sred[i * 6 + 5];    // rescan commit + block commit
      sum += sred[i * 6 + 2];
      sumsq += sred[i * 6 + 3];
    }
    double mean = sum / 8388608.0;
    double ss = sumsq - sum * mean;
    if (ss < 0.0) ss = 0.0;
    out[OFF_SC + 0] = (float)(cm / 8388608.0);         // commit_loss
    out[OFF_SC + 1] = (float)(fit / 131072.0);         // fit
    out[OFF_SC + 2] = (float)sqrt(ss / 8388608.0);     // prenorm
  }
}

extern "C" void kernel_launch(void* const* d_in, const int* in_sizes, int n_in,
                              void* d_out, int out_size, void* d_ws, size_t ws_size,
                              hipStream_t stream) {
  const float* x = (const float*)d_in[0];
  const float* k = (const float*)d_in[1];
  float* out = (float*)d_out;
  char* wsb = (char*)d_ws;

  hipMemsetAsync(d_ws, 0, 64, stream);                 // count (+ reserved)
  vq_prep<<<KB / 256, 256, 0, stream>>>(k, wsb);
  vq_scan<<<NT / 256, 256, 0, stream>>>(x, k, out, wsb);
  vq_rescan7<<<1024, 256, 0, stream>>>(x, k, out, wsb);
  vq_final<<<1, 256, 0, stream>>>(wsb, out);
}

// Round 20
// 159.436 us; speedup vs baseline: 2.2720x; 1.0083x over previous
//
#include <hip/hip_runtime.h>
#include <math.h>

#define WD 64
#define TD 8192
#define NT 131072           // 16 * 8192 rows
#define KB 2048
// Output layout (float32, concatenated): x_l [NT], x_d [NT*WD], commit, fit, prenorm
#define OFF_XL 0
#define OFF_XD NT
#define OFF_SC (NT + NT * WD)

// ws layout (bytes)
#define CNT_OFF   32                     // uint: rescan count
#define KN2_OFF   4096                   // float[2048] np-exact ||k||^2
#define CB_OFF    16384                  // bf16 B-frags: 128jt * 4frag * 64lane * 16B = 512KB
#define LIST_OFF  (16384 + 524288)       // int[NT] rescan rows
#define KT_OFF    (LIST_OFF + 4 * NT)    // float[64][2048] transposed codebook (512KB)
#define XR_OFF    (KT_OFF + 8 * NT)      // float[XRCAP][64] compacted rescan rows (8MB)
#define FITV_OFF  (XR_OFF + XRCAP * WD * 4)  // double[NT] per-rescan-slot min dist
#define CMV_OFF   (FITV_OFF + 8 * NT)        // double[NT] per-rescan-slot commit part
#define PB_OFF    (CMV_OFF + 8 * NT)         // double[512][4] per-block partials
#define XRCAP     32768                  // cap (count ~700 at 1e-3 gap)

#define EPS_GAP 1e-3f    // r19-verified: 10x margin over ~1e-4 worst-case flip gap
#define VEPS    2e-3f

typedef __attribute__((ext_vector_type(8))) short bf16x8_t;  // 8 bf16 (4 VGPRs)
typedef __attribute__((ext_vector_type(4))) float f32x4_t;

__device__ __forceinline__ unsigned short bf16_rne(float f) {
  unsigned int u = __float_as_uint(f);
  unsigned int r = u + 0x7fffu + ((u >> 16) & 1u);
  return (unsigned short)(r >> 16);
}

#define REP64(F) F(0) F(1) F(2) F(3) F(4) F(5) F(6) F(7) \
  F(8) F(9) F(10) F(11) F(12) F(13) F(14) F(15) \
  F(16) F(17) F(18) F(19) F(20) F(21) F(22) F(23) \
  F(24) F(25) F(26) F(27) F(28) F(29) F(30) F(31) \
  F(32) F(33) F(34) F(35) F(36) F(37) F(38) F(39) \
  F(40) F(41) F(42) F(43) F(44) F(45) F(46) F(47) \
  F(48) F(49) F(50) F(51) F(52) F(53) F(54) F(55) \
  F(56) F(57) F(58) F(59) F(60) F(61) F(62) F(63)

// numpy pairwise_sum (scalar 8-accumulator, n=64) of PRE-ROUNDED squares; *_rn
// intrinsics forbid contraction. Bit-exact vs np.sum(a*a, -1) (verified r2-r19).
#define NP_SUMSQ64_NAMED(SVAR) \
  float r0 = __fmul_rn(x0, x0); \
  float r1 = __fmul_rn(x1, x1); \
  float r2 = __fmul_rn(x2, x2); \
  float r3 = __fmul_rn(x3, x3); \
  float r4 = __fmul_rn(x4, x4); \
  float r5 = __fmul_rn(x5, x5); \
  float r6 = __fmul_rn(x6, x6); \
  float r7 = __fmul_rn(x7, x7); \
  SQ8(8, 9, 10, 11, 12, 13, 14, 15) \
  SQ8(16, 17, 18, 19, 20, 21, 22, 23) \
  SQ8(24, 25, 26, 27, 28, 29, 30, 31) \
  SQ8(32, 33, 34, 35, 36, 37, 38, 39) \
  SQ8(40, 41, 42, 43, 44, 45, 46, 47) \
  SQ8(48, 49, 50, 51, 52, 53, 54, 55) \
  SQ8(56, 57, 58, 59, 60, 61, 62, 63) \
  const float SVAR = __fadd_rn(__fadd_rn(__fadd_rn(r0, r1), __fadd_rn(r2, r3)), \
                               __fadd_rn(__fadd_rn(r4, r5), __fadd_rn(r6, r7)));
#define SQ8(a,b,c,d,e,f,g,h) \
  r0 = __fadd_rn(r0, __fmul_rn(x##a, x##a)); \
  r1 = __fadd_rn(r1, __fmul_rn(x##b, x##b)); \
  r2 = __fadd_rn(r2, __fmul_rn(x##c, x##c)); \
  r3 = __fadd_rn(r3, __fmul_rn(x##d, x##d)); \
  r4 = __fadd_rn(r4, __fmul_rn(x##e, x##e)); \
  r5 = __fadd_rn(r5, __fmul_rn(x##f, x##f)); \
  r6 = __fadd_rn(r6, __fmul_rn(x##g, x##g)); \
  r7 = __fadd_rn(r7, __fmul_rn(x##h, x##h));

__device__ __forceinline__ float np_sumsq64_ptr(const float* a) {
  float r0 = __fmul_rn(a[0], a[0]);
  float r1 = __fmul_rn(a[1], a[1]);
  float r2 = __fmul_rn(a[2], a[2]);
  float r3 = __fmul_rn(a[3], a[3]);
  float r4 = __fmul_rn(a[4], a[4]);
  float r5 = __fmul_rn(a[5], a[5]);
  float r6 = __fmul_rn(a[6], a[6]);
  float r7 = __fmul_rn(a[7], a[7]);
#pragma unroll
  for (int i = 8; i < 64; i += 8) {
    r0 = __fadd_rn(r0, __fmul_rn(a[i + 0], a[i + 0]));
    r1 = __fadd_rn(r1, __fmul_rn(a[i + 1], a[i + 1]));
    r2 = __fadd_rn(r2, __fmul_rn(a[i + 2], a[i + 2]));
    r3 = __fadd_rn(r3, __fmul_rn(a[i + 3], a[i + 3]));
    r4 = __fadd_rn(r4, __fmul_rn(a[i + 4], a[i + 4]));
    r5 = __fadd_rn(r5, __fmul_rn(a[i + 5], a[i + 5]));
    r6 = __fadd_rn(r6, __fmul_rn(a[i + 6], a[i + 6]));
    r7 = __fadd_rn(r7, __fmul_rn(a[i + 7], a[i + 7]));
  }
  float t01 = __fadd_rn(r0, r1);
  float t23 = __fadd_rn(r2, r3);
  float t45 = __fadd_rn(r4, r5);
  float t67 = __fadd_rn(r6, r7);
  return __fadd_rn(__fadd_rn(t01, t23), __fadd_rn(t45, t67));
}

// ---------- K0: kn2_np + bf16 B-frags + transposed codebook kT[w][c] ----------
__global__ __launch_bounds__(256)
void vq_prep(const float* __restrict__ k, char* __restrict__ wsb) {
  int c = blockIdx.x * 256 + threadIdx.x;
  if (c >= KB) return;
  const float* kr = k + (size_t)c * WD;
  ((float*)(wsb + KN2_OFF))[c] = np_sumsq64_ptr(kr);
  float* kt = (float*)(wsb + KT_OFF);
#pragma unroll
  for (int w = 0; w < WD; ++w) kt[(size_t)w * KB + c] = kr[w];
  int jt = c >> 4, col = c & 15;
  unsigned short* cb = (unsigned short*)(wsb + CB_OFF);
#pragma unroll
  for (int w = 0; w < WD; ++w) {
    float f = kr[w];
    unsigned short hb = bf16_rne(f);
    float hf = __uint_as_float((unsigned int)hb << 16);
    unsigned short lb = bf16_rne(f - hf);
    int fH = w >> 5;                       // K-half: frag 0/1 (hi), 2/3 (lo)
    int lane = col | (((w >> 3) & 3) << 4);
    int e = w & 7;
    cb[((size_t)((jt * 4 + fH) * 64 + lane)) * 8 + e] = hb;
    cb[((size_t)((jt * 4 + 2 + fH) * 64 + lane)) * 8 + e] = lb;
  }
}

// ---------- K1: FUSED scan + finalize, 8 waves x 2 tiles ----------
// r19 diagnosis: issue-cycle accounting (57k issue vs 295k measured cycles/SIMD)
// shows scan is LATENCY-bound at 2 waves/SIMD, not issue-bound. Fix: 512-thread
// blocks (8 waves x 2 tiles, same 256 rows) -> 4 waves/SIMD for dependency
// hiding. Finalize on lower 256 threads (barriers block-wide).
__global__ __launch_bounds__(512) __attribute__((amdgpu_waves_per_eu(4)))
void vq_scan(const float* __restrict__ x, const float* __restrict__ k,
             float* __restrict__ out, char* __restrict__ wsb) {
  __shared__ float lkn2n[KB];         // 8KB: -0.5 * ||k||^2 (prescaled)
  __shared__ char cbuf[2][32768];     // 64KB double-buffered B-frag chunks (8 jt)
  __shared__ float sm1[256], sm2[256];
  __shared__ int sj1[256];
  __shared__ double sred[16];
  const int tid = threadIdx.x, lane = tid & 63, wave = tid >> 6;  // 8 waves
  const int col = lane & 15, grp = lane >> 4;

  for (int i = tid; i < KB; i += 512)
    lkn2n[i] = -0.5f * ((const float*)(wsb + KN2_OFF))[i];

  const int n = blockIdx.x >> 5;           // 32 blocks per n (8192/256)
  const int t0 = (blockIdx.x & 31) * 256;
  const float* xb = x + (size_t)n * WD * TD;

  // A-frags: wave owns 2 tiles (32 rows): rows t0 + wave*32 + T*16 + (grp*4+e)
  bf16x8_t aH[2][2], aL[2][2];
#pragma unroll
  for (int T = 0; T < 2; ++T) {
    const int trow = t0 + wave * 32 + T * 16 + col;
#pragma unroll
    for (int s = 0; s < 2; ++s) {
#pragma unroll
      for (int e = 0; e < 8; ++e) {
        int w = s * 32 + grp * 8 + e;
        float f = xb[(size_t)w * TD + trow];
        unsigned short hb = bf16_rne(f);
        float hf = __uint_as_float((unsigned int)hb << 16);
        unsigned short lb = bf16_rne(f - hf);
        aH[T][s][e] = (short)hb;
        aL[T][s][e] = (short)lb;
      }
    }
  }

  // packed argmax trackers: value bits [31:7], jt in bits [6:0]
  float M1[2][4], M2[2][4];
#pragma unroll
  for (int T = 0; T < 2; ++T)
#pragma unroll
    for (int e = 0; e < 4; ++e) {
      M1[T][e] = -INFINITY; M2[T][e] = -INFINITY;
    }

  const char* cbsrc = wsb + CB_OFF;
  float4 pf0, pf1, pf2, pf3;
#define PREF(c) { const float4* sp = (const float4*)(cbsrc + (size_t)(c) * 32768); \
    pf0 = sp[tid]; pf1 = sp[tid + 512]; pf2 = sp[tid + 1024]; pf3 = sp[tid + 1536]; }
#define WRBUF(b) { float4* dp = (float4*)cbuf[b]; \
    dp[tid] = pf0; dp[tid + 512] = pf1; dp[tid + 1024] = pf2; dp[tid + 1536] = pf3; }

  PREF(0)
  WRBUF(0)
  PREF(1)
  __syncthreads();

  for (int c = 0; c < 16; ++c) {
    const int cur = c & 1;
    if (c < 15) WRBUF(cur ^ 1)
    if (c < 14) PREF(c + 2)
#pragma unroll
    for (int jl = 0; jl < 8; ++jl) {
      const bf16x8_t* bp = (const bf16x8_t*)(cbuf[cur] + jl * 4096) + lane;
      bf16x8_t bH0 = bp[0], bH1 = bp[64], bL0 = bp[128], bL1 = bp[192];
      const int jt = c * 8 + jl;
      const float ci = lkn2n[jt * 16 + col];
#pragma unroll
      for (int T = 0; T < 2; ++T) {
        f32x4_t acc = {ci, ci, ci, ci};
        acc = __builtin_amdgcn_mfma_f32_16x16x32_bf16(aH[T][0], bH0, acc, 0, 0, 0);
        acc = __builtin_amdgcn_mfma_f32_16x16x32_bf16(aH[T][1], bH1, acc, 0, 0, 0);
        acc = __builtin_amdgcn_mfma_f32_16x16x32_bf16(aL[T][0], bH0, acc, 0, 0, 0);
        acc = __builtin_amdgcn_mfma_f32_16x16x32_bf16(aL[T][1], bH1, acc, 0, 0, 0);
        acc = __builtin_amdgcn_mfma_f32_16x16x32_bf16(aH[T][0], bL0, acc, 0, 0, 0);
        acc = __builtin_amdgcn_mfma_f32_16x16x32_bf16(aH[T][1], bL1, acc, 0, 0, 0);
#pragma unroll
        for (int e = 0; e < 4; ++e) {
          float vp = __uint_as_float(
              (__float_as_uint(acc[e]) & 0xFFFFFF80u) | (unsigned)jt);
          M2[T][e] = __builtin_amdgcn_fmed3f(M1[T][e], M2[T][e], vp);
          M1[T][e] = fmaxf(M1[T][e], vp);
        }
      }
    }
    __syncthreads();
  }
#undef PREF
#undef WRBUF

  // cross-lane reduce -> per-row (m1,m2,j1) into LDS
#pragma unroll
  for (int T = 0; T < 2; ++T)
#pragma unroll
    for (int e = 0; e < 4; ++e) {
      float m1 = M1[T][e], m2 = M2[T][e];
      int cd = (int)(__float_as_uint(m1) & 0x7Fu) * 16 + col;
#pragma unroll
      for (int d = 1; d < 16; d <<= 1) {
        float om1 = __shfl_xor(m1, d, 64);
        float om2 = __shfl_xor(m2, d, 64);
        int ocd = __shfl_xor(cd, d, 64);
        bool take = (om1 > m1) || (om1 == m1 && ocd < cd);
        float loser = take ? m1 : om1;
        m2 = fmaxf(fmaxf(m2, om2), loser);
        m1 = take ? om1 : m1;
        cd = take ? ocd : cd;
      }
      if (col == 0) {
        int r = wave * 32 + T * 16 + grp * 4 + e;
        sm1[r] = -2.f * m1;                // score domain
        sm2[r] = -2.f * m2;
        sj1[r] = cd;
      }
    }
  __syncthreads();

  // ---- fused finalize: lower 256 threads, one row each ----
  if (tid < 256) {
    const int row = blockIdx.x * 256 + tid;
    const int t = row & (TD - 1);
    const float m1r = sm1[tid], m2r = sm2[tid];
    const int j1r = sj1[tid];

    const float* xr = x + ((size_t)n * WD) * TD + t;
#define LOADX(w) float x##w = xr[(size_t)(w) * TD];
    REP64(LOADX)
#undef LOADX

    NP_SUMSQ64_NAMED(s)

    double xsum = 0.0, xsumsq = 0.0;
#define PRE(w) { double xd = (double)x##w; xsum += xd; xsumsq = fma(xd, xd, xsumsq); }
    REP64(PRE)
#undef PRE

    const float4* k4 = (const float4*)(k + (size_t)j1r * WD);
    float* xo = out + OFF_XD + ((size_t)n * WD) * TD + t;
    double commit = 0.0;
    float g = 0.f;
#define EPI1(w, KW) { \
      float kw = KW; \
      float diff = __fsub_rn(kw, x##w); \
      commit = fma((double)diff, (double)diff, commit); \
      g = __fmaf_rn(x##w, kw, g); \
      xo[(size_t)(w) * TD] = __fadd_rn(x##w, diff); }
    {
      float4 ka = k4[0], kb = k4[1], kc = k4[2], kd = k4[3];
      EPI1(0, ka.x) EPI1(1, ka.y) EPI1(2, ka.z) EPI1(3, ka.w)
      EPI1(4, kb.x) EPI1(5, kb.y) EPI1(6, kb.z) EPI1(7, kb.w)
      EPI1(8, kc.x) EPI1(9, kc.y) EPI1(10, kc.z) EPI1(11, kc.w)
      EPI1(12, kd.x) EPI1(13, kd.y) EPI1(14, kd.z) EPI1(15, kd.w)
    }
    {
      float4 ka = k4[4], kb = k4[5], kc = k4[6], kd = k4[7];
      EPI1(16, ka.x) EPI1(17, ka.y) EPI1(18, ka.z) EPI1(19, ka.w)
      EPI1(20, kb.x) EPI1(21, kb.y) EPI1(22, kb.z) EPI1(23, kb.w)
      EPI1(24, kc.x) EPI1(25, kc.y) EPI1(26, kc.z) EPI1(27, kc.w)
      EPI1(28, kd.x) EPI1(29, kd.y) EPI1(30, kd.z) EPI1(31, kd.w)
    }
    {
      float4 ka = k4[8], kb = k4[9], kc = k4[10], kd = k4[11];
      EPI1(32, ka.x) EPI1(33, ka.y) EPI1(34, ka.z) EPI1(35, ka.w)
      EPI1(36, kb.x) EPI1(37, kb.y) EPI1(38, kb.z) EPI1(39, kb.w)
      EPI1(40, kc.x) EPI1(41, kc.y) EPI1(42, kc.z) EPI1(43, kc.w)
      EPI1(44, kd.x) EPI1(45, kd.y) EPI1(46, kd.z) EPI1(47, kd.w)
    }
    {
      float4 ka = k4[12], kb = k4[13], kc = k4[14], kd = k4[15];
      EPI1(48, ka.x) EPI1(49, ka.y) EPI1(50, ka.z) EPI1(51, ka.w)
      EPI1(52, kb.x) EPI1(53, kb.y) EPI1(54, kb.z) EPI1(55, kb.w)
      EPI1(56, kc.x) EPI1(57, kc.y) EPI1(58, kc.z) EPI1(59, kc.w)
      EPI1(60, kd.x) EPI1(61, kd.y) EPI1(62, kd.z) EPI1(63, kd.w)
    }
#undef EPI1

    float kn2j = ((const float*)(wsb + KN2_OFF))[j1r];
    float score = kn2j - 2.f * g;
    bool resc = (m2r - m1r < EPS_GAP) || (fabsf(score - m1r) > VEPS);
    float dist1 = __fadd_rn(__fsub_rn(s, __fmul_rn(2.f, g)), kn2j);

    out[OFF_XL + row] = (float)j1r;
    if (resc) {
      unsigned idx = atomicAdd((unsigned*)(wsb + CNT_OFF), 1u);
      ((int*)(wsb + LIST_OFF))[idx] = row;
      if (idx < XRCAP) {
        float* xrw = (float*)(wsb + XR_OFF) + (size_t)idx * WD;
#define XWR(w) xrw[w] = x##w;
        REP64(XWR)
#undef XWR
      }
    }

    // block reduction of 4 fp64 partials -> plain stores (no atomics)
    double v0 = xsum, v1 = xsumsq;
    double v2 = resc ? 0.0 : (double)dist1;
    double v3 = resc ? 0.0 : commit;
#pragma unroll
    for (int off = 32; off > 0; off >>= 1) {
      v0 += __shfl_down(v0, off, 64);
      v1 += __shfl_down(v1, off, 64);
      v2 += __shfl_down(v2, off, 64);
      v3 += __shfl_down(v3, off, 64);
    }
    if ((tid & 63) == 0) {
      int wv = tid >> 6;
      sred[wv * 4 + 0] = v0;
      sred[wv * 4 + 1] = v1;
      sred[wv * 4 + 2] = v2;
      sred[wv * 4 + 3] = v3;
    }
  }
  __syncthreads();
  if (tid == 0) {
    double a0 = 0, a1 = 0, a2 = 0, a3 = 0;
#pragma unroll
    for (int w2 = 0; w2 < 4; ++w2) {
      a0 += sred[w2 * 4 + 0];
      a1 += sred[w2 * 4 + 1];
      a2 += sred[w2 * 4 + 2];
      a3 += sred[w2 * 4 + 3];
    }
    double* pb = (double*)(wsb + PB_OFF) + (size_t)blockIdx.x * 4;
    pb[0] = a0; pb[1] = a1; pb[2] = a2; pb[3] = a3;
  }
}

// ---------- K3: exact rescan, 4 rows/block, per-slot results (no hot atomics) ----------
__global__ __launch_bounds__(256)
void vq_rescan7(const float* __restrict__ x, const float* __restrict__ k,
                float* __restrict__ out, char* __restrict__ wsb) {
  __shared__ float xs[4][WD];
  __shared__ float ss[4];
  __shared__ unsigned long long wred[4][4];   // [row][wave]
  __shared__ unsigned long long bbest[4];
  const unsigned count = *(const unsigned*)(wsb + CNT_OFF);
  const int* list = (const int*)(wsb + LIST_OFF);
  const float* kn2 = (const float*)(wsb + KN2_OFF);
  const float* XR = (const float*)(wsb + XR_OFF);
  const float* kT = (const float*)(wsb + KT_OFF);
  double* fitv = (double*)(wsb + FITV_OFF);
  double* cmv = (double*)(wsb + CMV_OFF);
  const int tid = threadIdx.x;
  const int lane = tid & 63, wv = tid >> 6;
  const int c0 = tid * 8;

  for (unsigned base = blockIdx.x * 4u; base < count; base += gridDim.x * 4u) {
    __syncthreads();                       // xs/ss/wred reuse guard
    {
      const int r = tid >> 6, w = tid & 63;
      const unsigned li = base + (unsigned)r;
      if (li < count) {
        if (li < XRCAP) {
          xs[r][w] = XR[(size_t)li * WD + w];
        } else {
          const int row = list[li];
          const int n = row >> 13, t = row & (TD - 1);
          xs[r][w] = x[(size_t)n * WD * TD + (size_t)w * TD + t];
        }
      }
    }
    __syncthreads();
    if (lane == 0) ss[wv] = np_sumsq64_ptr(xs[wv]);
    __syncthreads();
    const float s0 = ss[0], s1 = ss[1], s2 = ss[2], s3 = ss[3];

    float a00 = 0.f, a01 = 0.f, a02 = 0.f, a03 = 0.f, a04 = 0.f, a05 = 0.f, a06 = 0.f, a07 = 0.f;
    float a10 = 0.f, a11 = 0.f, a12 = 0.f, a13 = 0.f, a14 = 0.f, a15 = 0.f, a16 = 0.f, a17 = 0.f;
    float a20 = 0.f, a21 = 0.f, a22 = 0.f, a23 = 0.f, a24 = 0.f, a25 = 0.f, a26 = 0.f, a27 = 0.f;
    float a30 = 0.f, a31 = 0.f, a32 = 0.f, a33 = 0.f, a34 = 0.f, a35 = 0.f, a36 = 0.f, a37 = 0.f;
    const float* kt = kT + c0;
#pragma unroll 4
    for (int w = 0; w < WD; ++w) {
      const float4 ka = *(const float4*)(kt + (size_t)w * KB);
      const float4 kb = *(const float4*)(kt + (size_t)w * KB + 4);
      const float xw0 = xs[0][w], xw1 = xs[1][w], xw2 = xs[2][w], xw3 = xs[3][w];
      a00 = __fmaf_rn(xw0, ka.x, a00); a01 = __fmaf_rn(xw0, ka.y, a01);
      a02 = __fmaf_rn(xw0, ka.z, a02); a03 = __fmaf_rn(xw0, ka.w, a03);
      a04 = __fmaf_rn(xw0, kb.x, a04); a05 = __fmaf_rn(xw0, kb.y, a05);
      a06 = __fmaf_rn(xw0, kb.z, a06); a07 = __fmaf_rn(xw0, kb.w, a07);
      a10 = __fmaf_rn(xw1, ka.x, a10); a11 = __fmaf_rn(xw1, ka.y, a11);
      a12 = __fmaf_rn(xw1, ka.z, a12); a13 = __fmaf_rn(xw1, ka.w, a13);
      a14 = __fmaf_rn(xw1, kb.x, a14); a15 = __fmaf_rn(xw1, kb.y, a15);
      a16 = __fmaf_rn(xw1, kb.z, a16); a17 = __fmaf_rn(xw1, kb.w, a17);
      a20 = __fmaf_rn(xw2, ka.x, a20); a21 = __fmaf_rn(xw2, ka.y, a21);
      a22 = __fmaf_rn(xw2, ka.z, a22); a23 = __fmaf_rn(xw2, ka.w, a23);
      a24 = __fmaf_rn(xw2, kb.x, a24); a25 = __fmaf_rn(xw2, kb.y, a25);
      a26 = __fmaf_rn(xw2, kb.z, a26); a27 = __fmaf_rn(xw2, kb.w, a27);
      a30 = __fmaf_rn(xw3, ka.x, a30); a31 = __fmaf_rn(xw3, ka.y, a31);
      a32 = __fmaf_rn(xw3, ka.z, a32); a33 = __fmaf_rn(xw3, ka.w, a33);
      a34 = __fmaf_rn(xw3, kb.x, a34); a35 = __fmaf_rn(xw3, kb.y, a35);
      a36 = __fmaf_rn(xw3, kb.z, a36); a37 = __fmaf_rn(xw3, kb.w, a37);
    }

#define ROWBEST(R, SV, A0, A1, A2, A3, A4, A5, A6, A7) { \
      unsigned long long best = ~0ull; \
      float d; unsigned long long p; \
      d = __fadd_rn(__fsub_rn(SV, __fmul_rn(2.f, A0)), kn2[c0 + 0]); \
      p = ((unsigned long long)__float_as_uint(d) << 32) | (unsigned)(c0 + 0); best = p < best ? p : best; \
      d = __fadd_rn(__fsub_rn(SV, __fmul_rn(2.f, A1)), kn2[c0 + 1]); \
      p = ((unsigned long long)__float_as_uint(d) << 32) | (unsigned)(c0 + 1); best = p < best ? p : best; \
      d = __fadd_rn(__fsub_rn(SV, __fmul_rn(2.f, A2)), kn2[c0 + 2]); \
      p = ((unsigned long long)__float_as_uint(d) << 32) | (unsigned)(c0 + 2); best = p < best ? p : best; \
      d = __fadd_rn(__fsub_rn(SV, __fmul_rn(2.f, A3)), kn2[c0 + 3]); \
      p = ((unsigned long long)__float_as_uint(d) << 32) | (unsigned)(c0 + 3); best = p < best ? p : best; \
      d = __fadd_rn(__fsub_rn(SV, __fmul_rn(2.f, A4)), kn2[c0 + 4]); \
      p = ((unsigned long long)__float_as_uint(d) << 32) | (unsigned)(c0 + 4); best = p < best ? p : best; \
      d = __fadd_rn(__fsub_rn(SV, __fmul_rn(2.f, A5)), kn2[c0 + 5]); \
      p = ((unsigned long long)__float_as_uint(d) << 32) | (unsigned)(c0 + 5); best = p < best ? p : best; \
      d = __fadd_rn(__fsub_rn(SV, __fmul_rn(2.f, A6)), kn2[c0 + 6]); \
      p = ((unsigned long long)__float_as_uint(d) << 32) | (unsigned)(c0 + 6); best = p < best ? p : best; \
      d = __fadd_rn(__fsub_rn(SV, __fmul_rn(2.f, A7)), kn2[c0 + 7]); \
      p = ((unsigned long long)__float_as_uint(d) << 32) | (unsigned)(c0 + 7); best = p < best ? p : best; \
      _Pragma("unroll") \
      for (int dd = 1; dd < 64; dd <<= 1) { \
        unsigned lo = (unsigned)best, hi = (unsigned)(best >> 32); \
        unsigned olo = __shfl_xor(lo, dd, 64); \
        unsigned ohi = __shfl_xor(hi, dd, 64); \
        unsigned long long o = ((unsigned long long)ohi << 32) | olo; \
        best = o < best ? o : best; \
      } \
      if (lane == 0) wred[R][wv] = best; }
    ROWBEST(0, s0, a00, a01, a02, a03, a04, a05, a06, a07)
    ROWBEST(1, s1, a10, a11, a12, a13, a14, a15, a16, a17)
    ROWBEST(2, s2, a20, a21, a22, a23, a24, a25, a26, a27)
    ROWBEST(3, s3, a30, a31, a32, a33, a34, a35, a36, a37)
#undef ROWBEST
    __syncthreads();
    if (tid < 4) {
      unsigned long long b = wred[tid][0];
      b = wred[tid][1] < b ? wred[tid][1] : b;
      b = wred[tid][2] < b ? wred[tid][2] : b;
      b = wred[tid][3] < b ? wred[tid][3] : b;
      bbest[tid] = b;
    }
    __syncthreads();

    {
      const int r = wv, w = lane;
      const unsigned li = base + (unsigned)r;
      if (li < count) {
        const int row = list[li];
        const int n = row >> 13, t = row & (TD - 1);
        const unsigned long long fb = bbest[r];
        const int bi = (int)(fb & 0xffffffffu);
        const float bv = __uint_as_float((unsigned)(fb >> 32));
        float kw = k[(size_t)bi * WD + w];
        float xw = xs[r][w];
        float diff = __fsub_rn(kw, xw);
        out[OFF_XD + (size_t)n * WD * TD + (size_t)w * TD + t] = __fadd_rn(xw, diff);
        double d2 = (double)diff * (double)diff;
#pragma unroll
        for (int dd = 32; dd > 0; dd >>= 1) d2 += __shfl_down(d2, dd, 64);
        if (w == 0) {
          out[OFF_XL + row] = (float)bi;
          fitv[li] = (double)bv;
          cmv[li] = d2;
        }
      }
    }
  }
}

// ---------- K4: final scalars — reduce PB partials + rescan arrays ----------
__global__ __launch_bounds__(256)
void vq_final(const char* __restrict__ wsb, float* __restrict__ out) {
  __shared__ double sred[24];
  const unsigned count = *(const unsigned*)(wsb + CNT_OFF);
  const double* fitv = (const double*)(wsb + FITV_OFF);
  const double* cmv = (const double*)(wsb + CMV_OFF);
  const double* pb = (const double*)(wsb + PB_OFF);
  const int tid = threadIdx.x;

  double fa = 0.0, ca = 0.0;
  for (unsigned i = tid; i < count; i += 256) {
    fa += fitv[i];
    ca += cmv[i];
  }
  double b0 = 0.0, b1 = 0.0, b2 = 0.0, b3 = 0.0;
  for (int i = tid; i < 512; i += 256) {
    b0 += pb[i * 4 + 0];
    b1 += pb[i * 4 + 1];
    b2 += pb[i * 4 + 2];
    b3 += pb[i * 4 + 3];
  }
#pragma unroll
  for (int off = 32; off > 0; off >>= 1) {
    fa += __shfl_down(fa, off, 64);
    ca += __shfl_down(ca, off, 64);
    b0 += __shfl_down(b0, off, 64);
    b1 += __shfl_down(b1, off, 64);
    b2 += __shfl_down(b2, off, 64);
    b3 += __shfl_down(b3, off, 64);
  }
  if ((tid & 63) == 0) {
    int wv = tid >> 6;
    sred[wv * 6 + 0] = fa;
    sred[wv * 6 + 1] = ca;
    sred[wv * 6 + 2] = b0;
    sred[wv * 6 + 3] = b1;
    sred[wv * 6 + 4] = b2;
    sred[wv * 6 + 5] = b3;
  }
  __syncthreads();
  if (tid == 0) {
    double fit = 0, cm = 0, sum = 0, sumsq = 0;
#pragma unroll
    for (int i = 0; i < 4; ++i) {
      fit += sred[i * 6 + 0] + sred[i * 6 + 4];   // rescan fit + block fit
      cm += sred[i * 6 + 1] + sred[i * 6 + 5];    // rescan commit + block commit
      sum += sred[i * 6 + 2];
      sumsq += sred[i * 6 + 3];
    }
    double mean = sum / 8388608.0;
    double ss = sumsq - sum * mean;
    if (ss < 0.0) ss = 0.0;
    out[OFF_SC + 0] = (float)(cm / 8388608.0);         // commit_loss
    out[OFF_SC + 1] = (float)(fit / 131072.0);         // fit
    out[OFF_SC + 2] = (float)sqrt(ss / 8388608.0);     // prenorm
  }
}

extern "C" void kernel_launch(void* const* d_in, const int* in_sizes, int n_in,
                              void* d_out, int out_size, void* d_ws, size_t ws_size,
                              hipStream_t stream) {
  const float* x = (const float*)d_in[0];
  const float* k = (const float*)d_in[1];
  float* out = (float*)d_out;
  char* wsb = (char*)d_ws;

  hipMemsetAsync(d_ws, 0, 64, stream);                 // count (+ reserved)
  vq_prep<<<KB / 256, 256, 0, stream>>>(k, wsb);
  vq_scan<<<NT / 256, 512, 0, stream>>>(x, k, out, wsb);
  vq_rescan7<<<1024, 256, 0, stream>>>(x, k, out, wsb);
  vq_final<<<1, 256, 0, stream>>>(wsb, out);
}

// Round 21
// 159.234 us; speedup vs baseline: 2.2749x; 1.0013x over previous
//
#include <hip/hip_runtime.h>
#include <math.h>

#define WD 64
#define TD 8192
#define NT 131072           // 16 * 8192 rows
#define KB 2048
// Output layout (float32, concatenated): x_l [NT], x_d [NT*WD], commit, fit, prenorm
#define OFF_XL 0
#define OFF_XD NT
#define OFF_SC (NT + NT * WD)

// ws layout (bytes)
#define CNT_OFF   32                     // uint: rescan count
#define KN2_OFF   4096                   // float[2048] np-exact ||k||^2
#define CB_OFF    16384                  // bf16 B-frags: 128jt * 4frag * 64lane * 16B = 512KB
#define LIST_OFF  (16384 + 524288)       // int[NT] rescan rows
#define KT_OFF    (LIST_OFF + 4 * NT)    // float[64][2048] transposed codebook (512KB)
#define FITV_OFF  (KT_OFF + 8 * NT)      // double[NT] per-rescan-slot min dist
#define CMV_OFF   (FITV_OFF + 8 * NT)    // double[NT] per-rescan-slot commit part
#define PB_OFF    (CMV_OFF + 8 * NT)     // double[512][4] per-block partials

#define EPS_GAP 1e-3f    // r19-verified: 10x margin over ~1e-4 worst-case flip gap
#define VEPS    2e-3f

typedef __attribute__((ext_vector_type(8))) short bf16x8_t;  // 8 bf16 (4 VGPRs)
typedef __attribute__((ext_vector_type(4))) float f32x4_t;

__device__ __forceinline__ unsigned short bf16_rne(float f) {
  unsigned int u = __float_as_uint(f);
  unsigned int r = u + 0x7fffu + ((u >> 16) & 1u);
  return (unsigned short)(r >> 16);
}

#define REP32(F) F(0) F(1) F(2) F(3) F(4) F(5) F(6) F(7) \
  F(8) F(9) F(10) F(11) F(12) F(13) F(14) F(15) \
  F(16) F(17) F(18) F(19) F(20) F(21) F(22) F(23) \
  F(24) F(25) F(26) F(27) F(28) F(29) F(30) F(31)

// numpy pairwise_sum (scalar 8-accumulator, n=64) of PRE-ROUNDED squares; *_rn
// intrinsics forbid contraction. Bit-exact vs np.sum(a*a, -1). Used by prep and
// rescan (the exact path); the fused finalize uses split partials (its outputs
// have 2% thresholds and don't need np rounding order).
__device__ __forceinline__ float np_sumsq64_ptr(const float* a) {
  float r0 = __fmul_rn(a[0], a[0]);
  float r1 = __fmul_rn(a[1], a[1]);
  float r2 = __fmul_rn(a[2], a[2]);
  float r3 = __fmul_rn(a[3], a[3]);
  float r4 = __fmul_rn(a[4], a[4]);
  float r5 = __fmul_rn(a[5], a[5]);
  float r6 = __fmul_rn(a[6], a[6]);
  float r7 = __fmul_rn(a[7], a[7]);
#pragma unroll
  for (int i = 8; i < 64; i += 8) {
    r0 = __fadd_rn(r0, __fmul_rn(a[i + 0], a[i + 0]));
    r1 = __fadd_rn(r1, __fmul_rn(a[i + 1], a[i + 1]));
    r2 = __fadd_rn(r2, __fmul_rn(a[i + 2], a[i + 2]));
    r3 = __fadd_rn(r3, __fmul_rn(a[i + 3], a[i + 3]));
    r4 = __fadd_rn(r4, __fmul_rn(a[i + 4], a[i + 4]));
    r5 = __fadd_rn(r5, __fmul_rn(a[i + 5], a[i + 5]));
    r6 = __fadd_rn(r6, __fmul_rn(a[i + 6], a[i + 6]));
    r7 = __fadd_rn(r7, __fmul_rn(a[i + 7], a[i + 7]));
  }
  float t01 = __fadd_rn(r0, r1);
  float t23 = __fadd_rn(r2, r3);
  float t45 = __fadd_rn(r4, r5);
  float t67 = __fadd_rn(r6, r7);
  return __fadd_rn(__fadd_rn(t01, t23), __fadd_rn(t45, t67));
}

// ---------- K0: kn2_np + bf16 B-frags + transposed codebook kT[w][c] ----------
__global__ __launch_bounds__(256)
void vq_prep(const float* __restrict__ k, char* __restrict__ wsb) {
  int c = blockIdx.x * 256 + threadIdx.x;
  if (c >= KB) return;
  const float* kr = k + (size_t)c * WD;
  ((float*)(wsb + KN2_OFF))[c] = np_sumsq64_ptr(kr);
  float* kt = (float*)(wsb + KT_OFF);
#pragma unroll
  for (int w = 0; w < WD; ++w) kt[(size_t)w * KB + c] = kr[w];
  int jt = c >> 4, col = c & 15;
  unsigned short* cb = (unsigned short*)(wsb + CB_OFF);
#pragma unroll
  for (int w = 0; w < WD; ++w) {
    float f = kr[w];
    unsigned short hb = bf16_rne(f);
    float hf = __uint_as_float((unsigned int)hb << 16);
    unsigned short lb = bf16_rne(f - hf);
    int fH = w >> 5;                       // K-half: frag 0/1 (hi), 2/3 (lo)
    int lane = col | (((w >> 3) & 3) << 4);
    int e = w & 7;
    cb[((size_t)((jt * 4 + fH) * 64 + lane)) * 8 + e] = hb;
    cb[((size_t)((jt * 4 + 2 + fH) * 64 + lane)) * 8 + e] = lb;
  }
}

// ---------- K1: FUSED scan + finalize, 8 waves; SPLIT finalize (no spill) ----------
// r20 diagnosis: waves_per_eu(4) gave 4 waves/SIMD but spilled the finalize
// phase (VGPR 64, +65MB scratch traffic) — occupancy win eaten by spill.
// Fix: finalize split across thread PAIRS (tid, tid+256): 32 elements each
// (~55 live VGPR, no spill). Partials exchanged through the retired cbuf LDS.
// Legal: x_d is elementwise; commit/prenorm fp64 partials; s/g feed only
// 2%-threshold scalars and the resc decision (VEPS >> reassociation drift).
// XR compaction dropped (rescan count ~700 -> strided re-read is ~3MB).
__global__ __launch_bounds__(512) __attribute__((amdgpu_waves_per_eu(4)))
void vq_scan(const float* __restrict__ x, const float* __restrict__ k,
             float* __restrict__ out, char* __restrict__ wsb) {
  __shared__ float lkn2n[KB];         // 8KB: -0.5 * ||k||^2 (prescaled)
  __shared__ char cbuf[2][32768];     // 64KB dbuf B-frag chunks; reused for exchange
  __shared__ float sm1[256], sm2[256];
  __shared__ int sj1[256];
  __shared__ double sred[16];
  const int tid = threadIdx.x, lane = tid & 63, wave = tid >> 6;  // 8 waves
  const int col = lane & 15, grp = lane >> 4;

  for (int i = tid; i < KB; i += 512)
    lkn2n[i] = -0.5f * ((const float*)(wsb + KN2_OFF))[i];

  const int n = blockIdx.x >> 5;           // 32 blocks per n (8192/256)
  const int t0 = (blockIdx.x & 31) * 256;
  const float* xb = x + (size_t)n * WD * TD;

  // A-frags: wave owns 2 tiles (32 rows): rows t0 + wave*32 + T*16 + (grp*4+e)
  bf16x8_t aH[2][2], aL[2][2];
#pragma unroll
  for (int T = 0; T < 2; ++T) {
    const int trow = t0 + wave * 32 + T * 16 + col;
#pragma unroll
    for (int s = 0; s < 2; ++s) {
#pragma unroll
      for (int e = 0; e < 8; ++e) {
        int w = s * 32 + grp * 8 + e;
        float f = xb[(size_t)w * TD + trow];
        unsigned short hb = bf16_rne(f);
        float hf = __uint_as_float((unsigned int)hb << 16);
        unsigned short lb = bf16_rne(f - hf);
        aH[T][s][e] = (short)hb;
        aL[T][s][e] = (short)lb;
      }
    }
  }

  // packed argmax trackers: value bits [31:7], jt in bits [6:0]
  float M1[2][4], M2[2][4];
#pragma unroll
  for (int T = 0; T < 2; ++T)
#pragma unroll
    for (int e = 0; e < 4; ++e) {
      M1[T][e] = -INFINITY; M2[T][e] = -INFINITY;
    }

  const char* cbsrc = wsb + CB_OFF;
  float4 pf0, pf1, pf2, pf3;
#define PREF(c) { const float4* sp = (const float4*)(cbsrc + (size_t)(c) * 32768); \
    pf0 = sp[tid]; pf1 = sp[tid + 512]; pf2 = sp[tid + 1024]; pf3 = sp[tid + 1536]; }
#define WRBUF(b) { float4* dp = (float4*)cbuf[b]; \
    dp[tid] = pf0; dp[tid + 512] = pf1; dp[tid + 1024] = pf2; dp[tid + 1536] = pf3; }

  PREF(0)
  WRBUF(0)
  PREF(1)
  __syncthreads();

  for (int c = 0; c < 16; ++c) {
    const int cur = c & 1;
    if (c < 15) WRBUF(cur ^ 1)
    if (c < 14) PREF(c + 2)
#pragma unroll
    for (int jl = 0; jl < 8; ++jl) {
      const bf16x8_t* bp = (const bf16x8_t*)(cbuf[cur] + jl * 4096) + lane;
      bf16x8_t bH0 = bp[0], bH1 = bp[64], bL0 = bp[128], bL1 = bp[192];
      const int jt = c * 8 + jl;
      const float ci = lkn2n[jt * 16 + col];
#pragma unroll
      for (int T = 0; T < 2; ++T) {
        f32x4_t acc = {ci, ci, ci, ci};
        acc = __builtin_amdgcn_mfma_f32_16x16x32_bf16(aH[T][0], bH0, acc, 0, 0, 0);
        acc = __builtin_amdgcn_mfma_f32_16x16x32_bf16(aH[T][1], bH1, acc, 0, 0, 0);
        acc = __builtin_amdgcn_mfma_f32_16x16x32_bf16(aL[T][0], bH0, acc, 0, 0, 0);
        acc = __builtin_amdgcn_mfma_f32_16x16x32_bf16(aL[T][1], bH1, acc, 0, 0, 0);
        acc = __builtin_amdgcn_mfma_f32_16x16x32_bf16(aH[T][0], bL0, acc, 0, 0, 0);
        acc = __builtin_amdgcn_mfma_f32_16x16x32_bf16(aH[T][1], bL1, acc, 0, 0, 0);
#pragma unroll
        for (int e = 0; e < 4; ++e) {
          float vp = __uint_as_float(
              (__float_as_uint(acc[e]) & 0xFFFFFF80u) | (unsigned)jt);
          M2[T][e] = __builtin_amdgcn_fmed3f(M1[T][e], M2[T][e], vp);
          M1[T][e] = fmaxf(M1[T][e], vp);
        }
      }
    }
    __syncthreads();
  }
#undef PREF
#undef WRBUF

  // cross-lane reduce -> per-row (m1,m2,j1) into LDS
#pragma unroll
  for (int T = 0; T < 2; ++T)
#pragma unroll
    for (int e = 0; e < 4; ++e) {
      float m1 = M1[T][e], m2 = M2[T][e];
      int cd = (int)(__float_as_uint(m1) & 0x7Fu) * 16 + col;
#pragma unroll
      for (int d = 1; d < 16; d <<= 1) {
        float om1 = __shfl_xor(m1, d, 64);
        float om2 = __shfl_xor(m2, d, 64);
        int ocd = __shfl_xor(cd, d, 64);
        bool take = (om1 > m1) || (om1 == m1 && ocd < cd);
        float loser = take ? m1 : om1;
        m2 = fmaxf(fmaxf(m2, om2), loser);
        m1 = take ? om1 : m1;
        cd = take ? ocd : cd;
      }
      if (col == 0) {
        int r = wave * 32 + T * 16 + grp * 4 + e;
        sm1[r] = -2.f * m1;                // score domain
        sm2[r] = -2.f * m2;
        sj1[r] = cd;
      }
    }
  __syncthreads();

  // ---- fused finalize, SPLIT: thread pair (r, r+256) handles row r ----
  // Exchange area reuses cbuf[0] (retired; last read before prior barrier).
  float* s_ex = (float*)cbuf[0];                 // [2][256]
  float* g_ex = (float*)(cbuf[0] + 2048);        // [2][256]
  double* xs_ex = (double*)(cbuf[0] + 4096);     // [2][256]
  double* xq_ex = (double*)(cbuf[0] + 8192);     // [2][256]
  double* cm_ex = (double*)(cbuf[0] + 12288);    // [2][256]

  const int r = tid & 255, h = tid >> 8;         // row slot, half
  const int row = blockIdx.x * 256 + r;
  const int t = row & (TD - 1);
  const int j1r = sj1[r];
  {
    const float* xrh = x + ((size_t)n * WD + (size_t)h * 32) * TD + t;
    float* xoh = out + OFF_XD + ((size_t)n * WD + (size_t)h * 32) * TD + t;
    const float4* k4 = (const float4*)(k + (size_t)j1r * WD) + h * 8;

#define LOADX(w) float x##w = xrh[(size_t)(w) * TD];
    REP32(LOADX)
#undef LOADX

    float sp = 0.f, gp = 0.f;
    double xsum = 0.0, xsumsq = 0.0, commit = 0.0;
#define EPI1(w, KW) { \
      float kw = KW; \
      sp = __fmaf_rn(x##w, x##w, sp); \
      gp = __fmaf_rn(x##w, kw, gp); \
      double xd = (double)x##w; \
      xsum += xd; xsumsq = fma(xd, xd, xsumsq); \
      float diff = __fsub_rn(kw, x##w); \
      commit = fma((double)diff, (double)diff, commit); \
      xoh[(size_t)(w) * TD] = __fadd_rn(x##w, diff); }
    {
      float4 ka = k4[0], kb = k4[1], kc = k4[2], kd = k4[3];
      EPI1(0, ka.x) EPI1(1, ka.y) EPI1(2, ka.z) EPI1(3, ka.w)
      EPI1(4, kb.x) EPI1(5, kb.y) EPI1(6, kb.z) EPI1(7, kb.w)
      EPI1(8, kc.x) EPI1(9, kc.y) EPI1(10, kc.z) EPI1(11, kc.w)
      EPI1(12, kd.x) EPI1(13, kd.y) EPI1(14, kd.z) EPI1(15, kd.w)
    }
    {
      float4 ka = k4[4], kb = k4[5], kc = k4[6], kd = k4[7];
      EPI1(16, ka.x) EPI1(17, ka.y) EPI1(18, ka.z) EPI1(19, ka.w)
      EPI1(20, kb.x) EPI1(21, kb.y) EPI1(22, kb.z) EPI1(23, kb.w)
      EPI1(24, kc.x) EPI1(25, kc.y) EPI1(26, kc.z) EPI1(27, kc.w)
      EPI1(28, kd.x) EPI1(29, kd.y) EPI1(30, kd.z) EPI1(31, kd.w)
    }
#undef EPI1

    s_ex[h * 256 + r] = sp;
    g_ex[h * 256 + r] = gp;
    xs_ex[h * 256 + r] = xsum;
    xq_ex[h * 256 + r] = xsumsq;
    cm_ex[h * 256 + r] = commit;
  }
  __syncthreads();

  if (tid < 256) {
    const float m1r = sm1[tid], m2r = sm2[tid];
    const float s = s_ex[tid] + s_ex[256 + tid];
    const float g = g_ex[tid] + g_ex[256 + tid];
    const double xsum = xs_ex[tid] + xs_ex[256 + tid];
    const double xsumsq = xq_ex[tid] + xq_ex[256 + tid];
    const double commit = cm_ex[tid] + cm_ex[256 + tid];
    const int rowq = blockIdx.x * 256 + tid;

    float kn2j = ((const float*)(wsb + KN2_OFF))[sj1[tid]];
    float score = kn2j - 2.f * g;
    bool resc = (m2r - m1r < EPS_GAP) || (fabsf(score - m1r) > VEPS);
    float dist1 = (s - 2.f * g) + kn2j;

    out[OFF_XL + rowq] = (float)sj1[tid];
    if (resc) {
      unsigned idx = atomicAdd((unsigned*)(wsb + CNT_OFF), 1u);
      ((int*)(wsb + LIST_OFF))[idx] = rowq;
    }

    double v0 = xsum, v1 = xsumsq;
    double v2 = resc ? 0.0 : (double)dist1;
    double v3 = resc ? 0.0 : commit;
#pragma unroll
    for (int off = 32; off > 0; off >>= 1) {
      v0 += __shfl_down(v0, off, 64);
      v1 += __shfl_down(v1, off, 64);
      v2 += __shfl_down(v2, off, 64);
      v3 += __shfl_down(v3, off, 64);
    }
    if ((tid & 63) == 0) {
      int wv = tid >> 6;
      sred[wv * 4 + 0] = v0;
      sred[wv * 4 + 1] = v1;
      sred[wv * 4 + 2] = v2;
      sred[wv * 4 + 3] = v3;
    }
  }
  __syncthreads();
  if (tid == 0) {
    double a0 = 0, a1 = 0, a2 = 0, a3 = 0;
#pragma unroll
    for (int w2 = 0; w2 < 4; ++w2) {
      a0 += sred[w2 * 4 + 0];
      a1 += sred[w2 * 4 + 1];
      a2 += sred[w2 * 4 + 2];
      a3 += sred[w2 * 4 + 3];
    }
    double* pb = (double*)(wsb + PB_OFF) + (size_t)blockIdx.x * 4;
    pb[0] = a0; pb[1] = a1; pb[2] = a2; pb[3] = a3;
  }
}

// ---------- K3: exact rescan, 4 rows/block, per-slot results ----------
__global__ __launch_bounds__(256)
void vq_rescan7(const float* __restrict__ x, const float* __restrict__ k,
                float* __restrict__ out, char* __restrict__ wsb) {
  __shared__ float xs[4][WD];
  __shared__ float ss[4];
  __shared__ unsigned long long wred[4][4];   // [row][wave]
  __shared__ unsigned long long bbest[4];
  const unsigned count = *(const unsigned*)(wsb + CNT_OFF);
  const int* list = (const int*)(wsb + LIST_OFF);
  const float* kn2 = (const float*)(wsb + KN2_OFF);
  const float* kT = (const float*)(wsb + KT_OFF);
  double* fitv = (double*)(wsb + FITV_OFF);
  double* cmv = (double*)(wsb + CMV_OFF);
  const int tid = threadIdx.x;
  const int lane = tid & 63, wv = tid >> 6;
  const int c0 = tid * 8;

  for (unsigned base = blockIdx.x * 4u; base < count; base += gridDim.x * 4u) {
    __syncthreads();                       // xs/ss/wred reuse guard
    {
      const int r = tid >> 6, w = tid & 63;
      const unsigned li = base + (unsigned)r;
      if (li < count) {
        const int row = list[li];
        const int n = row >> 13, t = row & (TD - 1);
        xs[r][w] = x[(size_t)n * WD * TD + (size_t)w * TD + t];
      }
    }
    __syncthreads();
    if (lane == 0) ss[wv] = np_sumsq64_ptr(xs[wv]);
    __syncthreads();
    const float s0 = ss[0], s1 = ss[1], s2 = ss[2], s3 = ss[3];

    float a00 = 0.f, a01 = 0.f, a02 = 0.f, a03 = 0.f, a04 = 0.f, a05 = 0.f, a06 = 0.f, a07 = 0.f;
    float a10 = 0.f, a11 = 0.f, a12 = 0.f, a13 = 0.f, a14 = 0.f, a15 = 0.f, a16 = 0.f, a17 = 0.f;
    float a20 = 0.f, a21 = 0.f, a22 = 0.f, a23 = 0.f, a24 = 0.f, a25 = 0.f, a26 = 0.f, a27 = 0.f;
    float a30 = 0.f, a31 = 0.f, a32 = 0.f, a33 = 0.f, a34 = 0.f, a35 = 0.f, a36 = 0.f, a37 = 0.f;
    const float* kt = kT + c0;
#pragma unroll 4
    for (int w = 0; w < WD; ++w) {
      const float4 ka = *(const float4*)(kt + (size_t)w * KB);
      const float4 kb = *(const float4*)(kt + (size_t)w * KB + 4);
      const float xw0 = xs[0][w], xw1 = xs[1][w], xw2 = xs[2][w], xw3 = xs[3][w];
      a00 = __fmaf_rn(xw0, ka.x, a00); a01 = __fmaf_rn(xw0, ka.y, a01);
      a02 = __fmaf_rn(xw0, ka.z, a02); a03 = __fmaf_rn(xw0, ka.w, a03);
      a04 = __fmaf_rn(xw0, kb.x, a04); a05 = __fmaf_rn(xw0, kb.y, a05);
      a06 = __fmaf_rn(xw0, kb.z, a06); a07 = __fmaf_rn(xw0, kb.w, a07);
      a10 = __fmaf_rn(xw1, ka.x, a10); a11 = __fmaf_rn(xw1, ka.y, a11);
      a12 = __fmaf_rn(xw1, ka.z, a12); a13 = __fmaf_rn(xw1, ka.w, a13);
      a14 = __fmaf_rn(xw1, kb.x, a14); a15 = __fmaf_rn(xw1, kb.y, a15);
      a16 = __fmaf_rn(xw1, kb.z, a16); a17 = __fmaf_rn(xw1, kb.w, a17);
      a20 = __fmaf_rn(xw2, ka.x, a20); a21 = __fmaf_rn(xw2, ka.y, a21);
      a22 = __fmaf_rn(xw2, ka.z, a22); a23 = __fmaf_rn(xw2, ka.w, a23);
      a24 = __fmaf_rn(xw2, kb.x, a24); a25 = __fmaf_rn(xw2, kb.y, a25);
      a26 = __fmaf_rn(xw2, kb.z, a26); a27 = __fmaf_rn(xw2, kb.w, a27);
      a30 = __fmaf_rn(xw3, ka.x, a30); a31 = __fmaf_rn(xw3, ka.y, a31);
      a32 = __fmaf_rn(xw3, ka.z, a32); a33 = __fmaf_rn(xw3, ka.w, a33);
      a34 = __fmaf_rn(xw3, kb.x, a34); a35 = __fmaf_rn(xw3, kb.y, a35);
      a36 = __fmaf_rn(xw3, kb.z, a36); a37 = __fmaf_rn(xw3, kb.w, a37);
    }

#define ROWBEST(R, SV, A0, A1, A2, A3, A4, A5, A6, A7) { \
      unsigned long long best = ~0ull; \
      float d; unsigned long long p; \
      d = __fadd_rn(__fsub_rn(SV, __fmul_rn(2.f, A0)), kn2[c0 + 0]); \
      p = ((unsigned long long)__float_as_uint(d) << 32) | (unsigned)(c0 + 0); best = p < best ? p : best; \
      d = __fadd_rn(__fsub_rn(SV, __fmul_rn(2.f, A1)), kn2[c0 + 1]); \
      p = ((unsigned long long)__float_as_uint(d) << 32) | (unsigned)(c0 + 1); best = p < best ? p : best; \
      d = __fadd_rn(__fsub_rn(SV, __fmul_rn(2.f, A2)), kn2[c0 + 2]); \
      p = ((unsigned long long)__float_as_uint(d) << 32) | (unsigned)(c0 + 2); best = p < best ? p : best; \
      d = __fadd_rn(__fsub_rn(SV, __fmul_rn(2.f, A3)), kn2[c0 + 3]); \
      p = ((unsigned long long)__float_as_uint(d) << 32) | (unsigned)(c0 + 3); best = p < best ? p : best; \
      d = __fadd_rn(__fsub_rn(SV, __fmul_rn(2.f, A4)), kn2[c0 + 4]); \
      p = ((unsigned long long)__float_as_uint(d) << 32) | (unsigned)(c0 + 4); best = p < best ? p : best; \
      d = __fadd_rn(__fsub_rn(SV, __fmul_rn(2.f, A5)), kn2[c0 + 5]); \
      p = ((unsigned long long)__float_as_uint(d) << 32) | (unsigned)(c0 + 5); best = p < best ? p : best; \
      d = __fadd_rn(__fsub_rn(SV, __fmul_rn(2.f, A6)), kn2[c0 + 6]); \
      p = ((unsigned long long)__float_as_uint(d) << 32) | (unsigned)(c0 + 6); best = p < best ? p : best; \
      d = __fadd_rn(__fsub_rn(SV, __fmul_rn(2.f, A7)), kn2[c0 + 7]); \
      p = ((unsigned long long)__float_as_uint(d) << 32) | (unsigned)(c0 + 7); best = p < best ? p : best; \
      _Pragma("unroll") \
      for (int dd = 1; dd < 64; dd <<= 1) { \
        unsigned lo = (unsigned)best, hi = (unsigned)(best >> 32); \
        unsigned olo = __shfl_xor(lo, dd, 64); \
        unsigned ohi = __shfl_xor(hi, dd, 64); \
        unsigned long long o = ((unsigned long long)ohi << 32) | olo; \
        best = o < best ? o : best; \
      } \
      if (lane == 0) wred[R][wv] = best; }
    ROWBEST(0, s0, a00, a01, a02, a03, a04, a05, a06, a07)
    ROWBEST(1, s1, a10, a11, a12, a13, a14, a15, a16, a17)
    ROWBEST(2, s2, a20, a21, a22, a23, a24, a25, a26, a27)
    ROWBEST(3, s3, a30, a31, a32, a33, a34, a35, a36, a37)
#undef ROWBEST
    __syncthreads();
    if (tid < 4) {
      unsigned long long b = wred[tid][0];
      b = wred[tid][1] < b ? wred[tid][1] : b;
      b = wred[tid][2] < b ? wred[tid][2] : b;
      b = wred[tid][3] < b ? wred[tid][3] : b;
      bbest[tid] = b;
    }
    __syncthreads();

    {
      const int r = wv, w = lane;
      const unsigned li = base + (unsigned)r;
      if (li < count) {
        const int row = list[li];
        const int n = row >> 13, t = row & (TD - 1);
        const unsigned long long fb = bbest[r];
        const int bi = (int)(fb & 0xffffffffu);
        const float bv = __uint_as_float((unsigned)(fb >> 32));
        float kw = k[(size_t)bi * WD + w];
        float xw = xs[r][w];
        float diff = __fsub_rn(kw, xw);
        out[OFF_XD + (size_t)n * WD * TD + (size_t)w * TD + t] = __fadd_rn(xw, diff);
        double d2 = (double)diff * (double)diff;
#pragma unroll
        for (int dd = 32; dd > 0; dd >>= 1) d2 += __shfl_down(d2, dd, 64);
        if (w == 0) {
          out[OFF_XL + row] = (float)bi;
          fitv[li] = (double)bv;
          cmv[li] = d2;
        }
      }
    }
  }
}

// ---------- K4: final scalars — reduce PB partials + rescan arrays ----------
__global__ __launch_bounds__(256)
void vq_final(const char* __restrict__ wsb, float* __restrict__ out) {
  __shared__ double sred[24];
  const unsigned count = *(const unsigned*)(wsb + CNT_OFF);
  const double* fitv = (const double*)(wsb + FITV_OFF);
  const double* cmv = (const double*)(wsb + CMV_OFF);
  const double* pb = (const double*)(wsb + PB_OFF);
  const int tid = threadIdx.x;

  double fa = 0.0, ca = 0.0;
  for (unsigned i = tid; i < count; i += 256) {
    fa += fitv[i];
    ca += cmv[i];
  }
  double b0 = 0.0, b1 = 0.0, b2 = 0.0, b3 = 0.0;
  for (int i = tid; i < 512; i += 256) {
    b0 += pb[i * 4 + 0];
    b1 += pb[i * 4 + 1];
    b2 += pb[i * 4 + 2];
    b3 += pb[i * 4 + 3];
  }
#pragma unroll
  for (int off = 32; off > 0; off >>= 1) {
    fa += __shfl_down(fa, off, 64);
    ca += __shfl_down(ca, off, 64);
    b0 += __shfl_down(b0, off, 64);
    b1 += __shfl_down(b1, off, 64);
    b2 += __shfl_down(b2, off, 64);
    b3 += __shfl_down(b3, off, 64);
  }
  if ((tid & 63) == 0) {
    int wv = tid >> 6;
    sred[wv * 6 + 0] = fa;
    sred[wv * 6 + 1] = ca;
    sred[wv * 6 + 2] = b0;
    sred[wv * 6 + 3] = b1;
    sred[wv * 6 + 4] = b2;
    sred[wv * 6 + 5] = b3;
  }
  __syncthreads();
  if (tid == 0) {
    double fit = 0, cm = 0, sum = 0, sumsq = 0;
#pragma unroll
    for (int i = 0; i < 4; ++i) {
      fit += sred[i * 6 + 0] + sred[i * 6 + 4];   // rescan fit + block fit
      cm += sred[i * 6 + 1] + sred[i * 6 + 5];    // rescan commit + block commit
      sum += sred[i * 6 + 2];
      sumsq += sred[i * 6 + 3];
    }
    double mean = sum / 8388608.0;
    double ss = sumsq - sum * mean;
    if (ss < 0.0) ss = 0.0;
    out[OFF_SC + 0] = (float)(cm / 8388608.0);         // commit_loss
    out[OFF_SC + 1] = (float)(fit / 131072.0);         // fit
    out[OFF_SC + 2] = (float)sqrt(ss / 8388608.0);     // prenorm
  }
}

extern "C" void kernel_launch(void* const* d_in, const int* in_sizes, int n_in,
                              void* d_out, int out_size, void* d_ws, size_t ws_size,
                              hipStream_t stream) {
  const float* x = (const float*)d_in[0];
  const float* k = (const float*)d_in[1];
  float* out = (float*)d_out;
  char* wsb = (char*)d_ws;

  hipMemsetAsync(d_ws, 0, 64, stream);                 // count (+ reserved)
  vq_prep<<<KB / 256, 256, 0, stream>>>(k, wsb);
  vq_scan<<<NT / 256, 512, 0, stream>>>(x, k, out, wsb);
  vq_rescan7<<<1024, 256, 0, stream>>>(x, k, out, wsb);
  vq_final<<<1, 256, 0, stream>>>(wsb, out);
}